// Round 6
// baseline (348.280 us; speedup 1.0000x reference)
//
#include <hip/hip_runtime.h>
#include <stdint.h>

typedef float  f32x4 __attribute__((ext_vector_type(4)));
typedef short  s16x8 __attribute__((ext_vector_type(8)));
typedef unsigned int u32;
typedef u32    u32x2 __attribute__((ext_vector_type(2)));
typedef u32    u32x4 __attribute__((ext_vector_type(4)));
typedef unsigned short u16;

#define MFMA16(a,b,c) __builtin_amdgcn_mfma_f32_16x16x32_bf16((a),(b),(c),0,0,0)

__device__ __forceinline__ u16 f2bf(float f){
  u32 u = __float_as_uint(f);
  return (u16)((u + 0x7fffu + ((u >> 16) & 1u)) >> 16);   // RNE
}
__device__ __forceinline__ float bf2f(u16 h){ return __uint_as_float(((u32)h) << 16); }
__device__ __forceinline__ u32 pack2bf(float a, float b){ return (u32)f2bf(a) | ((u32)f2bf(b) << 16); }
__device__ __forceinline__ f32x4 f4zero(){ f32x4 z; z[0]=0.f; z[1]=0.f; z[2]=0.f; z[3]=0.f; return z; }
// register-only vector build (NO union: unions can defeat SROA -> scratch)
__device__ __forceinline__ s16x8 mk8(u32 a, u32 b, u32 c, u32 d){
  u32x4 w; w[0]=a; w[1]=b; w[2]=c; w[3]=d;
  return __builtin_bit_cast(s16x8, w);
}

// async global->LDS, 16B per lane; LDS dest is wave-uniform base + lane*16
__device__ __forceinline__ void async16(const void* g, void* l){
  __builtin_amdgcn_global_load_lds(
      (const __attribute__((address_space(1))) unsigned int*)g,
      (__attribute__((address_space(3))) unsigned int*)l, 16, 0, 0);
}

// ---------------------------------------------------------------------------
// K1 (fused): blocks [0,1024): split x -> xh/xl + build Xt
//             blocks [1024,1032): wr^T hi/lo   [1032,1040): w1^T
//             blocks [1040,1104): k_s0 body (exact fp32 row-0 logits + maxpart)
// ---------------------------------------------------------------------------
__global__ __launch_bounds__(256) void k_prep(
    const float* __restrict__ x, const float* __restrict__ wr, const float* __restrict__ w1,
    u16* __restrict__ xh, u16* __restrict__ xl, u16* __restrict__ Xt,
    u16* __restrict__ wrth, u16* __restrict__ wrtl, u16* __restrict__ w1t,
    float* __restrict__ S0, float* __restrict__ maxpart)
{
  __shared__ float xs[16][132];
  __shared__ float x0s[128];
  __shared__ float ys[128];
  __shared__ float red[256];
  const int tid = threadIdx.x, bid = blockIdx.x;
  if (bid < 1024){
    const long base = (long)bid * 2048;          // 16 rows * 128
#pragma unroll
    for (int k = 0; k < 8; k++){
      int idx = tid + k*256;
      float v = x[base + idx];
      xs[idx>>7][idx&127] = v;
      u16 h = f2bf(v);
      xh[base+idx] = h;
      xl[base+idx] = f2bf(v - bf2f(h));
    }
    __syncthreads();
    const int b  = bid >> 7;                     // 128 blocks per batch
    const int n0 = (bid & 127) * 16;
    const int nn = tid & 15, d0 = tid >> 4;
#pragma unroll
    for (int d = 0; d < 8; d++){
      int dd = d0 + d*16;
      Xt[(long)b*262144 + (long)dd*2048 + n0 + nn] = f2bf(xs[nn][dd]);
    }
  } else if (bid < 1032){
    const int base = (bid - 1024) * 2048;
#pragma unroll
    for (int k = 0; k < 8; k++){
      int idx = base + k*256 + tid;
      int g = idx >> 7, f = idx & 127;
      float v = wr[f*128 + g];                   // wrT[g][f] = wr[f][g]
      u16 h = f2bf(v);
      wrth[idx] = h;
      wrtl[idx] = f2bf(v - bf2f(h));
    }
  } else if (bid < 1040){
    const int base = (bid - 1032) * 2048;
#pragma unroll
    for (int k = 0; k < 8; k++){
      int idx = base + k*256 + tid;
      int c = idx >> 7, f = idx & 127;
      w1t[idx] = f2bf(w1[f*128 + c]);            // w1T[c][f] = w1[f][c]
    }
  } else {
    const int jj = bid - 1040;
    const int b = jj >> 3, j = jj & 7;
    if (tid < 128) x0s[tid] = x[(long)b*262144 + tid];
    __syncthreads();
    if (tid < 128){
      float a = 0.f;
      for (int f = 0; f < 128; f++) a += x0s[f] * wr[f*128 + tid];
      ys[tid] = a;
    }
    __syncthreads();
    const int m = j*256 + tid;
    const float4* xr = (const float4*)(x + ((long)b*2048 + m)*128);
    const float4* yv = (const float4*)ys;
    float acc = 0.f;
#pragma unroll
    for (int f = 0; f < 32; f++){
      float4 a = xr[f], c = yv[f];
      acc += a.x*c.x + a.y*c.y + a.z*c.z + a.w*c.w;
    }
    S0[b*2048 + m] = acc;
    red[tid] = acc;
    __syncthreads();
    for (int sft = 128; sft > 0; sft >>= 1){
      if (tid < sft) red[tid] = fmaxf(red[tid], red[tid + sft]);
      __syncthreads();
    }
    if (tid == 0) maxpart[jj] = red[0];
  }
}

// ---------------------------------------------------------------------------
// K2: y = (x @ wr) * log2(e)  via 3-term split bf16 MFMA; write yh/yl hi/lo
// ---------------------------------------------------------------------------
__global__ __launch_bounds__(128, 2) void k_ygemm(
    const u16* __restrict__ xh, const u16* __restrict__ xl,
    const u16* __restrict__ wrth, const u16* __restrict__ wrtl,
    u16* __restrict__ yh, u16* __restrict__ yl)
{
  __shared__ u16 sbh[16384], sbl[16384];       // [c][f] bf16, XOR-swizzled
  const int tid = threadIdx.x, bid = blockIdx.x;
#pragma unroll
  for (int k = 0; k < 16; k++){
    int off = (tid + k*128) * 16;
    int row = off >> 8;
    int dst = off ^ ((row & 7) << 4);
    *(s16x8*)((char*)sbh + dst) = *(const s16x8*)((const char*)wrth + off);
    *(s16x8*)((char*)sbl + dst) = *(const s16x8*)((const char*)wrtl + off);
  }
  __syncthreads();
  const int w = tid >> 6, lane = tid & 63, lr = lane & 15, g = lane >> 4;
  const long rowbase = (long)bid*64 + w*32;
  s16x8 ah[2][4], al[2][4];
#pragma unroll
  for (int rh = 0; rh < 2; rh++)
#pragma unroll
    for (int kc = 0; kc < 4; kc++){
      long r = rowbase + rh*16 + lr;
      ah[rh][kc] = *(const s16x8*)(xh + r*128 + kc*32 + g*8);
      al[rh][kc] = *(const s16x8*)(xl + r*128 + kc*32 + g*8);
    }
  f32x4 acc[2][8];
#pragma unroll
  for (int rh = 0; rh < 2; rh++)
#pragma unroll
    for (int cg = 0; cg < 8; cg++) acc[rh][cg] = f4zero();
  const int swz = (lr & 7) << 4;
#pragma unroll
  for (int cg = 0; cg < 8; cg++){
    const int rowt = (cg*16 + lr) * 256;
#pragma unroll
    for (int kc = 0; kc < 4; kc++){
      int boff = rowt + ((kc*64 + g*16) ^ swz);
      s16x8 bh = *(const s16x8*)((const char*)sbh + boff);
      s16x8 bl = *(const s16x8*)((const char*)sbl + boff);
#pragma unroll
      for (int rh = 0; rh < 2; rh++){
        acc[rh][cg] = MFMA16(ah[rh][kc], bh, acc[rh][cg]);
        acc[rh][cg] = MFMA16(al[rh][kc], bh, acc[rh][cg]);
        acc[rh][cg] = MFMA16(ah[rh][kc], bl, acc[rh][cg]);
      }
    }
  }
#pragma unroll
  for (int rh = 0; rh < 2; rh++)
#pragma unroll
    for (int cg = 0; cg < 8; cg++)
#pragma unroll
      for (int r = 0; r < 4; r++){
        long q = rowbase + rh*16 + 4*g + r;    // C-layout: row=(l>>4)*4+reg
        int  c = cg*16 + lr;                   //           col=l&15
        float v = acc[rh][cg][r] * 1.4426950408889634f;
        u16 h = f2bf(v);
        yh[q*128 + c] = h;
        yl[q*128 + c] = f2bf(v - bf2f(h));
      }
}

// ---------------------------------------------------------------------------
// K3: fused flash, swapped-operand form.
//   sxh/sxl double-buffered (row&7 XOR-swz); sxt SINGLE-buffered (row&3 swz)
//   with two barriers per tile: bar1 after PV (guards overwrite), bar2 after
//   stage_t (its implicit vmcnt(0) drain completes sxt for the next tile).
//   LDS = 40KB -> 4 blocks/CU; launch_bounds (256,4) caps VGPR at 128
//   (measured pressure 112; (256,3)+ risked >128 -> 3 waves/SIMD).
//   KS=8 -> 1024 blocks (4/CU), Opart bf16.
// ---------------------------------------------------------------------------
__global__ __launch_bounds__(256, 4) void k_flash(
    const u16* __restrict__ xh, const u16* __restrict__ xl, const u16* __restrict__ Xt,
    const u16* __restrict__ yh, const u16* __restrict__ yl,
    u16* __restrict__ A1bf,
    u16* __restrict__ Opart, float* __restrict__ mpart, float* __restrict__ lpart,
    int KS, int kslog)
{
  __shared__ u16 sxh[2][4096], sxl[2][4096];   // 32kv x 128f, XOR-swz (row&7)
  __shared__ u16 sxt[4096];                    // 128d x 32kv, XOR-swz (row&3)
  const int tid = threadIdx.x, bid = blockIdx.x;
  const int b     = bid & 7;                   // XCD b owns batch b
  const int inner = bid >> 3;
  const int s     = inner & (KS - 1);
  const int qbl   = inner >> kslog;
  const int qb    = b*16 + qbl;
  const int nspan = 2048 >> kslog;
  const int kv0   = s * nspan;
  const int ntiles = nspan >> 5;
  const int w = tid >> 6, lane = tid & 63, lr = lane & 15, g = lane >> 4;
  const long qrow = (long)qb*128 + w*32;

  // Y fragments (B-operands), hi/lo — per-warp constants
  s16x8 byh[2][4], byl[2][4];
#pragma unroll
  for (int qh = 0; qh < 2; qh++)
#pragma unroll
    for (int kc = 0; kc < 4; kc++){
      long r = qrow + qh*16 + lr;
      byh[qh][kc] = *(const s16x8*)(yh + r*128 + kc*32 + g*8);
      byl[qh][kc] = *(const s16x8*)(yl + r*128 + kc*32 + g*8);
    }

  f32x4 o[8][2];                               // O^T: [d-tile dg][q-half qh]
#pragma unroll
  for (int dg = 0; dg < 8; dg++){ o[dg][0] = f4zero(); o[dg][1] = f4zero(); }
  float mrun[2] = {-1e30f, -1e30f}, lrun[2] = {0.f, 0.f};

  const char* gxh  = (const char*)xh + ((long)b*2048 + kv0)*256;
  const char* gxl  = (const char*)xl + ((long)b*2048 + kv0)*256;
  const char* gxtb = (const char*)(Xt + (long)b*262144 + kv0);

  auto stage_hl = [&](int bufi, int t){
#pragma unroll
    for (int c2 = 0; c2 < 2; c2++){
      int chunk = w*2 + c2;
      int off = chunk*1024 + lane*16;
      int row = off >> 8;
      int swo = off ^ ((row & 7) << 4);        // rows of 256B: swizzle row&7
      async16(gxh + (long)t*8192 + swo, &sxh[bufi][chunk*512]);
      async16(gxl + (long)t*8192 + swo, &sxl[bufi][chunk*512]);
    }
  };
  auto stage_t = [&](int t){
#pragma unroll
    for (int c2 = 0; c2 < 2; c2++){
      int chunk = w*2 + c2;
      int off = chunk*1024 + lane*16;
      int row = off >> 6;
      int col = off & 63;                      // rows of 64B: swizzle row&3
      int src = row*4096 + (col ^ ((row & 3) << 4));
      async16(gxtb + (long)t*64 + src, &sxt[chunk*512]);
    }
  };

  stage_hl(0, 0);
  stage_t(0);
  __syncthreads();

  for (int t = 0; t < ntiles; t++){
    const int cur = t & 1;
    if (t + 1 < ntiles) stage_hl(cur ^ 1, t + 1);
    const char* pxh = (const char*)&sxh[cur][0];
    const char* pxl = (const char*)&sxl[cur][0];

    // ---- S^T tile [32kv x 32q], 3-term hi/lo split ----
    f32x4 sacc[2][2];                          // [kv-half ch][q-half qh]
    sacc[0][0] = f4zero(); sacc[0][1] = f4zero();
    sacc[1][0] = f4zero(); sacc[1][1] = f4zero();
    __builtin_amdgcn_s_setprio(1);
#pragma unroll
    for (int ch = 0; ch < 2; ch++){
      const int rowb = ch*16 + lr;
#pragma unroll
      for (int kc = 0; kc < 4; kc++){
        const int boff = rowb*256 + ((kc*64 + g*16) ^ ((rowb & 7) << 4));
        s16x8 fh = *(const s16x8*)(pxh + boff);
        s16x8 fl = *(const s16x8*)(pxl + boff);
#pragma unroll
        for (int qh = 0; qh < 2; qh++){
          sacc[ch][qh] = MFMA16(fh, byh[qh][kc], sacc[ch][qh]);
          sacc[ch][qh] = MFMA16(fl, byh[qh][kc], sacc[ch][qh]);
          sacc[ch][qh] = MFMA16(fh, byl[qh][kc], sacc[ch][qh]);
        }
      }
    }
    __builtin_amdgcn_s_setprio(0);

    // ---- lane-local online softmax + in-register P^T redistribution ----
    s16x8 bpq[2];
#pragma unroll
    for (int qh = 0; qh < 2; qh++){
      float cm = fmaxf(fmaxf(fmaxf(sacc[0][qh][0], sacc[0][qh][1]),
                             fmaxf(sacc[0][qh][2], sacc[0][qh][3])),
                       fmaxf(fmaxf(sacc[1][qh][0], sacc[1][qh][1]),
                             fmaxf(sacc[1][qh][2], sacc[1][qh][3])));
      cm = fmaxf(cm, __shfl_xor(cm, 16, 64));
      cm = fmaxf(cm, __shfl_xor(cm, 32, 64));
      if (__any(cm > mrun[qh] + 8.f)){         // defer-max (log2 units, P<=256)
        float mn = fmaxf(mrun[qh], cm);
        float sc = exp2f(mrun[qh] - mn);
#pragma unroll
        for (int dg = 0; dg < 8; dg++)
#pragma unroll
          for (int r = 0; r < 4; r++) o[dg][qh][r] *= sc;
        lrun[qh] *= sc;
        mrun[qh] = mn;
      }
      float p[2][4];
#pragma unroll
      for (int ch = 0; ch < 2; ch++)
#pragma unroll
        for (int r = 0; r < 4; r++) p[ch][r] = exp2f(sacc[ch][qh][r] - mrun[qh]);
      float ls = ((p[0][0] + p[0][1]) + (p[0][2] + p[0][3]))
               + ((p[1][0] + p[1][1]) + (p[1][2] + p[1][3]));
      ls += __shfl_xor(ls, 16, 64);
      ls += __shfl_xor(ls, 32, 64);
      lrun[qh] += ls;
      // lane (g,lr) holds P[q=lr+16qh][kv=16ch+4g+r]; B-frag needs kv=8g+j.
      // 4-lane-group permute: sA = 32*(g&1)+lr gives j0..3, sB=sA+16 j4..7, ch=g>>1
      u32 pw00 = pack2bf(p[0][0], p[0][1]);
      u32 pw01 = pack2bf(p[0][2], p[0][3]);
      u32 pw10 = pack2bf(p[1][0], p[1][1]);
      u32 pw11 = pack2bf(p[1][2], p[1][3]);
      int sA = ((g & 1) << 5) + lr;
      int sB = sA + 16;
      u32 a0 = (u32)__shfl((int)pw00, sA, 64);
      u32 a1 = (u32)__shfl((int)pw01, sA, 64);
      u32 a2 = (u32)__shfl((int)pw10, sA, 64);
      u32 a3 = (u32)__shfl((int)pw11, sA, 64);
      u32 b0 = (u32)__shfl((int)pw00, sB, 64);
      u32 b1 = (u32)__shfl((int)pw01, sB, 64);
      u32 b2 = (u32)__shfl((int)pw10, sB, 64);
      u32 b3 = (u32)__shfl((int)pw11, sB, 64);
      bool hi = (g >= 2);
      bpq[qh] = mk8(hi ? a2 : a0, hi ? a3 : a1, hi ? b2 : b0, hi ? b3 : b1);
    }

    // ---- O^T += Xt-frag (LDS swz) x P^T (regs), 2 halves to cap liveness ----
    __builtin_amdgcn_s_setprio(1);
#pragma unroll
    for (int half = 0; half < 2; half++){
      s16x8 ax[4];
#pragma unroll
      for (int i = 0; i < 4; i++){
        int row = (half*4 + i)*16 + lr;
        int phys = row*64 + ((g*16) ^ ((row & 3) << 4));
        ax[i] = *(const s16x8*)((const char*)&sxt[0] + phys);
      }
#pragma unroll
      for (int i = 0; i < 4; i++){
        int dg = half*4 + i;
        o[dg][0] = MFMA16(ax[i], bpq[0], o[dg][0]);
        o[dg][1] = MFMA16(ax[i], bpq[1], o[dg][1]);
      }
    }
    __builtin_amdgcn_s_setprio(0);
    __syncthreads();                 // all waves done reading sxt + hbuf[cur]
    if (t + 1 < ntiles){
      stage_t(t + 1);                // overwrite sxt (safe after barrier)
      __syncthreads();               // implicit vmcnt(0): sxt complete for t+1
    }
  }

  // ---- epilogue: O^T lane holds (d = dg*16+4g+r, q = qh*16+lr) ----
  if (KS == 1){
#pragma unroll
    for (int qh = 0; qh < 2; qh++){
      float inv = 1.f / lrun[qh];
      long q = qrow + qh*16 + lr;
#pragma unroll
      for (int dg = 0; dg < 8; dg++){
        u32x2 pw;
        pw[0] = pack2bf(o[dg][qh][0]*inv, o[dg][qh][1]*inv);
        pw[1] = pack2bf(o[dg][qh][2]*inv, o[dg][qh][3]*inv);
        *(u32x2*)(A1bf + q*128 + dg*16 + 4*g) = pw;
      }
    }
  } else {
    const long pid = bid;
#pragma unroll
    for (int qh = 0; qh < 2; qh++){
      int lq = w*32 + qh*16 + lr;
#pragma unroll
      for (int dg = 0; dg < 8; dg++){
        u32x2 pw;
        pw[0] = pack2bf(o[dg][qh][0], o[dg][qh][1]);
        pw[1] = pack2bf(o[dg][qh][2], o[dg][qh][3]);
        *(u32x2*)(Opart + pid*16384 + (long)lq*128 + dg*16 + 4*g) = pw;
      }
      if (g == 0){
        mpart[pid*128 + lq] = mrun[qh];
        lpart[pid*128 + lq] = lrun[qh];
      }
    }
  }
}

// ---------------------------------------------------------------------------
// K4: merge kv-split partials (bf16 Opart) -> normalized A1 (bf16).
//     grid 2048 x 8 rows (grid-stride over 4 passes).
// ---------------------------------------------------------------------------
__global__ __launch_bounds__(256) void k_merge(
    const u16* __restrict__ Opart, const float* __restrict__ mpart, const float* __restrict__ lpart,
    u16* __restrict__ A1bf, int KS)
{
  const int tid = threadIdx.x, bid = blockIdx.x;
  const int d = tid & 127;
#pragma unroll
  for (int pass = 0; pass < 4; pass++){
    const long R = (long)bid*8 + pass*2 + (tid >> 7);
    const int qb = (int)(R >> 7), r = (int)(R & 127);
    const int pbase = (qb >> 4);               // batch bits (bid & 7)
    const int qblk  = (qb & 15);
    float m = -1e30f;
    for (int s = 0; s < KS; s++){
      long pid = (long)((qblk*KS + s)*8 + pbase);
      m = fmaxf(m, mpart[pid*128 + r]);
    }
    float acc = 0.f, ls = 0.f;
    for (int s = 0; s < KS; s++){
      long pid = (long)((qblk*KS + s)*8 + pbase);
      float wgt = exp2f(mpart[pid*128 + r] - m);
      ls  += lpart[pid*128 + r] * wgt;
      acc += bf2f(Opart[pid*16384 + (long)r*128 + d]) * wgt;
    }
    A1bf[R*128 + d] = f2bf(acc / ls);
  }
}

// ---------------------------------------------------------------------------
// K5: x1 = relu(A1 @ w1 + x)  (bf16 MFMA, fp32 out)
// ---------------------------------------------------------------------------
__global__ __launch_bounds__(128, 2) void k_layer1(
    const u16* __restrict__ A1bf, const u16* __restrict__ w1t,
    const float* __restrict__ x, float* __restrict__ x1)
{
  __shared__ u16 sb[16384];
  const int tid = threadIdx.x, bid = blockIdx.x;
#pragma unroll
  for (int k = 0; k < 16; k++){
    int off = (tid + k*128)*16;
    int row = off >> 8;
    *(s16x8*)((char*)sb + (off ^ ((row & 7) << 4))) = *(const s16x8*)((const char*)w1t + off);
  }
  __syncthreads();
  const int w = tid >> 6, lane = tid & 63, lr = lane & 15, g = lane >> 4;
  const long rowbase = (long)bid*64 + w*32;
  s16x8 aa[2][4];
#pragma unroll
  for (int rh = 0; rh < 2; rh++)
#pragma unroll
    for (int kc = 0; kc < 4; kc++)
      aa[rh][kc] = *(const s16x8*)(A1bf + (rowbase + rh*16 + lr)*128 + kc*32 + g*8);
  f32x4 acc[2][8];
#pragma unroll
  for (int rh = 0; rh < 2; rh++)
#pragma unroll
    for (int cg = 0; cg < 8; cg++) acc[rh][cg] = f4zero();
  const int swz = (lr & 7) << 4;
#pragma unroll
  for (int cg = 0; cg < 8; cg++){
    const int rowt = (cg*16 + lr)*256;
#pragma unroll
    for (int kc = 0; kc < 4; kc++){
      s16x8 bb = *(const s16x8*)((const char*)sb + rowt + ((kc*64 + g*16) ^ swz));
#pragma unroll
      for (int rh = 0; rh < 2; rh++)
        acc[rh][cg] = MFMA16(aa[rh][kc], bb, acc[rh][cg]);
    }
  }
#pragma unroll
  for (int rh = 0; rh < 2; rh++)
#pragma unroll
    for (int cg = 0; cg < 8; cg++)
#pragma unroll
      for (int r = 0; r < 4; r++){
        long q = rowbase + rh*16 + 4*g + r;
        int  c = cg*16 + lr;
        float v = acc[rh][cg][r] + x[q*128 + c];
        x1[q*128 + c] = fmaxf(v, 0.f);
      }
}

// ---------------------------------------------------------------------------
// K6: A2 partials with unnormalized softmax weights.
//   A2p[b,j,:] = sum_{m in chunk j} exp(S0[b,m]-M_b) * x1[b,m,:]
//   Lj[b*8+j]  = sum_{m in chunk j} exp(S0[b,m]-M_b)
// ---------------------------------------------------------------------------
__global__ __launch_bounds__(256) void k_a2(
    const float* __restrict__ S0, const float* __restrict__ maxpart,
    const float* __restrict__ x1, float* __restrict__ A2p, float* __restrict__ Lj)
{
  __shared__ float red[128];
  __shared__ float lred[2];
  const int tid = threadIdx.x, bid = blockIdx.x;
  const int b = bid >> 3, j = bid & 7;
  const int d = tid & 127, h = tid >> 7;
  float M = -1e30f;
#pragma unroll
  for (int jj = 0; jj < 8; jj++) M = fmaxf(M, maxpart[b*8 + jj]);
  float acc = 0.f, lacc = 0.f;
  for (int mi = j*256 + h; mi < j*256 + 256; mi += 2){
    float e = __expf(S0[b*2048 + mi] - M);
    acc  += e * x1[((long)b*2048 + mi)*128 + d];
    lacc += e;
  }
  if (h == 1) red[d] = acc;
  if (d == 0) lred[h] = lacc;
  __syncthreads();
  if (h == 0) A2p[(long)bid*128 + d] = acc + red[d];
  if (tid == 0) Lj[bid] = lred[0] + lred[1];
}

// K7: out = relu((A2/L) @ w2 + x1[:,0,:])
__global__ __launch_bounds__(256) void k_out(
    const float* __restrict__ A2p, const float* __restrict__ Lj,
    const float* __restrict__ w2, const float* __restrict__ x1,
    float* __restrict__ out)
{
  __shared__ float a2s[2][128];
  const int tid = threadIdx.x, bid = blockIdx.x;
  const int b0 = bid*2;
  {
    int which = tid >> 7, f = tid & 127;
    int bb = b0 + which;
    float s = 0.f, L = 0.f;
#pragma unroll
    for (int jj = 0; jj < 8; jj++){
      s += A2p[(long)(bb*8 + jj)*128 + f];
      L += Lj[bb*8 + jj];
    }
    a2s[which][f] = s / L;
  }
  __syncthreads();
  const int which = tid >> 7, d = tid & 127;
  const int b = b0 + which;
  float acc = x1[(long)b*262144 + d];
  for (int f = 0; f < 128; f++)
    acc += a2s[which][f] * w2[f*128 + d];
  out[b*128 + d] = fmaxf(acc, 0.f);
}

// ---------------------------------------------------------------------------
extern "C" void kernel_launch(void* const* d_in, const int* in_sizes, int n_in,
                              void* d_out, int out_size, void* d_ws, size_t ws_size,
                              hipStream_t stream)
{
  const float* x  = (const float*)d_in[0];
  const float* w1 = (const float*)d_in[1];
  const float* w2 = (const float*)d_in[2];
  const float* wr = (const float*)d_in[3];
  float* out = (float*)d_out;
  char* ws = (char*)d_ws;

  u16*   xh      = (u16*)  (ws + 0);
  u16*   xl      = (u16*)  (ws + 4194304);
  u16*   Xt      = (u16*)  (ws + 8388608);
  u16*   yh      = (u16*)  (ws + 12582912);
  u16*   yl      = (u16*)  (ws + 16777216);
  u16*   wrth    = (u16*)  (ws + 20971520);
  u16*   wrtl    = (u16*)  (ws + 21004288);
  u16*   w1t     = (u16*)  (ws + 21037056);
  u16*   A1bf    = (u16*)  (ws + 21069824);
  float* Lj      = (float*)(ws + 25264128);
  float* S0      = (float*)(ws + 25329664);
  float* maxpart = (float*)(ws + 25395200);
  float* A2p     = (float*)(ws + 25396224);
  // flash partials live in [tail, ...) and are DEAD before x1 is written,
  // so x1 aliases the same region (written by k_layer1 after k_merge).
  const size_t tail = 25428992;

  int KS = 8, kslog = 3;
  // per-KS bytes: mpart 64K + lpart 64K + Opart bf16 (128*16384*2)=4M => 4325376
  while (KS > 1 && tail + (size_t)KS*4325376ull > ws_size){ KS >>= 1; kslog--; }
  float* mpart = (float*)(ws + tail);
  float* lpart = (float*)(ws + tail + (size_t)KS*65536);
  u16*   Opart = (u16*)  (ws + tail + (size_t)KS*131072);
  float* x1    = (float*)(ws + tail);          // aliases mpart/lpart/Opart (dead)

  k_prep  <<<1104, 256, 0, stream>>>(x, wr, w1, xh, xl, Xt, wrth, wrtl, w1t, S0, maxpart);
  k_ygemm <<<256, 128, 0, stream>>>(xh, xl, wrth, wrtl, yh, yl);
  k_flash <<<128*KS, 256, 0, stream>>>(xh, xl, Xt, yh, yl, A1bf, Opart, mpart, lpart, KS, kslog);
  if (KS > 1)
    k_merge <<<2048, 256, 0, stream>>>(Opart, mpart, lpart, A1bf, KS);
  k_layer1<<<256, 128, 0, stream>>>(A1bf, w1t, x, x1);
  k_a2    <<<64, 256, 0, stream>>>(S0, maxpart, x1, A2p, Lj);
  k_out   <<<4, 256, 0, stream>>>(A2p, Lj, w2, x1, out);
}

// Round 7
// 151.792 us; speedup vs baseline: 2.2945x; 2.2945x over previous
//
#include <hip/hip_runtime.h>
#include <stdint.h>

typedef float  f32x4 __attribute__((ext_vector_type(4)));
typedef short  s16x8 __attribute__((ext_vector_type(8)));
typedef unsigned int u32;
typedef u32    u32x2 __attribute__((ext_vector_type(2)));
typedef u32    u32x4 __attribute__((ext_vector_type(4)));
typedef unsigned short u16;

#define MFMA16(a,b,c) __builtin_amdgcn_mfma_f32_16x16x32_bf16((a),(b),(c),0,0,0)

__device__ __forceinline__ u16 f2bf(float f){
  u32 u = __float_as_uint(f);
  return (u16)((u + 0x7fffu + ((u >> 16) & 1u)) >> 16);   // RNE
}
__device__ __forceinline__ float bf2f(u16 h){ return __uint_as_float(((u32)h) << 16); }
__device__ __forceinline__ u32 pack2bf(float a, float b){ return (u32)f2bf(a) | ((u32)f2bf(b) << 16); }
__device__ __forceinline__ f32x4 f4zero(){ f32x4 z; z[0]=0.f; z[1]=0.f; z[2]=0.f; z[3]=0.f; return z; }
// register-only vector build (NO union: unions can defeat SROA -> scratch)
__device__ __forceinline__ s16x8 mk8(u32 a, u32 b, u32 c, u32 d){
  u32x4 w; w[0]=a; w[1]=b; w[2]=c; w[3]=d;
  return __builtin_bit_cast(s16x8, w);
}

// async global->LDS, 16B per lane; LDS dest is wave-uniform base + lane*16
__device__ __forceinline__ void async16(const void* g, void* l){
  __builtin_amdgcn_global_load_lds(
      (const __attribute__((address_space(1))) unsigned int*)g,
      (__attribute__((address_space(3))) unsigned int*)l, 16, 0, 0);
}

// ---------------------------------------------------------------------------
// K1 (fused): blocks [0,1024): split x -> xh/xl + build Xt
//             blocks [1024,1032): wr^T hi/lo   [1032,1040): w1^T
//             blocks [1040,1104): row-0 exact fp32 logits S0 + maxpart
// ---------------------------------------------------------------------------
__global__ __launch_bounds__(256) void k_prep(
    const float* __restrict__ x, const float* __restrict__ wr, const float* __restrict__ w1,
    u16* __restrict__ xh, u16* __restrict__ xl, u16* __restrict__ Xt,
    u16* __restrict__ wrth, u16* __restrict__ wrtl, u16* __restrict__ w1t,
    float* __restrict__ S0, float* __restrict__ maxpart)
{
  __shared__ float xs[16][132];
  __shared__ float x0s[128];
  __shared__ float ys[128];
  __shared__ float red[256];
  const int tid = threadIdx.x, bid = blockIdx.x;
  if (bid < 1024){
    const long base = (long)bid * 2048;          // 16 rows * 128
#pragma unroll
    for (int k = 0; k < 8; k++){
      int idx = tid + k*256;
      float v = x[base + idx];
      xs[idx>>7][idx&127] = v;
      u16 h = f2bf(v);
      xh[base+idx] = h;
      xl[base+idx] = f2bf(v - bf2f(h));
    }
    __syncthreads();
    const int b  = bid >> 7;                     // 128 blocks per batch
    const int n0 = (bid & 127) * 16;
    const int nn = tid & 15, d0 = tid >> 4;
#pragma unroll
    for (int d = 0; d < 8; d++){
      int dd = d0 + d*16;
      Xt[(long)b*262144 + (long)dd*2048 + n0 + nn] = f2bf(xs[nn][dd]);
    }
  } else if (bid < 1032){
    const int base = (bid - 1024) * 2048;
#pragma unroll
    for (int k = 0; k < 8; k++){
      int idx = base + k*256 + tid;
      int g = idx >> 7, f = idx & 127;
      float v = wr[f*128 + g];                   // wrT[g][f] = wr[f][g]
      u16 h = f2bf(v);
      wrth[idx] = h;
      wrtl[idx] = f2bf(v - bf2f(h));
    }
  } else if (bid < 1040){
    const int base = (bid - 1032) * 2048;
#pragma unroll
    for (int k = 0; k < 8; k++){
      int idx = base + k*256 + tid;
      int c = idx >> 7, f = idx & 127;
      w1t[idx] = f2bf(w1[f*128 + c]);            // w1T[c][f] = w1[f][c]
    }
  } else {
    const int jj = bid - 1040;
    const int b = jj >> 3, j = jj & 7;
    if (tid < 128) x0s[tid] = x[(long)b*262144 + tid];
    __syncthreads();
    if (tid < 128){
      float a = 0.f;
      for (int f = 0; f < 128; f++) a += x0s[f] * wr[f*128 + tid];
      ys[tid] = a;
    }
    __syncthreads();
    const int m = j*256 + tid;
    const float4* xr = (const float4*)(x + ((long)b*2048 + m)*128);
    const float4* yv = (const float4*)ys;
    float acc = 0.f;
#pragma unroll
    for (int f = 0; f < 32; f++){
      float4 a = xr[f], c = yv[f];
      acc += a.x*c.x + a.y*c.y + a.z*c.z + a.w*c.w;
    }
    S0[b*2048 + m] = acc;
    red[tid] = acc;
    __syncthreads();
    for (int sft = 128; sft > 0; sft >>= 1){
      if (tid < sft) red[tid] = fmaxf(red[tid], red[tid + sft]);
      __syncthreads();
    }
    if (tid == 0) maxpart[jj] = red[0];
  }
}

// ---------------------------------------------------------------------------
// K2: y = (x @ wr) * log2(e)  via 3-term split bf16 MFMA; write yh/yl hi/lo
// ---------------------------------------------------------------------------
__global__ __launch_bounds__(128, 2) void k_ygemm(
    const u16* __restrict__ xh, const u16* __restrict__ xl,
    const u16* __restrict__ wrth, const u16* __restrict__ wrtl,
    u16* __restrict__ yh, u16* __restrict__ yl)
{
  __shared__ u16 sbh[16384], sbl[16384];       // [c][f] bf16, XOR-swizzled
  const int tid = threadIdx.x, bid = blockIdx.x;
#pragma unroll
  for (int k = 0; k < 16; k++){
    int off = (tid + k*128) * 16;
    int row = off >> 8;
    int dst = off ^ ((row & 7) << 4);
    *(s16x8*)((char*)sbh + dst) = *(const s16x8*)((const char*)wrth + off);
    *(s16x8*)((char*)sbl + dst) = *(const s16x8*)((const char*)wrtl + off);
  }
  __syncthreads();
  const int w = tid >> 6, lane = tid & 63, lr = lane & 15, g = lane >> 4;
  const long rowbase = (long)bid*64 + w*32;
  s16x8 ah[2][4], al[2][4];
#pragma unroll
  for (int rh = 0; rh < 2; rh++)
#pragma unroll
    for (int kc = 0; kc < 4; kc++){
      long r = rowbase + rh*16 + lr;
      ah[rh][kc] = *(const s16x8*)(xh + r*128 + kc*32 + g*8);
      al[rh][kc] = *(const s16x8*)(xl + r*128 + kc*32 + g*8);
    }
  f32x4 acc[2][8];
#pragma unroll
  for (int rh = 0; rh < 2; rh++)
#pragma unroll
    for (int cg = 0; cg < 8; cg++) acc[rh][cg] = f4zero();
  const int swz = (lr & 7) << 4;
#pragma unroll
  for (int cg = 0; cg < 8; cg++){
    const int rowt = (cg*16 + lr) * 256;
#pragma unroll
    for (int kc = 0; kc < 4; kc++){
      int boff = rowt + ((kc*64 + g*16) ^ swz);
      s16x8 bh = *(const s16x8*)((const char*)sbh + boff);
      s16x8 bl = *(const s16x8*)((const char*)sbl + boff);
#pragma unroll
      for (int rh = 0; rh < 2; rh++){
        acc[rh][cg] = MFMA16(ah[rh][kc], bh, acc[rh][cg]);
        acc[rh][cg] = MFMA16(al[rh][kc], bh, acc[rh][cg]);
        acc[rh][cg] = MFMA16(ah[rh][kc], bl, acc[rh][cg]);
      }
    }
  }
#pragma unroll
  for (int rh = 0; rh < 2; rh++)
#pragma unroll
    for (int cg = 0; cg < 8; cg++)
#pragma unroll
      for (int r = 0; r < 4; r++){
        long q = rowbase + rh*16 + 4*g + r;    // C-layout: row=(l>>4)*4+reg
        int  c = cg*16 + lr;                   //           col=l&15
        float v = acc[rh][cg][r] * 1.4426950408889634f;
        u16 h = f2bf(v);
        yh[q*128 + c] = h;
        yl[q*128 + c] = f2bf(v - bf2f(h));
      }
}

// ---------------------------------------------------------------------------
// K3: fused flash (round-5 verified body: launch_bounds(256,2), VGPR 112,
//     double-buffered sxh/sxl/sxt, 48KB LDS -> 3 blocks/CU).
//   Occupancy raised the SAFE way: KS=8 -> 1024 blocks; Opart in bf16.
//   DO NOT cap VGPR below ~130: (256,3)/(256,4) caused scratch spills
//   (rounds 2/4/6: phantom 120-700MB HBM writes).
// ---------------------------------------------------------------------------
__global__ __launch_bounds__(256, 2) void k_flash(
    const u16* __restrict__ xh, const u16* __restrict__ xl, const u16* __restrict__ Xt,
    const u16* __restrict__ yh, const u16* __restrict__ yl,
    u16* __restrict__ A1bf,
    u16* __restrict__ Opart, float* __restrict__ mpart, float* __restrict__ lpart,
    int KS, int kslog)
{
  __shared__ u16 sxh[2][4096], sxl[2][4096];   // 32kv x 128f, XOR-swz (row&7)
  __shared__ u16 sxt[2][4096];                 // 128d x 32kv, XOR-swz (row&3)
  const int tid = threadIdx.x, bid = blockIdx.x;
  const int b     = bid & 7;                   // XCD b owns batch b
  const int inner = bid >> 3;
  const int s     = inner & (KS - 1);
  const int qbl   = inner >> kslog;
  const int qb    = b*16 + qbl;
  const int nspan = 2048 >> kslog;
  const int kv0   = s * nspan;
  const int ntiles = nspan >> 5;
  const int w = tid >> 6, lane = tid & 63, lr = lane & 15, g = lane >> 4;
  const long qrow = (long)qb*128 + w*32;

  // Y fragments (B-operands), hi/lo — per-warp constants
  s16x8 byh[2][4], byl[2][4];
#pragma unroll
  for (int qh = 0; qh < 2; qh++)
#pragma unroll
    for (int kc = 0; kc < 4; kc++){
      long r = qrow + qh*16 + lr;
      byh[qh][kc] = *(const s16x8*)(yh + r*128 + kc*32 + g*8);
      byl[qh][kc] = *(const s16x8*)(yl + r*128 + kc*32 + g*8);
    }

  f32x4 o[8][2];                               // O^T: [d-tile dg][q-half qh]
#pragma unroll
  for (int dg = 0; dg < 8; dg++){ o[dg][0] = f4zero(); o[dg][1] = f4zero(); }
  float mrun[2] = {-1e30f, -1e30f}, lrun[2] = {0.f, 0.f};

  const char* gxh  = (const char*)xh + ((long)b*2048 + kv0)*256;
  const char* gxl  = (const char*)xl + ((long)b*2048 + kv0)*256;
  const char* gxtb = (const char*)(Xt + (long)b*262144 + kv0);

  auto stage = [&](int bufi, int t){
#pragma unroll
    for (int c2 = 0; c2 < 2; c2++){
      int chunk = w*2 + c2;
      int off = chunk*1024 + lane*16;
      {  // x tiles: rows of 256B (16 granules), swizzle by row&7
        int row = off >> 8;
        int swo = off ^ ((row & 7) << 4);
        async16(gxh + (long)t*8192 + swo, &sxh[bufi][chunk*512]);
        async16(gxl + (long)t*8192 + swo, &sxl[bufi][chunk*512]);
      }
      {  // xt tile: rows of 64B (4 granules), swizzle by row&3 ONLY
        int row = off >> 6;
        int col = off & 63;
        int src = row*4096 + (col ^ ((row & 3) << 4));
        async16(gxtb + (long)t*64 + src, &sxt[bufi][chunk*512]);
      }
    }
  };

  stage(0, 0);
  __syncthreads();

  for (int t = 0; t < ntiles; t++){
    const int cur = t & 1;
    if (t + 1 < ntiles) stage(cur ^ 1, t + 1);
    const char* pxh = (const char*)&sxh[cur][0];
    const char* pxl = (const char*)&sxl[cur][0];

    // ---- S^T tile [32kv x 32q], 3-term hi/lo split ----
    f32x4 sacc[2][2];                          // [kv-half ch][q-half qh]
    sacc[0][0] = f4zero(); sacc[0][1] = f4zero();
    sacc[1][0] = f4zero(); sacc[1][1] = f4zero();
    __builtin_amdgcn_s_setprio(1);
#pragma unroll
    for (int ch = 0; ch < 2; ch++){
      const int rowb = ch*16 + lr;
#pragma unroll
      for (int kc = 0; kc < 4; kc++){
        const int boff = rowb*256 + ((kc*64 + g*16) ^ ((rowb & 7) << 4));
        s16x8 fh = *(const s16x8*)(pxh + boff);
        s16x8 fl = *(const s16x8*)(pxl + boff);
#pragma unroll
        for (int qh = 0; qh < 2; qh++){
          sacc[ch][qh] = MFMA16(fh, byh[qh][kc], sacc[ch][qh]);
          sacc[ch][qh] = MFMA16(fl, byh[qh][kc], sacc[ch][qh]);
          sacc[ch][qh] = MFMA16(fh, byl[qh][kc], sacc[ch][qh]);
        }
      }
    }
    __builtin_amdgcn_s_setprio(0);

    // ---- lane-local online softmax + in-register P^T redistribution ----
    s16x8 bpq[2];
#pragma unroll
    for (int qh = 0; qh < 2; qh++){
      float cm = fmaxf(fmaxf(fmaxf(sacc[0][qh][0], sacc[0][qh][1]),
                             fmaxf(sacc[0][qh][2], sacc[0][qh][3])),
                       fmaxf(fmaxf(sacc[1][qh][0], sacc[1][qh][1]),
                             fmaxf(sacc[1][qh][2], sacc[1][qh][3])));
      cm = fmaxf(cm, __shfl_xor(cm, 16, 64));
      cm = fmaxf(cm, __shfl_xor(cm, 32, 64));
      if (__any(cm > mrun[qh] + 8.f)){         // defer-max (log2 units, P<=256)
        float mn = fmaxf(mrun[qh], cm);
        float sc = exp2f(mrun[qh] - mn);
#pragma unroll
        for (int dg = 0; dg < 8; dg++)
#pragma unroll
          for (int r = 0; r < 4; r++) o[dg][qh][r] *= sc;
        lrun[qh] *= sc;
        mrun[qh] = mn;
      }
      float p[2][4];
#pragma unroll
      for (int ch = 0; ch < 2; ch++)
#pragma unroll
        for (int r = 0; r < 4; r++) p[ch][r] = exp2f(sacc[ch][qh][r] - mrun[qh]);
      float ls = ((p[0][0] + p[0][1]) + (p[0][2] + p[0][3]))
               + ((p[1][0] + p[1][1]) + (p[1][2] + p[1][3]));
      ls += __shfl_xor(ls, 16, 64);
      ls += __shfl_xor(ls, 32, 64);
      lrun[qh] += ls;
      // lane (g,lr) holds P[q=lr+16qh][kv=16ch+4g+r]; B-frag needs kv=8g+j.
      // 4-lane-group permute: sA = 32*(g&1)+lr gives j0..3, sB=sA+16 j4..7, ch=g>>1
      u32 pw00 = pack2bf(p[0][0], p[0][1]);
      u32 pw01 = pack2bf(p[0][2], p[0][3]);
      u32 pw10 = pack2bf(p[1][0], p[1][1]);
      u32 pw11 = pack2bf(p[1][2], p[1][3]);
      int sA = ((g & 1) << 5) + lr;
      int sB = sA + 16;
      u32 a0 = (u32)__shfl((int)pw00, sA, 64);
      u32 a1 = (u32)__shfl((int)pw01, sA, 64);
      u32 a2 = (u32)__shfl((int)pw10, sA, 64);
      u32 a3 = (u32)__shfl((int)pw11, sA, 64);
      u32 b0 = (u32)__shfl((int)pw00, sB, 64);
      u32 b1 = (u32)__shfl((int)pw01, sB, 64);
      u32 b2 = (u32)__shfl((int)pw10, sB, 64);
      u32 b3 = (u32)__shfl((int)pw11, sB, 64);
      bool hi = (g >= 2);
      bpq[qh] = mk8(hi ? a2 : a0, hi ? a3 : a1, hi ? b2 : b0, hi ? b3 : b1);
    }

    // ---- O^T += Xt-frag (LDS swz) x P^T (regs), 2 halves to cap liveness ----
    __builtin_amdgcn_s_setprio(1);
#pragma unroll
    for (int half = 0; half < 2; half++){
      s16x8 ax[4];
#pragma unroll
      for (int i = 0; i < 4; i++){
        int row = (half*4 + i)*16 + lr;
        int phys = row*64 + ((g*16) ^ ((row & 3) << 4));
        ax[i] = *(const s16x8*)((const char*)&sxt[cur][0] + phys);
      }
#pragma unroll
      for (int i = 0; i < 4; i++){
        int dg = half*4 + i;
        o[dg][0] = MFMA16(ax[i], bpq[0], o[dg][0]);
        o[dg][1] = MFMA16(ax[i], bpq[1], o[dg][1]);
      }
    }
    __builtin_amdgcn_s_setprio(0);
    __syncthreads();   // drains prefetch + guards buffer reuse
  }

  // ---- epilogue: O^T lane holds (d = dg*16+4g+r, q = qh*16+lr) ----
  if (KS == 1){
#pragma unroll
    for (int qh = 0; qh < 2; qh++){
      float inv = 1.f / lrun[qh];
      long q = qrow + qh*16 + lr;
#pragma unroll
      for (int dg = 0; dg < 8; dg++){
        u32x2 pw;
        pw[0] = pack2bf(o[dg][qh][0]*inv, o[dg][qh][1]*inv);
        pw[1] = pack2bf(o[dg][qh][2]*inv, o[dg][qh][3]*inv);
        *(u32x2*)(A1bf + q*128 + dg*16 + 4*g) = pw;
      }
    }
  } else {
    const long pid = bid;
#pragma unroll
    for (int qh = 0; qh < 2; qh++){
      int lq = w*32 + qh*16 + lr;
#pragma unroll
      for (int dg = 0; dg < 8; dg++){
        u32x2 pw;
        pw[0] = pack2bf(o[dg][qh][0], o[dg][qh][1]);
        pw[1] = pack2bf(o[dg][qh][2], o[dg][qh][3]);
        *(u32x2*)(Opart + pid*16384 + (long)lq*128 + dg*16 + 4*g) = pw;
      }
      if (g == 0){
        mpart[pid*128 + lq] = mrun[qh];
        lpart[pid*128 + lq] = lrun[qh];
      }
    }
  }
}

// ---------------------------------------------------------------------------
// K4: merge kv-split partials (bf16 Opart) -> normalized A1 (bf16).
//     grid 2048, 4 passes of 2 rows each.
// ---------------------------------------------------------------------------
__global__ __launch_bounds__(256) void k_merge(
    const u16* __restrict__ Opart, const float* __restrict__ mpart, const float* __restrict__ lpart,
    u16* __restrict__ A1bf, int KS)
{
  const int tid = threadIdx.x, bid = blockIdx.x;
  const int d = tid & 127;
#pragma unroll
  for (int pass = 0; pass < 4; pass++){
    const long R = (long)bid*8 + pass*2 + (tid >> 7);
    const int qb = (int)(R >> 7), r = (int)(R & 127);
    const int pbase = (qb >> 4);               // batch bits (bid & 7)
    const int qblk  = (qb & 15);
    float m = -1e30f;
    for (int s = 0; s < KS; s++){
      long pid = (long)((qblk*KS + s)*8 + pbase);
      m = fmaxf(m, mpart[pid*128 + r]);
    }
    float acc = 0.f, ls = 0.f;
    for (int s = 0; s < KS; s++){
      long pid = (long)((qblk*KS + s)*8 + pbase);
      float wgt = exp2f(mpart[pid*128 + r] - m);
      ls  += lpart[pid*128 + r] * wgt;
      acc += bf2f(Opart[pid*16384 + (long)r*128 + d]) * wgt;
    }
    A1bf[R*128 + d] = f2bf(acc / ls);
  }
}

// ---------------------------------------------------------------------------
// K5: x1 = relu(A1 @ w1 + x)  (bf16 MFMA, fp32 out)
// ---------------------------------------------------------------------------
__global__ __launch_bounds__(128, 2) void k_layer1(
    const u16* __restrict__ A1bf, const u16* __restrict__ w1t,
    const float* __restrict__ x, float* __restrict__ x1)
{
  __shared__ u16 sb[16384];
  const int tid = threadIdx.x, bid = blockIdx.x;
#pragma unroll
  for (int k = 0; k < 16; k++){
    int off = (tid + k*128)*16;
    int row = off >> 8;
    *(s16x8*)((char*)sb + (off ^ ((row & 7) << 4))) = *(const s16x8*)((const char*)w1t + off);
  }
  __syncthreads();
  const int w = tid >> 6, lane = tid & 63, lr = lane & 15, g = lane >> 4;
  const long rowbase = (long)bid*64 + w*32;
  s16x8 aa[2][4];
#pragma unroll
  for (int rh = 0; rh < 2; rh++)
#pragma unroll
    for (int kc = 0; kc < 4; kc++)
      aa[rh][kc] = *(const s16x8*)(A1bf + (rowbase + rh*16 + lr)*128 + kc*32 + g*8);
  f32x4 acc[2][8];
#pragma unroll
  for (int rh = 0; rh < 2; rh++)
#pragma unroll
    for (int cg = 0; cg < 8; cg++) acc[rh][cg] = f4zero();
  const int swz = (lr & 7) << 4;
#pragma unroll
  for (int cg = 0; cg < 8; cg++){
    const int rowt = (cg*16 + lr)*256;
#pragma unroll
    for (int kc = 0; kc < 4; kc++){
      s16x8 bb = *(const s16x8*)((const char*)sb + rowt + ((kc*64 + g*16) ^ swz));
#pragma unroll
      for (int rh = 0; rh < 2; rh++)
        acc[rh][cg] = MFMA16(aa[rh][kc], bb, acc[rh][cg]);
    }
  }
#pragma unroll
  for (int rh = 0; rh < 2; rh++)
#pragma unroll
    for (int cg = 0; cg < 8; cg++)
#pragma unroll
      for (int r = 0; r < 4; r++){
        long q = rowbase + rh*16 + 4*g + r;
        int  c = cg*16 + lr;
        float v = acc[rh][cg][r] + x[q*128 + c];
        x1[q*128 + c] = fmaxf(v, 0.f);
      }
}

// ---------------------------------------------------------------------------
// K6: A2 partials with unnormalized softmax weights.
//   A2p[b,j,:] = sum_{m in chunk j} exp(S0[b,m]-M_b) * x1[b,m,:]
//   Lj[b*8+j]  = sum_{m in chunk j} exp(S0[b,m]-M_b)
// ---------------------------------------------------------------------------
__global__ __launch_bounds__(256) void k_a2(
    const float* __restrict__ S0, const float* __restrict__ maxpart,
    const float* __restrict__ x1, float* __restrict__ A2p, float* __restrict__ Lj)
{
  __shared__ float red[128];
  __shared__ float lred[2];
  const int tid = threadIdx.x, bid = blockIdx.x;
  const int b = bid >> 3, j = bid & 7;
  const int d = tid & 127, h = tid >> 7;
  float M = -1e30f;
#pragma unroll
  for (int jj = 0; jj < 8; jj++) M = fmaxf(M, maxpart[b*8 + jj]);
  float acc = 0.f, lacc = 0.f;
  for (int mi = j*256 + h; mi < j*256 + 256; mi += 2){
    float e = __expf(S0[b*2048 + mi] - M);
    acc  += e * x1[((long)b*2048 + mi)*128 + d];
    lacc += e;
  }
  if (h == 1) red[d] = acc;
  if (d == 0) lred[h] = lacc;
  __syncthreads();
  if (h == 0) A2p[(long)bid*128 + d] = acc + red[d];
  if (tid == 0) Lj[bid] = lred[0] + lred[1];
}

// K7: out = relu((A2/L) @ w2 + x1[:,0,:])
__global__ __launch_bounds__(256) void k_out(
    const float* __restrict__ A2p, const float* __restrict__ Lj,
    const float* __restrict__ w2, const float* __restrict__ x1,
    float* __restrict__ out)
{
  __shared__ float a2s[2][128];
  const int tid = threadIdx.x, bid = blockIdx.x;
  const int b0 = bid*2;
  {
    int which = tid >> 7, f = tid & 127;
    int bb = b0 + which;
    float s = 0.f, L = 0.f;
#pragma unroll
    for (int jj = 0; jj < 8; jj++){
      s += A2p[(long)(bb*8 + jj)*128 + f];
      L += Lj[bb*8 + jj];
    }
    a2s[which][f] = s / L;
  }
  __syncthreads();
  const int which = tid >> 7, d = tid & 127;
  const int b = b0 + which;
  float acc = x1[(long)b*262144 + d];
  for (int f = 0; f < 128; f++)
    acc += a2s[which][f] * w2[f*128 + d];
  out[b*128 + d] = fmaxf(acc, 0.f);
}

// ---------------------------------------------------------------------------
extern "C" void kernel_launch(void* const* d_in, const int* in_sizes, int n_in,
                              void* d_out, int out_size, void* d_ws, size_t ws_size,
                              hipStream_t stream)
{
  const float* x  = (const float*)d_in[0];
  const float* w1 = (const float*)d_in[1];
  const float* w2 = (const float*)d_in[2];
  const float* wr = (const float*)d_in[3];
  float* out = (float*)d_out;
  char* ws = (char*)d_ws;

  u16*   xh      = (u16*)  (ws + 0);
  u16*   xl      = (u16*)  (ws + 4194304);
  u16*   Xt      = (u16*)  (ws + 8388608);
  u16*   yh      = (u16*)  (ws + 12582912);
  u16*   yl      = (u16*)  (ws + 16777216);
  u16*   wrth    = (u16*)  (ws + 20971520);
  u16*   wrtl    = (u16*)  (ws + 21004288);
  u16*   w1t     = (u16*)  (ws + 21037056);
  u16*   A1bf    = (u16*)  (ws + 21069824);
  float* Lj      = (float*)(ws + 25264128);
  float* S0      = (float*)(ws + 25329664);
  float* maxpart = (float*)(ws + 25395200);
  float* A2p     = (float*)(ws + 25396224);
  // flash partials live in [tail, ...) and are DEAD before x1 is written,
  // so x1 aliases the same region (written by k_layer1 after k_merge).
  const size_t tail = 25428992;

  int KS = 8, kslog = 3;
  // per-KS bytes: mpart 64K + lpart 64K + Opart bf16 (128*16384*2)=4M => 4325376
  while (KS > 1 && tail + (size_t)KS*4325376ull > ws_size){ KS >>= 1; kslog--; }
  float* mpart = (float*)(ws + tail);
  float* lpart = (float*)(ws + tail + (size_t)KS*65536);
  u16*   Opart = (u16*)  (ws + tail + (size_t)KS*131072);
  float* x1    = (float*)(ws + tail);          // aliases mpart/lpart/Opart (dead)

  k_prep  <<<1104, 256, 0, stream>>>(x, wr, w1, xh, xl, Xt, wrth, wrtl, w1t, S0, maxpart);
  k_ygemm <<<256, 128, 0, stream>>>(xh, xl, wrth, wrtl, yh, yl);
  k_flash <<<128*KS, 256, 0, stream>>>(xh, xl, Xt, yh, yl, A1bf, Opart, mpart, lpart, KS, kslog);
  if (KS > 1)
    k_merge <<<2048, 256, 0, stream>>>(Opart, mpart, lpart, A1bf, KS);
  k_layer1<<<256, 128, 0, stream>>>(A1bf, w1t, x, x1);
  k_a2    <<<64, 256, 0, stream>>>(S0, maxpart, x1, A2p, Lj);
  k_out   <<<4, 256, 0, stream>>>(A2p, Lj, w2, x1, out);
}

// Round 9
// 133.667 us; speedup vs baseline: 2.6056x; 1.1356x over previous
//
#include <hip/hip_runtime.h>
#include <stdint.h>

typedef float  f32x4 __attribute__((ext_vector_type(4)));
typedef short  s16x8 __attribute__((ext_vector_type(8)));
typedef unsigned int u32;
typedef u32    u32x2 __attribute__((ext_vector_type(2)));
typedef u32    u32x4 __attribute__((ext_vector_type(4)));
typedef unsigned short u16;

#define MFMA16(a,b,c) __builtin_amdgcn_mfma_f32_16x16x32_bf16((a),(b),(c),0,0,0)

__device__ __forceinline__ u16 f2bf(float f){
  u32 u = __float_as_uint(f);
  return (u16)((u + 0x7fffu + ((u >> 16) & 1u)) >> 16);   // RNE
}
__device__ __forceinline__ float bf2f(u16 h){ return __uint_as_float(((u32)h) << 16); }
__device__ __forceinline__ u32 pack2bf(float a, float b){ return (u32)f2bf(a) | ((u32)f2bf(b) << 16); }
__device__ __forceinline__ f32x4 f4zero(){ f32x4 z; z[0]=0.f; z[1]=0.f; z[2]=0.f; z[3]=0.f; return z; }
// register-only vector build (NO union: unions can defeat SROA -> scratch)
__device__ __forceinline__ s16x8 mk8(u32 a, u32 b, u32 c, u32 d){
  u32x4 w; w[0]=a; w[1]=b; w[2]=c; w[3]=d;
  return __builtin_bit_cast(s16x8, w);
}

// async global->LDS, 16B per lane; LDS dest is wave-uniform base + lane*16
__device__ __forceinline__ void async16(const void* g, void* l){
  __builtin_amdgcn_global_load_lds(
      (const __attribute__((address_space(1))) unsigned int*)g,
      (__attribute__((address_space(3))) unsigned int*)l, 16, 0, 0);
}

// ---------------------------------------------------------------------------
// K1 mega-prep. Block ranges (one branch each, no cross-block deps):
//   [0,1024):    x -> xh/xl split + Xt transpose
//   [1024,1032): w1^T bf16
//   [1032,1096): exact fp32 row-0 logits S0 + per-chunk maxpart
//   [1096,1224): ygemm: y = (x @ wr)*log2e, 3-term split from RAW fp32 x/wr
//   smem = 64 KB: the ygemm branch needs TWO 32 KB wr^T tables (hi+lo).
//   (Round-8 bug: carved them from 33 KB with sbl=sbh+8192 -> LDS overflow.)
// ---------------------------------------------------------------------------
__global__ __launch_bounds__(256) void k_prep(
    const float* __restrict__ x, const float* __restrict__ wr, const float* __restrict__ w1,
    u16* __restrict__ xh, u16* __restrict__ xl, u16* __restrict__ Xt,
    u16* __restrict__ w1t, float* __restrict__ S0, float* __restrict__ maxpart,
    u16* __restrict__ yh, u16* __restrict__ yl)
{
  __shared__ __align__(16) char smem[65536];
  const int tid = threadIdx.x, bid = blockIdx.x;

  if (bid < 1024){
    float (*xs)[132] = (float(*)[132])smem;
    const long base = (long)bid * 2048;          // 16 rows * 128
#pragma unroll
    for (int k = 0; k < 8; k++){
      int idx = tid + k*256;
      float v = x[base + idx];
      xs[idx>>7][idx&127] = v;
      u16 h = f2bf(v);
      xh[base+idx] = h;
      xl[base+idx] = f2bf(v - bf2f(h));
    }
    __syncthreads();
    const int b  = bid >> 7;                     // 128 blocks per batch
    const int n0 = (bid & 127) * 16;
    const int nn = tid & 15, d0 = tid >> 4;
#pragma unroll
    for (int d = 0; d < 8; d++){
      int dd = d0 + d*16;
      Xt[(long)b*262144 + (long)dd*2048 + n0 + nn] = f2bf(xs[nn][dd]);
    }
  } else if (bid < 1032){
    const int base = (bid - 1024) * 2048;
#pragma unroll
    for (int k = 0; k < 8; k++){
      int idx = base + k*256 + tid;
      int c = idx >> 7, f = idx & 127;
      w1t[idx] = f2bf(w1[f*128 + c]);            // w1T[c][f] = w1[f][c]
    }
  } else if (bid < 1096){
    float* x0s = (float*)smem;                   // 128
    float* ys  = x0s + 128;                      // 128
    float* red = ys + 128;                       // 256
    const int jj = bid - 1032;
    const int b = jj >> 3, j = jj & 7;
    if (tid < 128) x0s[tid] = x[(long)b*262144 + tid];
    __syncthreads();
    if (tid < 128){
      float a = 0.f;
      for (int f = 0; f < 128; f++) a += x0s[f] * wr[f*128 + tid];
      ys[tid] = a;
    }
    __syncthreads();
    const int m = j*256 + tid;
    const float4* xr = (const float4*)(x + ((long)b*2048 + m)*128);
    const float4* yv = (const float4*)ys;
    float acc = 0.f;
#pragma unroll
    for (int f = 0; f < 32; f++){
      float4 a = xr[f], c = yv[f];
      acc += a.x*c.x + a.y*c.y + a.z*c.z + a.w*c.w;
    }
    S0[b*2048 + m] = acc;
    red[tid] = acc;
    __syncthreads();
    for (int sft = 128; sft > 0; sft >>= 1){
      if (tid < sft) red[tid] = fmaxf(red[tid], red[tid + sft]);
      __syncthreads();
    }
    if (tid == 0) maxpart[jj] = red[0];
  } else {
    // ---- fused ygemm: 128 blocks x 256 thr (4 warps), 128 rows/block ----
    u16* sbh = (u16*)smem;                       // [c][f] bf16 swizzled, 32 KB
    u16* sbl = sbh + 16384;                      // +16384 u16 = +32 KB
    // stage wr^T hi/lo into LDS (self-converted from fp32)
    {
      const int c = tid & 127, f0 = (tid >> 7) * 64;
      const int key = (c & 7) << 4;
#pragma unroll
      for (int fi = 0; fi < 64; fi += 2){
        int f = f0 + fi;
        float v0 = wr[f*128 + c], v1 = wr[(f+1)*128 + c];
        u16 h0 = f2bf(v0), h1 = f2bf(v1);
        u32 hw = (u32)h0 | ((u32)h1 << 16);
        u32 lw = (u32)f2bf(v0 - bf2f(h0)) | ((u32)f2bf(v1 - bf2f(h1)) << 16);
        int byte = c*256 + ((((2*f) & ~15) ^ key) + ((2*f) & 15));
        *(u32*)((char*)sbh + byte) = hw;
        *(u32*)((char*)sbl + byte) = lw;
      }
    }
    __syncthreads();
    const int w = tid >> 6, lane = tid & 63, lr = lane & 15, g = lane >> 4;
    const long rowbase = (long)(bid - 1096)*128 + w*32;
    s16x8 ah[2][4], al[2][4];
#pragma unroll
    for (int rh = 0; rh < 2; rh++)
#pragma unroll
      for (int kc = 0; kc < 4; kc++){
        long r = rowbase + rh*16 + lr;
        const float4* px = (const float4*)(x + r*128 + kc*32 + g*8);
        float4 a = px[0], bV = px[1];
        u32 hh0, hh1, hh2, hh3, ll0, ll1, ll2, ll3;
        { u16 p=f2bf(a.x), q=f2bf(a.y); hh0=(u32)p|((u32)q<<16);
          ll0=(u32)f2bf(a.x-bf2f(p))|((u32)f2bf(a.y-bf2f(q))<<16); }
        { u16 p=f2bf(a.z), q=f2bf(a.w); hh1=(u32)p|((u32)q<<16);
          ll1=(u32)f2bf(a.z-bf2f(p))|((u32)f2bf(a.w-bf2f(q))<<16); }
        { u16 p=f2bf(bV.x), q=f2bf(bV.y); hh2=(u32)p|((u32)q<<16);
          ll2=(u32)f2bf(bV.x-bf2f(p))|((u32)f2bf(bV.y-bf2f(q))<<16); }
        { u16 p=f2bf(bV.z), q=f2bf(bV.w); hh3=(u32)p|((u32)q<<16);
          ll3=(u32)f2bf(bV.z-bf2f(p))|((u32)f2bf(bV.w-bf2f(q))<<16); }
        ah[rh][kc] = mk8(hh0,hh1,hh2,hh3);
        al[rh][kc] = mk8(ll0,ll1,ll2,ll3);
      }
    f32x4 acc[2][8];
#pragma unroll
    for (int rh = 0; rh < 2; rh++)
#pragma unroll
      for (int cg = 0; cg < 8; cg++) acc[rh][cg] = f4zero();
    const int swz = (lr & 7) << 4;
#pragma unroll
    for (int cg = 0; cg < 8; cg++){
      const int rowt = (cg*16 + lr) * 256;
#pragma unroll
      for (int kc = 0; kc < 4; kc++){
        int boff = rowt + ((kc*64 + g*16) ^ swz);
        s16x8 bh = *(const s16x8*)((const char*)sbh + boff);
        s16x8 bl = *(const s16x8*)((const char*)sbl + boff);
#pragma unroll
        for (int rh = 0; rh < 2; rh++){
          acc[rh][cg] = MFMA16(ah[rh][kc], bh, acc[rh][cg]);
          acc[rh][cg] = MFMA16(al[rh][kc], bh, acc[rh][cg]);
          acc[rh][cg] = MFMA16(ah[rh][kc], bl, acc[rh][cg]);
        }
      }
    }
#pragma unroll
    for (int rh = 0; rh < 2; rh++)
#pragma unroll
      for (int cg = 0; cg < 8; cg++)
#pragma unroll
        for (int r = 0; r < 4; r++){
          long q = rowbase + rh*16 + 4*g + r;  // C-layout: row=(l>>4)*4+reg
          int  c = cg*16 + lr;                 //           col=l&15
          float v = acc[rh][cg][r] * 1.4426950408889634f;
          u16 h = f2bf(v);
          yh[q*128 + c] = h;
          yl[q*128 + c] = f2bf(v - bf2f(h));
        }
  }
}

// ---------------------------------------------------------------------------
// K3: fused flash (round-5/7 verified body: launch_bounds(256,2), VGPR 112,
//     double-buffered sxh/sxl/sxt, 48KB LDS). KS=4 (measured best).
//   Always writes bf16 Opart + m/l partials (A1 never hits HBM).
//   DO NOT cap VGPR below ~130 (spill signature: rounds 2/4/6).
// ---------------------------------------------------------------------------
__global__ __launch_bounds__(256, 2) void k_flash(
    const u16* __restrict__ xh, const u16* __restrict__ xl, const u16* __restrict__ Xt,
    const u16* __restrict__ yh, const u16* __restrict__ yl,
    u16* __restrict__ Opart, float* __restrict__ mpart, float* __restrict__ lpart,
    int KS, int kslog)
{
  __shared__ u16 sxh[2][4096], sxl[2][4096];   // 32kv x 128f, XOR-swz (row&7)
  __shared__ u16 sxt[2][4096];                 // 128d x 32kv, XOR-swz (row&3)
  const int tid = threadIdx.x, bid = blockIdx.x;
  const int b     = bid & 7;                   // XCD b owns batch b
  const int inner = bid >> 3;
  const int s     = inner & (KS - 1);
  const int qbl   = inner >> kslog;
  const int qb    = b*16 + qbl;
  const int nspan = 2048 >> kslog;
  const int kv0   = s * nspan;
  const int ntiles = nspan >> 5;
  const int w = tid >> 6, lane = tid & 63, lr = lane & 15, g = lane >> 4;
  const long qrow = (long)qb*128 + w*32;

  // Y fragments (B-operands), hi/lo — per-warp constants
  s16x8 byh[2][4], byl[2][4];
#pragma unroll
  for (int qh = 0; qh < 2; qh++)
#pragma unroll
    for (int kc = 0; kc < 4; kc++){
      long r = qrow + qh*16 + lr;
      byh[qh][kc] = *(const s16x8*)(yh + r*128 + kc*32 + g*8);
      byl[qh][kc] = *(const s16x8*)(yl + r*128 + kc*32 + g*8);
    }

  f32x4 o[8][2];                               // O^T: [d-tile dg][q-half qh]
#pragma unroll
  for (int dg = 0; dg < 8; dg++){ o[dg][0] = f4zero(); o[dg][1] = f4zero(); }
  float mrun[2] = {-1e30f, -1e30f}, lrun[2] = {0.f, 0.f};

  const char* gxh  = (const char*)xh + ((long)b*2048 + kv0)*256;
  const char* gxl  = (const char*)xl + ((long)b*2048 + kv0)*256;
  const char* gxtb = (const char*)(Xt + (long)b*262144 + kv0);

  auto stage = [&](int bufi, int t){
#pragma unroll
    for (int c2 = 0; c2 < 2; c2++){
      int chunk = w*2 + c2;
      int off = chunk*1024 + lane*16;
      {  // x tiles: rows of 256B (16 granules), swizzle by row&7
        int row = off >> 8;
        int swo = off ^ ((row & 7) << 4);
        async16(gxh + (long)t*8192 + swo, &sxh[bufi][chunk*512]);
        async16(gxl + (long)t*8192 + swo, &sxl[bufi][chunk*512]);
      }
      {  // xt tile: rows of 64B (4 granules), swizzle by row&3 ONLY
        int row = off >> 6;
        int col = off & 63;
        int src = row*4096 + (col ^ ((row & 3) << 4));
        async16(gxtb + (long)t*64 + src, &sxt[bufi][chunk*512]);
      }
    }
  };

  stage(0, 0);
  __syncthreads();

  for (int t = 0; t < ntiles; t++){
    const int cur = t & 1;
    if (t + 1 < ntiles) stage(cur ^ 1, t + 1);
    const char* pxh = (const char*)&sxh[cur][0];
    const char* pxl = (const char*)&sxl[cur][0];

    // ---- S^T tile [32kv x 32q], 3-term hi/lo split ----
    f32x4 sacc[2][2];                          // [kv-half ch][q-half qh]
    sacc[0][0] = f4zero(); sacc[0][1] = f4zero();
    sacc[1][0] = f4zero(); sacc[1][1] = f4zero();
    __builtin_amdgcn_s_setprio(1);
#pragma unroll
    for (int ch = 0; ch < 2; ch++){
      const int rowb = ch*16 + lr;
#pragma unroll
      for (int kc = 0; kc < 4; kc++){
        const int boff = rowb*256 + ((kc*64 + g*16) ^ ((rowb & 7) << 4));
        s16x8 fh = *(const s16x8*)(pxh + boff);
        s16x8 fl = *(const s16x8*)(pxl + boff);
#pragma unroll
        for (int qh = 0; qh < 2; qh++){
          sacc[ch][qh] = MFMA16(fh, byh[qh][kc], sacc[ch][qh]);
          sacc[ch][qh] = MFMA16(fl, byh[qh][kc], sacc[ch][qh]);
          sacc[ch][qh] = MFMA16(fh, byl[qh][kc], sacc[ch][qh]);
        }
      }
    }
    __builtin_amdgcn_s_setprio(0);

    // ---- lane-local online softmax + in-register P^T redistribution ----
    s16x8 bpq[2];
#pragma unroll
    for (int qh = 0; qh < 2; qh++){
      float cm = fmaxf(fmaxf(fmaxf(sacc[0][qh][0], sacc[0][qh][1]),
                             fmaxf(sacc[0][qh][2], sacc[0][qh][3])),
                       fmaxf(fmaxf(sacc[1][qh][0], sacc[1][qh][1]),
                             fmaxf(sacc[1][qh][2], sacc[1][qh][3])));
      cm = fmaxf(cm, __shfl_xor(cm, 16, 64));
      cm = fmaxf(cm, __shfl_xor(cm, 32, 64));
      if (__any(cm > mrun[qh] + 8.f)){         // defer-max (log2 units, P<=256)
        float mn = fmaxf(mrun[qh], cm);
        float sc = exp2f(mrun[qh] - mn);
#pragma unroll
        for (int dg = 0; dg < 8; dg++)
#pragma unroll
          for (int r = 0; r < 4; r++) o[dg][qh][r] *= sc;
        lrun[qh] *= sc;
        mrun[qh] = mn;
      }
      float p[2][4];
#pragma unroll
      for (int ch = 0; ch < 2; ch++)
#pragma unroll
        for (int r = 0; r < 4; r++) p[ch][r] = exp2f(sacc[ch][qh][r] - mrun[qh]);
      float ls = ((p[0][0] + p[0][1]) + (p[0][2] + p[0][3]))
               + ((p[1][0] + p[1][1]) + (p[1][2] + p[1][3]));
      ls += __shfl_xor(ls, 16, 64);
      ls += __shfl_xor(ls, 32, 64);
      lrun[qh] += ls;
      // lane (g,lr) holds P[q=lr+16qh][kv=16ch+4g+r]; B-frag needs kv=8g+j.
      // 4-lane-group permute: sA = 32*(g&1)+lr gives j0..3, sB=sA+16 j4..7, ch=g>>1
      u32 pw00 = pack2bf(p[0][0], p[0][1]);
      u32 pw01 = pack2bf(p[0][2], p[0][3]);
      u32 pw10 = pack2bf(p[1][0], p[1][1]);
      u32 pw11 = pack2bf(p[1][2], p[1][3]);
      int sA = ((g & 1) << 5) + lr;
      int sB = sA + 16;
      u32 a0 = (u32)__shfl((int)pw00, sA, 64);
      u32 a1 = (u32)__shfl((int)pw01, sA, 64);
      u32 a2 = (u32)__shfl((int)pw10, sA, 64);
      u32 a3 = (u32)__shfl((int)pw11, sA, 64);
      u32 b0 = (u32)__shfl((int)pw00, sB, 64);
      u32 b1 = (u32)__shfl((int)pw01, sB, 64);
      u32 b2 = (u32)__shfl((int)pw10, sB, 64);
      u32 b3 = (u32)__shfl((int)pw11, sB, 64);
      bool hi = (g >= 2);
      bpq[qh] = mk8(hi ? a2 : a0, hi ? a3 : a1, hi ? b2 : b0, hi ? b3 : b1);
    }

    // ---- O^T += Xt-frag (LDS swz) x P^T (regs), 2 halves to cap liveness ----
    __builtin_amdgcn_s_setprio(1);
#pragma unroll
    for (int half = 0; half < 2; half++){
      s16x8 ax[4];
#pragma unroll
      for (int i = 0; i < 4; i++){
        int row = (half*4 + i)*16 + lr;
        int phys = row*64 + ((g*16) ^ ((row & 3) << 4));
        ax[i] = *(const s16x8*)((const char*)&sxt[cur][0] + phys);
      }
#pragma unroll
      for (int i = 0; i < 4; i++){
        int dg = half*4 + i;
        o[dg][0] = MFMA16(ax[i], bpq[0], o[dg][0]);
        o[dg][1] = MFMA16(ax[i], bpq[1], o[dg][1]);
      }
    }
    __builtin_amdgcn_s_setprio(0);
    __syncthreads();   // drains prefetch + guards buffer reuse
  }

  // ---- epilogue: bf16 partials (merge happens fused in k_mergeL1) ----
  const long pid = bid;
#pragma unroll
  for (int qh = 0; qh < 2; qh++){
    int lq = w*32 + qh*16 + lr;
#pragma unroll
    for (int dg = 0; dg < 8; dg++){
      u32x2 pw;
      pw[0] = pack2bf(o[dg][qh][0], o[dg][qh][1]);
      pw[1] = pack2bf(o[dg][qh][2], o[dg][qh][3]);
      *(u32x2*)(Opart + pid*16384 + (long)lq*128 + dg*16 + 4*g) = pw;
    }
    if (g == 0){
      mpart[pid*128 + lq] = mrun[qh];
      lpart[pid*128 + lq] = lrun[qh];
    }
  }
}

// ---------------------------------------------------------------------------
// K4 (fused merge + layer1): 256 blocks x 128 thr, 64 rows each.
//   Phase 1: merge KS partials -> swizzled LDS A1 tile (bf16).
//   Phase 2: x1 = relu(A1 @ w1 + x).
// ---------------------------------------------------------------------------
__global__ __launch_bounds__(128) void k_mergeL1(
    const u16* __restrict__ Opart, const float* __restrict__ mpart, const float* __restrict__ lpart,
    const u16* __restrict__ w1t, const float* __restrict__ x, float* __restrict__ x1,
    int KS)
{
  __shared__ u16 sb[16384];                    // w1^T [c][f] swizzled
  __shared__ u16 sa[8192];                     // A1 tile [64][128] swizzled
  const int tid = threadIdx.x, bid = blockIdx.x;
#pragma unroll
  for (int k = 0; k < 16; k++){
    int off = (tid + k*128)*16;
    int row = off >> 8;
    *(s16x8*)((char*)sb + (off ^ ((row & 7) << 4))) = *(const s16x8*)((const char*)w1t + off);
  }
  const long R0 = (long)bid*64;
  // merge phase: 1024 granules (64 rows x 16), 8 per thread
#pragma unroll
  for (int k = 0; k < 8; k++){
    int gidx = tid + k*128;
    int lrow = gidx >> 4, gcol = gidx & 15;
    long R = R0 + lrow;
    int qb = (int)(R >> 7), r = (int)(R & 127);
    int pbase = qb >> 4, qblk = qb & 15;
    float m = -1e30f;
    for (int s = 0; s < KS; s++){
      long pid = (long)((qblk*KS + s)*8 + pbase);
      m = fmaxf(m, mpart[pid*128 + r]);
    }
    float ls = 0.f;
    float a0=0.f,a1=0.f,a2=0.f,a3=0.f,a4=0.f,a5=0.f,a6=0.f,a7=0.f;
    for (int s = 0; s < KS; s++){
      long pid = (long)((qblk*KS + s)*8 + pbase);
      float wgt = exp2f(mpart[pid*128 + r] - m);
      ls += lpart[pid*128 + r] * wgt;
      u32x4 v = *(const u32x4*)(Opart + pid*16384 + (long)r*128 + gcol*8);
      a0 += bf2f((u16)(v[0] & 0xffff)) * wgt;  a1 += bf2f((u16)(v[0] >> 16)) * wgt;
      a2 += bf2f((u16)(v[1] & 0xffff)) * wgt;  a3 += bf2f((u16)(v[1] >> 16)) * wgt;
      a4 += bf2f((u16)(v[2] & 0xffff)) * wgt;  a5 += bf2f((u16)(v[2] >> 16)) * wgt;
      a6 += bf2f((u16)(v[3] & 0xffff)) * wgt;  a7 += bf2f((u16)(v[3] >> 16)) * wgt;
    }
    float inv = 1.f / ls;
    u32x4 pw;
    pw[0] = pack2bf(a0*inv, a1*inv); pw[1] = pack2bf(a2*inv, a3*inv);
    pw[2] = pack2bf(a4*inv, a5*inv); pw[3] = pack2bf(a6*inv, a7*inv);
    int off = lrow*256 + gcol*16;
    *(u32x4*)((char*)sa + (off ^ ((lrow & 7) << 4))) = pw;
  }
  __syncthreads();
  // GEMM phase (identical structure to verified k_layer1, A from LDS)
  const int w = tid >> 6, lane = tid & 63, lr = lane & 15, g = lane >> 4;
  const long rowbase = R0 + w*32;
  s16x8 aa[2][4];
#pragma unroll
  for (int rh = 0; rh < 2; rh++)
#pragma unroll
    for (int kc = 0; kc < 4; kc++){
      int lrow = w*32 + rh*16 + lr;
      aa[rh][kc] = *(const s16x8*)((const char*)sa +
                     (lrow*256 + ((kc*64 + g*16) ^ ((lrow & 7) << 4))));
    }
  f32x4 acc[2][8];
#pragma unroll
  for (int rh = 0; rh < 2; rh++)
#pragma unroll
    for (int cg = 0; cg < 8; cg++) acc[rh][cg] = f4zero();
  const int swz = (lr & 7) << 4;
#pragma unroll
  for (int cg = 0; cg < 8; cg++){
    const int rowt = (cg*16 + lr)*256;
#pragma unroll
    for (int kc = 0; kc < 4; kc++){
      s16x8 bb = *(const s16x8*)((const char*)sb + rowt + ((kc*64 + g*16) ^ swz));
#pragma unroll
      for (int rh = 0; rh < 2; rh++)
        acc[rh][cg] = MFMA16(aa[rh][kc], bb, acc[rh][cg]);
    }
  }
#pragma unroll
  for (int rh = 0; rh < 2; rh++)
#pragma unroll
    for (int cg = 0; cg < 8; cg++)
#pragma unroll
      for (int r = 0; r < 4; r++){
        long q = rowbase + rh*16 + 4*g + r;
        int  c = cg*16 + lr;
        float v = acc[rh][cg][r] + x[q*128 + c];
        x1[q*128 + c] = fmaxf(v, 0.f);
      }
}

// ---------------------------------------------------------------------------
// K5: A2 partials with unnormalized softmax weights (exact fp32 row-0 path).
// ---------------------------------------------------------------------------
__global__ __launch_bounds__(256) void k_a2(
    const float* __restrict__ S0, const float* __restrict__ maxpart,
    const float* __restrict__ x1, float* __restrict__ A2p, float* __restrict__ Lj)
{
  __shared__ float red[128];
  __shared__ float lred[2];
  const int tid = threadIdx.x, bid = blockIdx.x;
  const int b = bid >> 3, j = bid & 7;
  const int d = tid & 127, h = tid >> 7;
  float M = -1e30f;
#pragma unroll
  for (int jj = 0; jj < 8; jj++) M = fmaxf(M, maxpart[b*8 + jj]);
  float acc = 0.f, lacc = 0.f;
  for (int mi = j*256 + h; mi < j*256 + 256; mi += 2){
    float e = __expf(S0[b*2048 + mi] - M);
    acc  += e * x1[((long)b*2048 + mi)*128 + d];
    lacc += e;
  }
  if (h == 1) red[d] = acc;
  if (d == 0) lred[h] = lacc;
  __syncthreads();
  if (h == 0) A2p[(long)bid*128 + d] = acc + red[d];
  if (tid == 0) Lj[bid] = lred[0] + lred[1];
}

// K6: out = relu((A2/L) @ w2 + x1[:,0,:])
__global__ __launch_bounds__(256) void k_out(
    const float* __restrict__ A2p, const float* __restrict__ Lj,
    const float* __restrict__ w2, const float* __restrict__ x1,
    float* __restrict__ out)
{
  __shared__ float a2s[2][128];
  const int tid = threadIdx.x, bid = blockIdx.x;
  const int b0 = bid*2;
  {
    int which = tid >> 7, f = tid & 127;
    int bb = b0 + which;
    float s = 0.f, L = 0.f;
#pragma unroll
    for (int jj = 0; jj < 8; jj++){
      s += A2p[(long)(bb*8 + jj)*128 + f];
      L += Lj[bb*8 + jj];
    }
    a2s[which][f] = s / L;
  }
  __syncthreads();
  const int which = tid >> 7, d = tid & 127;
  const int b = b0 + which;
  float acc = x1[(long)b*262144 + d];
  for (int f = 0; f < 128; f++)
    acc += a2s[which][f] * w2[f*128 + d];
  out[b*128 + d] = fmaxf(acc, 0.f);
}

// ---------------------------------------------------------------------------
extern "C" void kernel_launch(void* const* d_in, const int* in_sizes, int n_in,
                              void* d_out, int out_size, void* d_ws, size_t ws_size,
                              hipStream_t stream)
{
  const float* x  = (const float*)d_in[0];
  const float* w1 = (const float*)d_in[1];
  const float* w2 = (const float*)d_in[2];
  const float* wr = (const float*)d_in[3];
  float* out = (float*)d_out;
  char* ws = (char*)d_ws;

  u16*   xh      = (u16*)  (ws + 0);
  u16*   xl      = (u16*)  (ws + 4194304);
  u16*   Xt      = (u16*)  (ws + 8388608);
  u16*   yh      = (u16*)  (ws + 12582912);
  u16*   yl      = (u16*)  (ws + 16777216);
  u16*   w1t     = (u16*)  (ws + 20971520);
  float* S0      = (float*)(ws + 21004288);
  float* maxpart = (float*)(ws + 21069824);
  float* Lj      = (float*)(ws + 21070848);
  float* A2p     = (float*)(ws + 21071872);
  const size_t tail = 21104640;

  int KS = 4, kslog = 2;
  // per-KS bytes: mpart 64K + lpart 64K + Opart bf16 4M; x1 (8M) after Opart
  while (KS > 1 && tail + (size_t)KS*4325376ull + 8388608ull > ws_size){ KS >>= 1; kslog--; }
  float* mpart = (float*)(ws + tail);
  float* lpart = (float*)(ws + tail + (size_t)KS*65536);
  u16*   Opart = (u16*)  (ws + tail + (size_t)KS*131072);
  float* x1    = (float*)(ws + tail + (size_t)KS*131072 + (size_t)KS*4194304);

  k_prep   <<<1224, 256, 0, stream>>>(x, wr, w1, xh, xl, Xt, w1t, S0, maxpart, yh, yl);
  k_flash  <<<128*KS, 256, 0, stream>>>(xh, xl, Xt, yh, yl, Opart, mpart, lpart, KS, kslog);
  k_mergeL1<<<256, 128, 0, stream>>>(Opart, mpart, lpart, w1t, x, x1, KS);
  k_a2     <<<64, 256, 0, stream>>>(S0, maxpart, x1, A2p, Lj);
  k_out    <<<4, 256, 0, stream>>>(A2p, Lj, w2, x1, out);
}

// Round 10
// 130.825 us; speedup vs baseline: 2.6622x; 1.0217x over previous
//
#include <hip/hip_runtime.h>
#include <stdint.h>

typedef float  f32x4 __attribute__((ext_vector_type(4)));
typedef short  s16x8 __attribute__((ext_vector_type(8)));
typedef unsigned int u32;
typedef u32    u32x2 __attribute__((ext_vector_type(2)));
typedef u32    u32x4 __attribute__((ext_vector_type(4)));
typedef unsigned short u16;

#define MFMA16(a,b,c) __builtin_amdgcn_mfma_f32_16x16x32_bf16((a),(b),(c),0,0,0)

__device__ __forceinline__ u16 f2bf(float f){
  u32 u = __float_as_uint(f);
  return (u16)((u + 0x7fffu + ((u >> 16) & 1u)) >> 16);   // RNE
}
__device__ __forceinline__ float bf2f(u16 h){ return __uint_as_float(((u32)h) << 16); }
__device__ __forceinline__ u32 pack2bf(float a, float b){ return (u32)f2bf(a) | ((u32)f2bf(b) << 16); }
__device__ __forceinline__ f32x4 f4zero(){ f32x4 z; z[0]=0.f; z[1]=0.f; z[2]=0.f; z[3]=0.f; return z; }
// register-only vector build (NO union: unions can defeat SROA -> scratch)
__device__ __forceinline__ s16x8 mk8(u32 a, u32 b, u32 c, u32 d){
  u32x4 w; w[0]=a; w[1]=b; w[2]=c; w[3]=d;
  return __builtin_bit_cast(s16x8, w);
}

// async global->LDS, 16B per lane; LDS dest is wave-uniform base + lane*16
__device__ __forceinline__ void async16(const void* g, void* l){
  __builtin_amdgcn_global_load_lds(
      (const __attribute__((address_space(1))) unsigned int*)g,
      (__attribute__((address_space(3))) unsigned int*)l, 16, 0, 0);
}

// ---------------------------------------------------------------------------
// K1 mega-prep. Block ranges (one branch each, no cross-block deps):
//   [0,1024):    x -> xh/xl split + Xt transpose
//   [1024,1032): w1^T bf16
//   [1032,1096): exact fp32 row-0 logits S0 + per-chunk maxpart
//   [1096,1224): ygemm: y = (x @ wr)*log2e, 3-term split from RAW fp32 x/wr
//   smem = 64 KB: the ygemm branch needs TWO 32 KB wr^T tables (hi+lo).
// ---------------------------------------------------------------------------
__global__ __launch_bounds__(256) void k_prep(
    const float* __restrict__ x, const float* __restrict__ wr, const float* __restrict__ w1,
    u16* __restrict__ xh, u16* __restrict__ xl, u16* __restrict__ Xt,
    u16* __restrict__ w1t, float* __restrict__ S0, float* __restrict__ maxpart,
    u16* __restrict__ yh, u16* __restrict__ yl)
{
  __shared__ __align__(16) char smem[65536];
  const int tid = threadIdx.x, bid = blockIdx.x;

  if (bid < 1024){
    float (*xs)[132] = (float(*)[132])smem;
    const long base = (long)bid * 2048;          // 16 rows * 128
#pragma unroll
    for (int k = 0; k < 8; k++){
      int idx = tid + k*256;
      float v = x[base + idx];
      xs[idx>>7][idx&127] = v;
      u16 h = f2bf(v);
      xh[base+idx] = h;
      xl[base+idx] = f2bf(v - bf2f(h));
    }
    __syncthreads();
    const int b  = bid >> 7;                     // 128 blocks per batch
    const int n0 = (bid & 127) * 16;
    const int nn = tid & 15, d0 = tid >> 4;
#pragma unroll
    for (int d = 0; d < 8; d++){
      int dd = d0 + d*16;
      Xt[(long)b*262144 + (long)dd*2048 + n0 + nn] = f2bf(xs[nn][dd]);
    }
  } else if (bid < 1032){
    const int base = (bid - 1024) * 2048;
#pragma unroll
    for (int k = 0; k < 8; k++){
      int idx = base + k*256 + tid;
      int c = idx >> 7, f = idx & 127;
      w1t[idx] = f2bf(w1[f*128 + c]);            // w1T[c][f] = w1[f][c]
    }
  } else if (bid < 1096){
    float* x0s = (float*)smem;                   // 128
    float* ys  = x0s + 128;                      // 128
    float* red = ys + 128;                       // 256
    const int jj = bid - 1032;
    const int b = jj >> 3, j = jj & 7;
    if (tid < 128) x0s[tid] = x[(long)b*262144 + tid];
    __syncthreads();
    if (tid < 128){
      float a = 0.f;
      for (int f = 0; f < 128; f++) a += x0s[f] * wr[f*128 + tid];
      ys[tid] = a;
    }
    __syncthreads();
    const int m = j*256 + tid;
    const float4* xr = (const float4*)(x + ((long)b*2048 + m)*128);
    const float4* yv = (const float4*)ys;
    float acc = 0.f;
#pragma unroll
    for (int f = 0; f < 32; f++){
      float4 a = xr[f], c = yv[f];
      acc += a.x*c.x + a.y*c.y + a.z*c.z + a.w*c.w;
    }
    S0[b*2048 + m] = acc;
    red[tid] = acc;
    __syncthreads();
    for (int sft = 128; sft > 0; sft >>= 1){
      if (tid < sft) red[tid] = fmaxf(red[tid], red[tid + sft]);
      __syncthreads();
    }
    if (tid == 0) maxpart[jj] = red[0];
  } else {
    // ---- fused ygemm: 128 blocks x 256 thr (4 warps), 128 rows/block ----
    u16* sbh = (u16*)smem;                       // [c][f] bf16 swizzled, 32 KB
    u16* sbl = sbh + 16384;                      // +16384 u16 = +32 KB
    // stage wr^T hi/lo into LDS (self-converted from fp32)
    {
      const int c = tid & 127, f0 = (tid >> 7) * 64;
      const int key = (c & 7) << 4;
#pragma unroll
      for (int fi = 0; fi < 64; fi += 2){
        int f = f0 + fi;
        float v0 = wr[f*128 + c], v1 = wr[(f+1)*128 + c];
        u16 h0 = f2bf(v0), h1 = f2bf(v1);
        u32 hw = (u32)h0 | ((u32)h1 << 16);
        u32 lw = (u32)f2bf(v0 - bf2f(h0)) | ((u32)f2bf(v1 - bf2f(h1)) << 16);
        int byte = c*256 + ((((2*f) & ~15) ^ key) + ((2*f) & 15));
        *(u32*)((char*)sbh + byte) = hw;
        *(u32*)((char*)sbl + byte) = lw;
      }
    }
    __syncthreads();
    const int w = tid >> 6, lane = tid & 63, lr = lane & 15, g = lane >> 4;
    const long rowbase = (long)(bid - 1096)*128 + w*32;
    s16x8 ah[2][4], al[2][4];
#pragma unroll
    for (int rh = 0; rh < 2; rh++)
#pragma unroll
      for (int kc = 0; kc < 4; kc++){
        long r = rowbase + rh*16 + lr;
        const float4* px = (const float4*)(x + r*128 + kc*32 + g*8);
        float4 a = px[0], bV = px[1];
        u32 hh0, hh1, hh2, hh3, ll0, ll1, ll2, ll3;
        { u16 p=f2bf(a.x), q=f2bf(a.y); hh0=(u32)p|((u32)q<<16);
          ll0=(u32)f2bf(a.x-bf2f(p))|((u32)f2bf(a.y-bf2f(q))<<16); }
        { u16 p=f2bf(a.z), q=f2bf(a.w); hh1=(u32)p|((u32)q<<16);
          ll1=(u32)f2bf(a.z-bf2f(p))|((u32)f2bf(a.w-bf2f(q))<<16); }
        { u16 p=f2bf(bV.x), q=f2bf(bV.y); hh2=(u32)p|((u32)q<<16);
          ll2=(u32)f2bf(bV.x-bf2f(p))|((u32)f2bf(bV.y-bf2f(q))<<16); }
        { u16 p=f2bf(bV.z), q=f2bf(bV.w); hh3=(u32)p|((u32)q<<16);
          ll3=(u32)f2bf(bV.z-bf2f(p))|((u32)f2bf(bV.w-bf2f(q))<<16); }
        ah[rh][kc] = mk8(hh0,hh1,hh2,hh3);
        al[rh][kc] = mk8(ll0,ll1,ll2,ll3);
      }
    f32x4 acc[2][8];
#pragma unroll
    for (int rh = 0; rh < 2; rh++)
#pragma unroll
      for (int cg = 0; cg < 8; cg++) acc[rh][cg] = f4zero();
    const int swz = (lr & 7) << 4;
#pragma unroll
    for (int cg = 0; cg < 8; cg++){
      const int rowt = (cg*16 + lr) * 256;
#pragma unroll
      for (int kc = 0; kc < 4; kc++){
        int boff = rowt + ((kc*64 + g*16) ^ swz);
        s16x8 bh = *(const s16x8*)((const char*)sbh + boff);
        s16x8 bl = *(const s16x8*)((const char*)sbl + boff);
#pragma unroll
        for (int rh = 0; rh < 2; rh++){
          acc[rh][cg] = MFMA16(ah[rh][kc], bh, acc[rh][cg]);
          acc[rh][cg] = MFMA16(al[rh][kc], bh, acc[rh][cg]);
          acc[rh][cg] = MFMA16(ah[rh][kc], bl, acc[rh][cg]);
        }
      }
    }
#pragma unroll
    for (int rh = 0; rh < 2; rh++)
#pragma unroll
      for (int cg = 0; cg < 8; cg++)
#pragma unroll
        for (int r = 0; r < 4; r++){
          long q = rowbase + rh*16 + 4*g + r;  // C-layout: row=(l>>4)*4+reg
          int  c = cg*16 + lr;                 //           col=l&15
          float v = acc[rh][cg][r] * 1.4426950408889634f;
          u16 h = f2bf(v);
          yh[q*128 + c] = h;
          yl[q*128 + c] = f2bf(v - bf2f(h));
        }
  }
}

// ---------------------------------------------------------------------------
// K3: fused flash, 8-warp variant: 512 thr, 16 q-rows/warp (same 128-row
//   block, same LDS tiles now shared by 8 warps). Doubles waves/SIMD (2->4)
//   at identical per-CU footprint — latency-hiding for the per-tile chain.
//   Memory layout/swizzles/numerics identical to the 4-warp verified body.
//   NO launch_bounds min-wave cap (spill rule: rounds 2/4/6).
// ---------------------------------------------------------------------------
__global__ __launch_bounds__(512) void k_flash(
    const u16* __restrict__ xh, const u16* __restrict__ xl, const u16* __restrict__ Xt,
    const u16* __restrict__ yh, const u16* __restrict__ yl,
    u16* __restrict__ Opart, float* __restrict__ mpart, float* __restrict__ lpart,
    int KS, int kslog)
{
  __shared__ u16 sxh[2][4096], sxl[2][4096];   // 32kv x 128f, XOR-swz (row&7)
  __shared__ u16 sxt[2][4096];                 // 128d x 32kv, XOR-swz (row&3)
  const int tid = threadIdx.x, bid = blockIdx.x;
  const int b     = bid & 7;                   // XCD b owns batch b
  const int inner = bid >> 3;
  const int s     = inner & (KS - 1);
  const int qbl   = inner >> kslog;
  const int qb    = b*16 + qbl;
  const int nspan = 2048 >> kslog;
  const int kv0   = s * nspan;
  const int ntiles = nspan >> 5;
  const int w = tid >> 6, lane = tid & 63, lr = lane & 15, g = lane >> 4;
  const long qrow = (long)qb*128 + w*16;       // 16 q-rows per warp

  // Y fragments (B-operands), hi/lo — 16 q-cols per warp
  s16x8 byh[4], byl[4];
#pragma unroll
  for (int kc = 0; kc < 4; kc++){
    long r = qrow + lr;
    byh[kc] = *(const s16x8*)(yh + r*128 + kc*32 + g*8);
    byl[kc] = *(const s16x8*)(yl + r*128 + kc*32 + g*8);
  }

  f32x4 o[8];                                  // O^T: [d-tile dg]
#pragma unroll
  for (int dg = 0; dg < 8; dg++) o[dg] = f4zero();
  float mrun = -1e30f, lrun = 0.f;

  const char* gxh  = (const char*)xh + ((long)b*2048 + kv0)*256;
  const char* gxl  = (const char*)xl + ((long)b*2048 + kv0)*256;
  const char* gxtb = (const char*)(Xt + (long)b*262144 + kv0);

  auto stage = [&](int bufi, int t){
    // one 1024B chunk per warp per array (8 warps cover 8192B)
    int off = w*1024 + lane*16;
    {  // x tiles: rows of 256B (16 granules), swizzle by row&7
      int row = off >> 8;
      int swo = off ^ ((row & 7) << 4);
      async16(gxh + (long)t*8192 + swo, &sxh[bufi][w*512]);
      async16(gxl + (long)t*8192 + swo, &sxl[bufi][w*512]);
    }
    {  // xt tile: rows of 64B (4 granules), swizzle by row&3 ONLY
      int row = off >> 6;
      int col = off & 63;
      int src = row*4096 + (col ^ ((row & 3) << 4));
      async16(gxtb + (long)t*64 + src, &sxt[bufi][w*512]);
    }
  };

  stage(0, 0);
  __syncthreads();

  for (int t = 0; t < ntiles; t++){
    const int cur = t & 1;
    if (t + 1 < ntiles) stage(cur ^ 1, t + 1);
    const char* pxh = (const char*)&sxh[cur][0];
    const char* pxl = (const char*)&sxl[cur][0];

    // ---- S^T tile [32kv x 16q], 3-term hi/lo split ----
    f32x4 sacc[2];                             // [kv-half ch]
    sacc[0] = f4zero(); sacc[1] = f4zero();
    __builtin_amdgcn_s_setprio(1);
#pragma unroll
    for (int ch = 0; ch < 2; ch++){
      const int rowb = ch*16 + lr;
#pragma unroll
      for (int kc = 0; kc < 4; kc++){
        const int boff = rowb*256 + ((kc*64 + g*16) ^ ((rowb & 7) << 4));
        s16x8 fh = *(const s16x8*)(pxh + boff);
        s16x8 fl = *(const s16x8*)(pxl + boff);
        sacc[ch] = MFMA16(fh, byh[kc], sacc[ch]);
        sacc[ch] = MFMA16(fl, byh[kc], sacc[ch]);
        sacc[ch] = MFMA16(fh, byl[kc], sacc[ch]);
      }
    }
    __builtin_amdgcn_s_setprio(0);

    // ---- lane-local online softmax (q = lr lives in this lane) ----
    float cm = fmaxf(fmaxf(fmaxf(sacc[0][0], sacc[0][1]),
                           fmaxf(sacc[0][2], sacc[0][3])),
                     fmaxf(fmaxf(sacc[1][0], sacc[1][1]),
                           fmaxf(sacc[1][2], sacc[1][3])));
    cm = fmaxf(cm, __shfl_xor(cm, 16, 64));
    cm = fmaxf(cm, __shfl_xor(cm, 32, 64));
    if (__any(cm > mrun + 8.f)){               // defer-max (log2 units, P<=256)
      float mn = fmaxf(mrun, cm);
      float sc = exp2f(mrun - mn);
#pragma unroll
      for (int dg = 0; dg < 8; dg++)
#pragma unroll
        for (int r = 0; r < 4; r++) o[dg][r] *= sc;
      lrun *= sc;
      mrun = mn;
    }
    float p[2][4];
#pragma unroll
    for (int ch = 0; ch < 2; ch++)
#pragma unroll
      for (int r = 0; r < 4; r++) p[ch][r] = exp2f(sacc[ch][r] - mrun);
    float ls = ((p[0][0] + p[0][1]) + (p[0][2] + p[0][3]))
             + ((p[1][0] + p[1][1]) + (p[1][2] + p[1][3]));
    ls += __shfl_xor(ls, 16, 64);
    ls += __shfl_xor(ls, 32, 64);
    lrun += ls;
    // lane (g,lr) holds P[q=lr][kv=16ch+4g+r]; B-frag needs kv=8g+j.
    // 4-lane-group permute: sA = 32*(g&1)+lr gives j0..3, sB=sA+16 j4..7, ch=g>>1
    s16x8 bpq;
    {
      u32 pw00 = pack2bf(p[0][0], p[0][1]);
      u32 pw01 = pack2bf(p[0][2], p[0][3]);
      u32 pw10 = pack2bf(p[1][0], p[1][1]);
      u32 pw11 = pack2bf(p[1][2], p[1][3]);
      int sA = ((g & 1) << 5) + lr;
      int sB = sA + 16;
      u32 a0 = (u32)__shfl((int)pw00, sA, 64);
      u32 a1 = (u32)__shfl((int)pw01, sA, 64);
      u32 a2 = (u32)__shfl((int)pw10, sA, 64);
      u32 a3 = (u32)__shfl((int)pw11, sA, 64);
      u32 b0 = (u32)__shfl((int)pw00, sB, 64);
      u32 b1 = (u32)__shfl((int)pw01, sB, 64);
      u32 b2 = (u32)__shfl((int)pw10, sB, 64);
      u32 b3 = (u32)__shfl((int)pw11, sB, 64);
      bool hi = (g >= 2);
      bpq = mk8(hi ? a2 : a0, hi ? a3 : a1, hi ? b2 : b0, hi ? b3 : b1);
    }

    // ---- O^T += Xt-frag (LDS swz) x P^T (regs), 2 halves to cap liveness ----
    __builtin_amdgcn_s_setprio(1);
#pragma unroll
    for (int half = 0; half < 2; half++){
      s16x8 ax[4];
#pragma unroll
      for (int i = 0; i < 4; i++){
        int row = (half*4 + i)*16 + lr;
        int phys = row*64 + ((g*16) ^ ((row & 3) << 4));
        ax[i] = *(const s16x8*)((const char*)&sxt[cur][0] + phys);
      }
#pragma unroll
      for (int i = 0; i < 4; i++){
        int dg = half*4 + i;
        o[dg] = MFMA16(ax[i], bpq, o[dg]);
      }
    }
    __builtin_amdgcn_s_setprio(0);
    __syncthreads();   // drains prefetch + guards buffer reuse
  }

  // ---- epilogue: O^T lane holds (d = dg*16+4g+r, q = qrow+lr) ----
  const long pid = bid;
  {
    int lq = w*16 + lr;
#pragma unroll
    for (int dg = 0; dg < 8; dg++){
      u32x2 pw;
      pw[0] = pack2bf(o[dg][0], o[dg][1]);
      pw[1] = pack2bf(o[dg][2], o[dg][3]);
      *(u32x2*)(Opart + pid*16384 + (long)lq*128 + dg*16 + 4*g) = pw;
    }
    if (g == 0){
      mpart[pid*128 + lq] = mrun;
      lpart[pid*128 + lq] = lrun;
    }
  }
}

// ---------------------------------------------------------------------------
// K4 (fused merge + layer1): 256 blocks x 128 thr, 64 rows each.
//   Phase 1: merge KS partials -> swizzled LDS A1 tile (bf16).
//   Phase 2: x1 = relu(A1 @ w1 + x).
// ---------------------------------------------------------------------------
__global__ __launch_bounds__(128) void k_mergeL1(
    const u16* __restrict__ Opart, const float* __restrict__ mpart, const float* __restrict__ lpart,
    const u16* __restrict__ w1t, const float* __restrict__ x, float* __restrict__ x1,
    int KS)
{
  __shared__ u16 sb[16384];                    // w1^T [c][f] swizzled
  __shared__ u16 sa[8192];                     // A1 tile [64][128] swizzled
  const int tid = threadIdx.x, bid = blockIdx.x;
#pragma unroll
  for (int k = 0; k < 16; k++){
    int off = (tid + k*128)*16;
    int row = off >> 8;
    *(s16x8*)((char*)sb + (off ^ ((row & 7) << 4))) = *(const s16x8*)((const char*)w1t + off);
  }
  const long R0 = (long)bid*64;
  // merge phase: 1024 granules (64 rows x 16), 8 per thread
#pragma unroll
  for (int k = 0; k < 8; k++){
    int gidx = tid + k*128;
    int lrow = gidx >> 4, gcol = gidx & 15;
    long R = R0 + lrow;
    int qb = (int)(R >> 7), r = (int)(R & 127);
    int pbase = qb >> 4, qblk = qb & 15;
    float m = -1e30f;
    for (int s = 0; s < KS; s++){
      long pid = (long)((qblk*KS + s)*8 + pbase);
      m = fmaxf(m, mpart[pid*128 + r]);
    }
    float ls = 0.f;
    float a0=0.f,a1=0.f,a2=0.f,a3=0.f,a4=0.f,a5=0.f,a6=0.f,a7=0.f;
    for (int s = 0; s < KS; s++){
      long pid = (long)((qblk*KS + s)*8 + pbase);
      float wgt = exp2f(mpart[pid*128 + r] - m);
      ls += lpart[pid*128 + r] * wgt;
      u32x4 v = *(const u32x4*)(Opart + pid*16384 + (long)r*128 + gcol*8);
      a0 += bf2f((u16)(v[0] & 0xffff)) * wgt;  a1 += bf2f((u16)(v[0] >> 16)) * wgt;
      a2 += bf2f((u16)(v[1] & 0xffff)) * wgt;  a3 += bf2f((u16)(v[1] >> 16)) * wgt;
      a4 += bf2f((u16)(v[2] & 0xffff)) * wgt;  a5 += bf2f((u16)(v[2] >> 16)) * wgt;
      a6 += bf2f((u16)(v[3] & 0xffff)) * wgt;  a7 += bf2f((u16)(v[3] >> 16)) * wgt;
    }
    float inv = 1.f / ls;
    u32x4 pw;
    pw[0] = pack2bf(a0*inv, a1*inv); pw[1] = pack2bf(a2*inv, a3*inv);
    pw[2] = pack2bf(a4*inv, a5*inv); pw[3] = pack2bf(a6*inv, a7*inv);
    int off = lrow*256 + gcol*16;
    *(u32x4*)((char*)sa + (off ^ ((lrow & 7) << 4))) = pw;
  }
  __syncthreads();
  // GEMM phase (identical structure to verified k_layer1, A from LDS)
  const int w = tid >> 6, lane = tid & 63, lr = lane & 15, g = lane >> 4;
  const long rowbase = R0 + w*32;
  s16x8 aa[2][4];
#pragma unroll
  for (int rh = 0; rh < 2; rh++)
#pragma unroll
    for (int kc = 0; kc < 4; kc++){
      int lrow = w*32 + rh*16 + lr;
      aa[rh][kc] = *(const s16x8*)((const char*)sa +
                     (lrow*256 + ((kc*64 + g*16) ^ ((lrow & 7) << 4))));
    }
  f32x4 acc[2][8];
#pragma unroll
  for (int rh = 0; rh < 2; rh++)
#pragma unroll
    for (int cg = 0; cg < 8; cg++) acc[rh][cg] = f4zero();
  const int swz = (lr & 7) << 4;
#pragma unroll
  for (int cg = 0; cg < 8; cg++){
    const int rowt = (cg*16 + lr)*256;
#pragma unroll
    for (int kc = 0; kc < 4; kc++){
      s16x8 bb = *(const s16x8*)((const char*)sb + rowt + ((kc*64 + g*16) ^ swz));
#pragma unroll
      for (int rh = 0; rh < 2; rh++)
        acc[rh][cg] = MFMA16(aa[rh][kc], bb, acc[rh][cg]);
    }
  }
#pragma unroll
  for (int rh = 0; rh < 2; rh++)
#pragma unroll
    for (int cg = 0; cg < 8; cg++)
#pragma unroll
      for (int r = 0; r < 4; r++){
        long q = rowbase + rh*16 + 4*g + r;
        int  c = cg*16 + lr;
        float v = acc[rh][cg][r] + x[q*128 + c];
        x1[q*128 + c] = fmaxf(v, 0.f);
      }
}

// ---------------------------------------------------------------------------
// K5: A2 partials with unnormalized softmax weights (exact fp32 row-0 path).
// ---------------------------------------------------------------------------
__global__ __launch_bounds__(256) void k_a2(
    const float* __restrict__ S0, const float* __restrict__ maxpart,
    const float* __restrict__ x1, float* __restrict__ A2p, float* __restrict__ Lj)
{
  __shared__ float red[128];
  __shared__ float lred[2];
  const int tid = threadIdx.x, bid = blockIdx.x;
  const int b = bid >> 3, j = bid & 7;
  const int d = tid & 127, h = tid >> 7;
  float M = -1e30f;
#pragma unroll
  for (int jj = 0; jj < 8; jj++) M = fmaxf(M, maxpart[b*8 + jj]);
  float acc = 0.f, lacc = 0.f;
  for (int mi = j*256 + h; mi < j*256 + 256; mi += 2){
    float e = __expf(S0[b*2048 + mi] - M);
    acc  += e * x1[((long)b*2048 + mi)*128 + d];
    lacc += e;
  }
  if (h == 1) red[d] = acc;
  if (d == 0) lred[h] = lacc;
  __syncthreads();
  if (h == 0) A2p[(long)bid*128 + d] = acc + red[d];
  if (tid == 0) Lj[bid] = lred[0] + lred[1];
}

// K6: out = relu((A2/L) @ w2 + x1[:,0,:])
__global__ __launch_bounds__(256) void k_out(
    const float* __restrict__ A2p, const float* __restrict__ Lj,
    const float* __restrict__ w2, const float* __restrict__ x1,
    float* __restrict__ out)
{
  __shared__ float a2s[2][128];
  const int tid = threadIdx.x, bid = blockIdx.x;
  const int b0 = bid*2;
  {
    int which = tid >> 7, f = tid & 127;
    int bb = b0 + which;
    float s = 0.f, L = 0.f;
#pragma unroll
    for (int jj = 0; jj < 8; jj++){
      s += A2p[(long)(bb*8 + jj)*128 + f];
      L += Lj[bb*8 + jj];
    }
    a2s[which][f] = s / L;
  }
  __syncthreads();
  const int which = tid >> 7, d = tid & 127;
  const int b = b0 + which;
  float acc = x1[(long)b*262144 + d];
  for (int f = 0; f < 128; f++)
    acc += a2s[which][f] * w2[f*128 + d];
  out[b*128 + d] = fmaxf(acc, 0.f);
}

// ---------------------------------------------------------------------------
extern "C" void kernel_launch(void* const* d_in, const int* in_sizes, int n_in,
                              void* d_out, int out_size, void* d_ws, size_t ws_size,
                              hipStream_t stream)
{
  const float* x  = (const float*)d_in[0];
  const float* w1 = (const float*)d_in[1];
  const float* w2 = (const float*)d_in[2];
  const float* wr = (const float*)d_in[3];
  float* out = (float*)d_out;
  char* ws = (char*)d_ws;

  u16*   xh      = (u16*)  (ws + 0);
  u16*   xl      = (u16*)  (ws + 4194304);
  u16*   Xt      = (u16*)  (ws + 8388608);
  u16*   yh      = (u16*)  (ws + 12582912);
  u16*   yl      = (u16*)  (ws + 16777216);
  u16*   w1t     = (u16*)  (ws + 20971520);
  float* S0      = (float*)(ws + 21004288);
  float* maxpart = (float*)(ws + 21069824);
  float* Lj      = (float*)(ws + 21070848);
  float* A2p     = (float*)(ws + 21071872);
  const size_t tail = 21104640;

  int KS = 4, kslog = 2;
  // per-KS bytes: mpart 64K + lpart 64K + Opart bf16 4M; x1 (8M) after Opart
  while (KS > 1 && tail + (size_t)KS*4325376ull + 8388608ull > ws_size){ KS >>= 1; kslog--; }
  float* mpart = (float*)(ws + tail);
  float* lpart = (float*)(ws + tail + (size_t)KS*65536);
  u16*   Opart = (u16*)  (ws + tail + (size_t)KS*131072);
  float* x1    = (float*)(ws + tail + (size_t)KS*131072 + (size_t)KS*4194304);

  k_prep   <<<1224, 256, 0, stream>>>(x, wr, w1, xh, xl, Xt, w1t, S0, maxpart, yh, yl);
  k_flash  <<<128*KS, 512, 0, stream>>>(xh, xl, Xt, yh, yl, Opart, mpart, lpart, KS, kslog);
  k_mergeL1<<<256, 128, 0, stream>>>(Opart, mpart, lpart, w1t, x, x1, KS);
  k_a2     <<<64, 256, 0, stream>>>(S0, maxpart, x1, A2p, Lj);
  k_out    <<<4, 256, 0, stream>>>(A2p, Lj, w2, x1, out);
}

// Round 11
// 99.741 us; speedup vs baseline: 3.4918x; 1.3116x over previous
//
#include <hip/hip_runtime.h>
#include <stdint.h>

typedef float  f32x4 __attribute__((ext_vector_type(4)));
typedef short  s16x8 __attribute__((ext_vector_type(8)));
typedef unsigned int u32;
typedef u32    u32x2 __attribute__((ext_vector_type(2)));
typedef u32    u32x4 __attribute__((ext_vector_type(4)));
typedef unsigned short u16;

#define MFMA16(a,b,c) __builtin_amdgcn_mfma_f32_16x16x32_bf16((a),(b),(c),0,0,0)

__device__ __forceinline__ u16 f2bf(float f){
  u32 u = __float_as_uint(f);
  return (u16)((u + 0x7fffu + ((u >> 16) & 1u)) >> 16);   // RNE
}
__device__ __forceinline__ float bf2f(u16 h){ return __uint_as_float(((u32)h) << 16); }
__device__ __forceinline__ u32 pack2bf(float a, float b){ return (u32)f2bf(a) | ((u32)f2bf(b) << 16); }
__device__ __forceinline__ f32x4 f4zero(){ f32x4 z; z[0]=0.f; z[1]=0.f; z[2]=0.f; z[3]=0.f; return z; }
// register-only vector build (NO union: unions can defeat SROA -> scratch)
__device__ __forceinline__ s16x8 mk8(u32 a, u32 b, u32 c, u32 d){
  u32x4 w; w[0]=a; w[1]=b; w[2]=c; w[3]=d;
  return __builtin_bit_cast(s16x8, w);
}

// async global->LDS, 16B per lane; LDS dest is wave-uniform base + lane*16
__device__ __forceinline__ void async16(const void* g, void* l){
  __builtin_amdgcn_global_load_lds(
      (const __attribute__((address_space(1))) unsigned int*)g,
      (__attribute__((address_space(3))) unsigned int*)l, 16, 0, 0);
}

// ---------------------------------------------------------------------------
// K1 mega-prep. Block ranges (one branch each, no cross-block deps):
//   [0,1024):    x -> xh/xl split + Xt transpose
//   [1024,1032): w1^T bf16
//   [1032,1096): exact fp32 row-0 logits S0 + per-chunk maxpart
//   [1096,1224): ygemm: y = (x @ wr)*log2e, 3-term split from RAW fp32 x/wr
//   smem = 64 KB: the ygemm branch needs TWO 32 KB wr^T tables (hi+lo).
// ---------------------------------------------------------------------------
__global__ __launch_bounds__(256) void k_prep(
    const float* __restrict__ x, const float* __restrict__ wr, const float* __restrict__ w1,
    u16* __restrict__ xh, u16* __restrict__ xl, u16* __restrict__ Xt,
    u16* __restrict__ w1t, float* __restrict__ S0, float* __restrict__ maxpart,
    u16* __restrict__ yh, u16* __restrict__ yl)
{
  __shared__ __align__(16) char smem[65536];
  const int tid = threadIdx.x, bid = blockIdx.x;

  if (bid < 1024){
    float (*xs)[132] = (float(*)[132])smem;
    const long base = (long)bid * 2048;          // 16 rows * 128
#pragma unroll
    for (int k = 0; k < 8; k++){
      int idx = tid + k*256;
      float v = x[base + idx];
      xs[idx>>7][idx&127] = v;
      u16 h = f2bf(v);
      xh[base+idx] = h;
      xl[base+idx] = f2bf(v - bf2f(h));
    }
    __syncthreads();
    const int b  = bid >> 7;                     // 128 blocks per batch
    const int n0 = (bid & 127) * 16;
    const int nn = tid & 15, d0 = tid >> 4;
#pragma unroll
    for (int d = 0; d < 8; d++){
      int dd = d0 + d*16;
      Xt[(long)b*262144 + (long)dd*2048 + n0 + nn] = f2bf(xs[nn][dd]);
    }
  } else if (bid < 1032){
    const int base = (bid - 1024) * 2048;
#pragma unroll
    for (int k = 0; k < 8; k++){
      int idx = base + k*256 + tid;
      int c = idx >> 7, f = idx & 127;
      w1t[idx] = f2bf(w1[f*128 + c]);            // w1T[c][f] = w1[f][c]
    }
  } else if (bid < 1096){
    float* x0s = (float*)smem;                   // 128
    float* ys  = x0s + 128;                      // 128
    float* red = ys + 128;                       // 256
    const int jj = bid - 1032;
    const int b = jj >> 3, j = jj & 7;
    if (tid < 128) x0s[tid] = x[(long)b*262144 + tid];
    __syncthreads();
    if (tid < 128){
      float a = 0.f;
      for (int f = 0; f < 128; f++) a += x0s[f] * wr[f*128 + tid];
      ys[tid] = a;
    }
    __syncthreads();
    const int m = j*256 + tid;
    const float4* xr = (const float4*)(x + ((long)b*2048 + m)*128);
    const float4* yv = (const float4*)ys;
    float acc = 0.f;
#pragma unroll
    for (int f = 0; f < 32; f++){
      float4 a = xr[f], c = yv[f];
      acc += a.x*c.x + a.y*c.y + a.z*c.z + a.w*c.w;
    }
    S0[b*2048 + m] = acc;
    red[tid] = acc;
    __syncthreads();
    for (int sft = 128; sft > 0; sft >>= 1){
      if (tid < sft) red[tid] = fmaxf(red[tid], red[tid + sft]);
      __syncthreads();
    }
    if (tid == 0) maxpart[jj] = red[0];
  } else {
    // ---- fused ygemm: 128 blocks x 256 thr (4 warps), 128 rows/block ----
    u16* sbh = (u16*)smem;                       // [c][f] bf16 swizzled, 32 KB
    u16* sbl = sbh + 16384;                      // +16384 u16 = +32 KB
    // stage wr^T hi/lo into LDS (self-converted from fp32)
    {
      const int c = tid & 127, f0 = (tid >> 7) * 64;
      const int key = (c & 7) << 4;
#pragma unroll
      for (int fi = 0; fi < 64; fi += 2){
        int f = f0 + fi;
        float v0 = wr[f*128 + c], v1 = wr[(f+1)*128 + c];
        u16 h0 = f2bf(v0), h1 = f2bf(v1);
        u32 hw = (u32)h0 | ((u32)h1 << 16);
        u32 lw = (u32)f2bf(v0 - bf2f(h0)) | ((u32)f2bf(v1 - bf2f(h1)) << 16);
        int byte = c*256 + ((((2*f) & ~15) ^ key) + ((2*f) & 15));
        *(u32*)((char*)sbh + byte) = hw;
        *(u32*)((char*)sbl + byte) = lw;
      }
    }
    __syncthreads();
    const int w = tid >> 6, lane = tid & 63, lr = lane & 15, g = lane >> 4;
    const long rowbase = (long)(bid - 1096)*128 + w*32;
    s16x8 ah[2][4], al[2][4];
#pragma unroll
    for (int rh = 0; rh < 2; rh++)
#pragma unroll
      for (int kc = 0; kc < 4; kc++){
        long r = rowbase + rh*16 + lr;
        const float4* px = (const float4*)(x + r*128 + kc*32 + g*8);
        float4 a = px[0], bV = px[1];
        u32 hh0, hh1, hh2, hh3, ll0, ll1, ll2, ll3;
        { u16 p=f2bf(a.x), q=f2bf(a.y); hh0=(u32)p|((u32)q<<16);
          ll0=(u32)f2bf(a.x-bf2f(p))|((u32)f2bf(a.y-bf2f(q))<<16); }
        { u16 p=f2bf(a.z), q=f2bf(a.w); hh1=(u32)p|((u32)q<<16);
          ll1=(u32)f2bf(a.z-bf2f(p))|((u32)f2bf(a.w-bf2f(q))<<16); }
        { u16 p=f2bf(bV.x), q=f2bf(bV.y); hh2=(u32)p|((u32)q<<16);
          ll2=(u32)f2bf(bV.x-bf2f(p))|((u32)f2bf(bV.y-bf2f(q))<<16); }
        { u16 p=f2bf(bV.z), q=f2bf(bV.w); hh3=(u32)p|((u32)q<<16);
          ll3=(u32)f2bf(bV.z-bf2f(p))|((u32)f2bf(bV.w-bf2f(q))<<16); }
        ah[rh][kc] = mk8(hh0,hh1,hh2,hh3);
        al[rh][kc] = mk8(ll0,ll1,ll2,ll3);
      }
    f32x4 acc[2][8];
#pragma unroll
    for (int rh = 0; rh < 2; rh++)
#pragma unroll
      for (int cg = 0; cg < 8; cg++) acc[rh][cg] = f4zero();
    const int swz = (lr & 7) << 4;
#pragma unroll
    for (int cg = 0; cg < 8; cg++){
      const int rowt = (cg*16 + lr) * 256;
#pragma unroll
      for (int kc = 0; kc < 4; kc++){
        int boff = rowt + ((kc*64 + g*16) ^ swz);
        s16x8 bh = *(const s16x8*)((const char*)sbh + boff);
        s16x8 bl = *(const s16x8*)((const char*)sbl + boff);
#pragma unroll
        for (int rh = 0; rh < 2; rh++){
          acc[rh][cg] = MFMA16(ah[rh][kc], bh, acc[rh][cg]);
          acc[rh][cg] = MFMA16(al[rh][kc], bh, acc[rh][cg]);
          acc[rh][cg] = MFMA16(ah[rh][kc], bl, acc[rh][cg]);
        }
      }
    }
#pragma unroll
    for (int rh = 0; rh < 2; rh++)
#pragma unroll
      for (int cg = 0; cg < 8; cg++)
#pragma unroll
        for (int r = 0; r < 4; r++){
          long q = rowbase + rh*16 + 4*g + r;  // C-layout: row=(l>>4)*4+reg
          int  c = cg*16 + lr;                 //           col=l&15
          float v = acc[rh][cg][r] * 1.4426950408889634f;
          u16 h = f2bf(v);
          yh[q*128 + c] = h;
          yl[q*128 + c] = f2bf(v - bf2f(h));
        }
  }
}

// ---------------------------------------------------------------------------
// K3: fused flash, 8-warp variant (verified round 10): 512 thr, 16 q/warp,
//   double-buffered LDS, KS=4. NO launch_bounds min-wave cap (spill rule).
// ---------------------------------------------------------------------------
__global__ __launch_bounds__(512) void k_flash(
    const u16* __restrict__ xh, const u16* __restrict__ xl, const u16* __restrict__ Xt,
    const u16* __restrict__ yh, const u16* __restrict__ yl,
    u16* __restrict__ Opart, float* __restrict__ mpart, float* __restrict__ lpart,
    int KS, int kslog)
{
  __shared__ u16 sxh[2][4096], sxl[2][4096];   // 32kv x 128f, XOR-swz (row&7)
  __shared__ u16 sxt[2][4096];                 // 128d x 32kv, XOR-swz (row&3)
  const int tid = threadIdx.x, bid = blockIdx.x;
  const int b     = bid & 7;                   // XCD b owns batch b
  const int inner = bid >> 3;
  const int s     = inner & (KS - 1);
  const int qbl   = inner >> kslog;
  const int qb    = b*16 + qbl;
  const int nspan = 2048 >> kslog;
  const int kv0   = s * nspan;
  const int ntiles = nspan >> 5;
  const int w = tid >> 6, lane = tid & 63, lr = lane & 15, g = lane >> 4;
  const long qrow = (long)qb*128 + w*16;       // 16 q-rows per warp

  // Y fragments (B-operands), hi/lo — 16 q-cols per warp
  s16x8 byh[4], byl[4];
#pragma unroll
  for (int kc = 0; kc < 4; kc++){
    long r = qrow + lr;
    byh[kc] = *(const s16x8*)(yh + r*128 + kc*32 + g*8);
    byl[kc] = *(const s16x8*)(yl + r*128 + kc*32 + g*8);
  }

  f32x4 o[8];                                  // O^T: [d-tile dg]
#pragma unroll
  for (int dg = 0; dg < 8; dg++) o[dg] = f4zero();
  float mrun = -1e30f, lrun = 0.f;

  const char* gxh  = (const char*)xh + ((long)b*2048 + kv0)*256;
  const char* gxl  = (const char*)xl + ((long)b*2048 + kv0)*256;
  const char* gxtb = (const char*)(Xt + (long)b*262144 + kv0);

  auto stage = [&](int bufi, int t){
    // one 1024B chunk per warp per array (8 warps cover 8192B)
    int off = w*1024 + lane*16;
    {  // x tiles: rows of 256B (16 granules), swizzle by row&7
      int row = off >> 8;
      int swo = off ^ ((row & 7) << 4);
      async16(gxh + (long)t*8192 + swo, &sxh[bufi][w*512]);
      async16(gxl + (long)t*8192 + swo, &sxl[bufi][w*512]);
    }
    {  // xt tile: rows of 64B (4 granules), swizzle by row&3 ONLY
      int row = off >> 6;
      int col = off & 63;
      int src = row*4096 + (col ^ ((row & 3) << 4));
      async16(gxtb + (long)t*64 + src, &sxt[bufi][w*512]);
    }
  };

  stage(0, 0);
  __syncthreads();

  for (int t = 0; t < ntiles; t++){
    const int cur = t & 1;
    if (t + 1 < ntiles) stage(cur ^ 1, t + 1);
    const char* pxh = (const char*)&sxh[cur][0];
    const char* pxl = (const char*)&sxl[cur][0];

    // ---- S^T tile [32kv x 16q], 3-term hi/lo split ----
    f32x4 sacc[2];                             // [kv-half ch]
    sacc[0] = f4zero(); sacc[1] = f4zero();
    __builtin_amdgcn_s_setprio(1);
#pragma unroll
    for (int ch = 0; ch < 2; ch++){
      const int rowb = ch*16 + lr;
#pragma unroll
      for (int kc = 0; kc < 4; kc++){
        const int boff = rowb*256 + ((kc*64 + g*16) ^ ((rowb & 7) << 4));
        s16x8 fh = *(const s16x8*)(pxh + boff);
        s16x8 fl = *(const s16x8*)(pxl + boff);
        sacc[ch] = MFMA16(fh, byh[kc], sacc[ch]);
        sacc[ch] = MFMA16(fl, byh[kc], sacc[ch]);
        sacc[ch] = MFMA16(fh, byl[kc], sacc[ch]);
      }
    }
    __builtin_amdgcn_s_setprio(0);

    // ---- lane-local online softmax (q = lr lives in this lane) ----
    float cm = fmaxf(fmaxf(fmaxf(sacc[0][0], sacc[0][1]),
                           fmaxf(sacc[0][2], sacc[0][3])),
                     fmaxf(fmaxf(sacc[1][0], sacc[1][1]),
                           fmaxf(sacc[1][2], sacc[1][3])));
    cm = fmaxf(cm, __shfl_xor(cm, 16, 64));
    cm = fmaxf(cm, __shfl_xor(cm, 32, 64));
    if (__any(cm > mrun + 8.f)){               // defer-max (log2 units, P<=256)
      float mn = fmaxf(mrun, cm);
      float sc = exp2f(mrun - mn);
#pragma unroll
      for (int dg = 0; dg < 8; dg++)
#pragma unroll
        for (int r = 0; r < 4; r++) o[dg][r] *= sc;
      lrun *= sc;
      mrun = mn;
    }
    float p[2][4];
#pragma unroll
    for (int ch = 0; ch < 2; ch++)
#pragma unroll
      for (int r = 0; r < 4; r++) p[ch][r] = exp2f(sacc[ch][r] - mrun);
    float ls = ((p[0][0] + p[0][1]) + (p[0][2] + p[0][3]))
             + ((p[1][0] + p[1][1]) + (p[1][2] + p[1][3]));
    ls += __shfl_xor(ls, 16, 64);
    ls += __shfl_xor(ls, 32, 64);
    lrun += ls;
    // lane (g,lr) holds P[q=lr][kv=16ch+4g+r]; B-frag needs kv=8g+j.
    // 4-lane-group permute: sA = 32*(g&1)+lr gives j0..3, sB=sA+16 j4..7, ch=g>>1
    s16x8 bpq;
    {
      u32 pw00 = pack2bf(p[0][0], p[0][1]);
      u32 pw01 = pack2bf(p[0][2], p[0][3]);
      u32 pw10 = pack2bf(p[1][0], p[1][1]);
      u32 pw11 = pack2bf(p[1][2], p[1][3]);
      int sA = ((g & 1) << 5) + lr;
      int sB = sA + 16;
      u32 a0 = (u32)__shfl((int)pw00, sA, 64);
      u32 a1 = (u32)__shfl((int)pw01, sA, 64);
      u32 a2 = (u32)__shfl((int)pw10, sA, 64);
      u32 a3 = (u32)__shfl((int)pw11, sA, 64);
      u32 b0 = (u32)__shfl((int)pw00, sB, 64);
      u32 b1 = (u32)__shfl((int)pw01, sB, 64);
      u32 b2 = (u32)__shfl((int)pw10, sB, 64);
      u32 b3 = (u32)__shfl((int)pw11, sB, 64);
      bool hi = (g >= 2);
      bpq = mk8(hi ? a2 : a0, hi ? a3 : a1, hi ? b2 : b0, hi ? b3 : b1);
    }

    // ---- O^T += Xt-frag (LDS swz) x P^T (regs), 2 halves to cap liveness ----
    __builtin_amdgcn_s_setprio(1);
#pragma unroll
    for (int half = 0; half < 2; half++){
      s16x8 ax[4];
#pragma unroll
      for (int i = 0; i < 4; i++){
        int row = (half*4 + i)*16 + lr;
        int phys = row*64 + ((g*16) ^ ((row & 3) << 4));
        ax[i] = *(const s16x8*)((const char*)&sxt[cur][0] + phys);
      }
#pragma unroll
      for (int i = 0; i < 4; i++){
        int dg = half*4 + i;
        o[dg] = MFMA16(ax[i], bpq, o[dg]);
      }
    }
    __builtin_amdgcn_s_setprio(0);
    __syncthreads();   // drains prefetch + guards buffer reuse
  }

  // ---- epilogue: O^T lane holds (d = dg*16+4g+r, q = qrow+lr) ----
  const long pid = bid;
  {
    int lq = w*16 + lr;
#pragma unroll
    for (int dg = 0; dg < 8; dg++){
      u32x2 pw;
      pw[0] = pack2bf(o[dg][0], o[dg][1]);
      pw[1] = pack2bf(o[dg][2], o[dg][3]);
      *(u32x2*)(Opart + pid*16384 + (long)lq*128 + dg*16 + 4*g) = pw;
    }
    if (g == 0){
      mpart[pid*128 + lq] = mrun;
      lpart[pid*128 + lq] = lrun;
    }
  }
}

// ---------------------------------------------------------------------------
// K4 (fused merge + layer1), 256 threads (4 waves — was 128/2, latency-bound):
//   Phase 1: merge KS partials -> swizzled LDS A1 tile (bf16), 4-wide.
//   Phase 2: x1 = relu(A1 @ w1 + x), 4 warps x 16 rows each.
// ---------------------------------------------------------------------------
__global__ __launch_bounds__(256) void k_mergeL1(
    const u16* __restrict__ Opart, const float* __restrict__ mpart, const float* __restrict__ lpart,
    const u16* __restrict__ w1t, const float* __restrict__ x, float* __restrict__ x1,
    int KS)
{
  __shared__ u16 sb[16384];                    // w1^T [c][f] swizzled
  __shared__ u16 sa[8192];                     // A1 tile [64][128] swizzled
  const int tid = threadIdx.x, bid = blockIdx.x;
#pragma unroll
  for (int k = 0; k < 8; k++){
    int off = (tid + k*256)*16;
    int row = off >> 8;
    *(s16x8*)((char*)sb + (off ^ ((row & 7) << 4))) = *(const s16x8*)((const char*)w1t + off);
  }
  const long R0 = (long)bid*64;
  // merge phase: 1024 granules (64 rows x 16), 4 per thread
#pragma unroll
  for (int k = 0; k < 4; k++){
    int gidx = tid + k*256;
    int lrow = gidx >> 4, gcol = gidx & 15;
    long R = R0 + lrow;
    int qb = (int)(R >> 7), r = (int)(R & 127);
    int pbase = qb >> 4, qblk = qb & 15;
    float m = -1e30f;
    for (int s = 0; s < KS; s++){
      long pid = (long)((qblk*KS + s)*8 + pbase);
      m = fmaxf(m, mpart[pid*128 + r]);
    }
    float ls = 0.f;
    float a0=0.f,a1=0.f,a2=0.f,a3=0.f,a4=0.f,a5=0.f,a6=0.f,a7=0.f;
    for (int s = 0; s < KS; s++){
      long pid = (long)((qblk*KS + s)*8 + pbase);
      float wgt = exp2f(mpart[pid*128 + r] - m);
      ls += lpart[pid*128 + r] * wgt;
      u32x4 v = *(const u32x4*)(Opart + pid*16384 + (long)r*128 + gcol*8);
      a0 += bf2f((u16)(v[0] & 0xffff)) * wgt;  a1 += bf2f((u16)(v[0] >> 16)) * wgt;
      a2 += bf2f((u16)(v[1] & 0xffff)) * wgt;  a3 += bf2f((u16)(v[1] >> 16)) * wgt;
      a4 += bf2f((u16)(v[2] & 0xffff)) * wgt;  a5 += bf2f((u16)(v[2] >> 16)) * wgt;
      a6 += bf2f((u16)(v[3] & 0xffff)) * wgt;  a7 += bf2f((u16)(v[3] >> 16)) * wgt;
    }
    float inv = 1.f / ls;
    u32x4 pw;
    pw[0] = pack2bf(a0*inv, a1*inv); pw[1] = pack2bf(a2*inv, a3*inv);
    pw[2] = pack2bf(a4*inv, a5*inv); pw[3] = pack2bf(a6*inv, a7*inv);
    int off = lrow*256 + gcol*16;
    *(u32x4*)((char*)sa + (off ^ ((lrow & 7) << 4))) = pw;
  }
  __syncthreads();
  // GEMM phase: 4 warps x 16 rows each (A rows = lane&15 of this warp's 16)
  const int w = tid >> 6, lane = tid & 63, lr = lane & 15, g = lane >> 4;
  const long rowbase = R0 + w*16;
  s16x8 aa[4];
#pragma unroll
  for (int kc = 0; kc < 4; kc++){
    int lrow = w*16 + lr;
    aa[kc] = *(const s16x8*)((const char*)sa +
               (lrow*256 + ((kc*64 + g*16) ^ ((lrow & 7) << 4))));
  }
  f32x4 acc[8];
#pragma unroll
  for (int cg = 0; cg < 8; cg++) acc[cg] = f4zero();
  const int swz = (lr & 7) << 4;
#pragma unroll
  for (int cg = 0; cg < 8; cg++){
    const int rowt = (cg*16 + lr)*256;
#pragma unroll
    for (int kc = 0; kc < 4; kc++){
      s16x8 bb = *(const s16x8*)((const char*)sb + rowt + ((kc*64 + g*16) ^ swz));
      acc[cg] = MFMA16(aa[kc], bb, acc[cg]);
    }
  }
#pragma unroll
  for (int cg = 0; cg < 8; cg++)
#pragma unroll
    for (int r = 0; r < 4; r++){
      long q = rowbase + 4*g + r;              // C: row=4g+r, col=lr
      int  c = cg*16 + lr;
      float v = acc[cg][r] + x[q*128 + c];
      x1[q*128 + c] = fmaxf(v, 0.f);
    }
}

// ---------------------------------------------------------------------------
// K5: A2 partials with unnormalized softmax weights (exact fp32 row-0 path).
//   256 blocks (32 chunks x 64 rows per batch) — was 64 blocks/25% of CUs.
// ---------------------------------------------------------------------------
__global__ __launch_bounds__(256) void k_a2(
    const float* __restrict__ S0, const float* __restrict__ maxpart,
    const float* __restrict__ x1, float* __restrict__ A2p, float* __restrict__ Lj)
{
  __shared__ float red[128];
  __shared__ float lred[2];
  const int tid = threadIdx.x, bid = blockIdx.x;
  const int b = bid >> 5, j = bid & 31;
  const int d = tid & 127, h = tid >> 7;
  float M = -1e30f;
#pragma unroll
  for (int jj = 0; jj < 8; jj++) M = fmaxf(M, maxpart[b*8 + jj]);
  float acc = 0.f, lacc = 0.f;
  for (int mi = j*64 + h; mi < j*64 + 64; mi += 2){
    float e = __expf(S0[b*2048 + mi] - M);
    acc  += e * x1[((long)b*2048 + mi)*128 + d];
    lacc += e;
  }
  if (h == 1) red[d] = acc;
  if (d == 0) lred[h] = lacc;
  __syncthreads();
  if (h == 0) A2p[(long)bid*128 + d] = acc + red[d];
  if (tid == 0) Lj[bid] = lred[0] + lred[1];
}

// K6: out = relu((A2/L) @ w2 + x1[:,0,:]) — sums 32 chunks per batch
__global__ __launch_bounds__(256) void k_out(
    const float* __restrict__ A2p, const float* __restrict__ Lj,
    const float* __restrict__ w2, const float* __restrict__ x1,
    float* __restrict__ out)
{
  __shared__ float a2s[2][128];
  const int tid = threadIdx.x, bid = blockIdx.x;
  const int b0 = bid*2;
  {
    int which = tid >> 7, f = tid & 127;
    int bb = b0 + which;
    float s = 0.f, L = 0.f;
#pragma unroll
    for (int jj = 0; jj < 32; jj++){
      s += A2p[(long)(bb*32 + jj)*128 + f];
      L += Lj[bb*32 + jj];
    }
    a2s[which][f] = s / L;
  }
  __syncthreads();
  const int which = tid >> 7, d = tid & 127;
  const int b = b0 + which;
  float acc = x1[(long)b*262144 + d];
  for (int f = 0; f < 128; f++)
    acc += a2s[which][f] * w2[f*128 + d];
  out[b*128 + d] = fmaxf(acc, 0.f);
}

// ---------------------------------------------------------------------------
extern "C" void kernel_launch(void* const* d_in, const int* in_sizes, int n_in,
                              void* d_out, int out_size, void* d_ws, size_t ws_size,
                              hipStream_t stream)
{
  const float* x  = (const float*)d_in[0];
  const float* w1 = (const float*)d_in[1];
  const float* w2 = (const float*)d_in[2];
  const float* wr = (const float*)d_in[3];
  float* out = (float*)d_out;
  char* ws = (char*)d_ws;

  u16*   xh      = (u16*)  (ws + 0);
  u16*   xl      = (u16*)  (ws + 4194304);
  u16*   Xt      = (u16*)  (ws + 8388608);
  u16*   yh      = (u16*)  (ws + 12582912);
  u16*   yl      = (u16*)  (ws + 16777216);
  u16*   w1t     = (u16*)  (ws + 20971520);
  float* S0      = (float*)(ws + 21004288);
  float* maxpart = (float*)(ws + 21069824);
  float* Lj      = (float*)(ws + 21070848);   // 256 floats
  float* A2p     = (float*)(ws + 21071872);   // 256*128*4 = 131072 B
  const size_t tail = 21202944;

  int KS = 4, kslog = 2;
  // per-KS bytes: mpart 64K + lpart 64K + Opart bf16 4M; x1 (8M) after Opart
  while (KS > 1 && tail + (size_t)KS*4325376ull + 8388608ull > ws_size){ KS >>= 1; kslog--; }
  float* mpart = (float*)(ws + tail);
  float* lpart = (float*)(ws + tail + (size_t)KS*65536);
  u16*   Opart = (u16*)  (ws + tail + (size_t)KS*131072);
  float* x1    = (float*)(ws + tail + (size_t)KS*131072 + (size_t)KS*4194304);

  k_prep   <<<1224, 256, 0, stream>>>(x, wr, w1, xh, xl, Xt, w1t, S0, maxpart, yh, yl);
  k_flash  <<<128*KS, 512, 0, stream>>>(xh, xl, Xt, yh, yl, Opart, mpart, lpart, KS, kslog);
  k_mergeL1<<<256, 256, 0, stream>>>(Opart, mpart, lpart, w1t, x, x1, KS);
  k_a2     <<<256, 256, 0, stream>>>(S0, maxpart, x1, A2p, Lj);
  k_out    <<<4, 256, 0, stream>>>(A2p, Lj, w2, x1, out);
}

// Round 12
// 88.673 us; speedup vs baseline: 3.9277x; 1.1248x over previous
//
#include <hip/hip_runtime.h>
#include <stdint.h>

typedef float  f32x4 __attribute__((ext_vector_type(4)));
typedef short  s16x8 __attribute__((ext_vector_type(8)));
typedef unsigned int u32;
typedef u32    u32x2 __attribute__((ext_vector_type(2)));
typedef u32    u32x4 __attribute__((ext_vector_type(4)));
typedef unsigned short u16;

#define MFMA16(a,b,c) __builtin_amdgcn_mfma_f32_16x16x32_bf16((a),(b),(c),0,0,0)

__device__ __forceinline__ u16 f2bf(float f){
  u32 u = __float_as_uint(f);
  return (u16)((u + 0x7fffu + ((u >> 16) & 1u)) >> 16);   // RNE
}
__device__ __forceinline__ float bf2f(u16 h){ return __uint_as_float(((u32)h) << 16); }
__device__ __forceinline__ u32 pack2bf(float a, float b){ return (u32)f2bf(a) | ((u32)f2bf(b) << 16); }
// truncation pack (round-to-zero): fine for P in [0,1], saves ~6 VALU ops/pair
__device__ __forceinline__ u32 packtrunc(float a, float b){
  return (__float_as_uint(a) >> 16) | (__float_as_uint(b) & 0xffff0000u);
}
__device__ __forceinline__ f32x4 f4zero(){ f32x4 z; z[0]=0.f; z[1]=0.f; z[2]=0.f; z[3]=0.f; return z; }
// register-only vector build (NO union: unions can defeat SROA -> scratch)
__device__ __forceinline__ s16x8 mk8(u32 a, u32 b, u32 c, u32 d){
  u32x4 w; w[0]=a; w[1]=b; w[2]=c; w[3]=d;
  return __builtin_bit_cast(s16x8, w);
}

// async global->LDS, 16B per lane; LDS dest is wave-uniform base + lane*16
__device__ __forceinline__ void async16(const void* g, void* l){
  __builtin_amdgcn_global_load_lds(
      (const __attribute__((address_space(1))) unsigned int*)g,
      (__attribute__((address_space(3))) unsigned int*)l, 16, 0, 0);
}

// ---------------------------------------------------------------------------
// K1 mega-prep. Block ranges (one branch each, no cross-block deps):
//   [0,1024):    x -> xh/xl split + Xt transpose
//   [1024,1032): w1^T bf16
//   [1032,1096): exact fp32 row-0 logits S0 + per-chunk maxpart
//   [1096,1224): ygemm: y = (x @ wr)*log2e, 3-term split from RAW fp32 x/wr
//   smem = 64 KB: the ygemm branch needs TWO 32 KB wr^T tables (hi+lo).
// ---------------------------------------------------------------------------
__global__ __launch_bounds__(256) void k_prep(
    const float* __restrict__ x, const float* __restrict__ wr, const float* __restrict__ w1,
    u16* __restrict__ xh, u16* __restrict__ xl, u16* __restrict__ Xt,
    u16* __restrict__ w1t, float* __restrict__ S0, float* __restrict__ maxpart,
    u16* __restrict__ yh, u16* __restrict__ yl)
{
  __shared__ __align__(16) char smem[65536];
  const int tid = threadIdx.x, bid = blockIdx.x;

  if (bid < 1024){
    float (*xs)[132] = (float(*)[132])smem;
    const long base = (long)bid * 2048;          // 16 rows * 128
#pragma unroll
    for (int k = 0; k < 8; k++){
      int idx = tid + k*256;
      float v = x[base + idx];
      xs[idx>>7][idx&127] = v;
      u16 h = f2bf(v);
      xh[base+idx] = h;
      xl[base+idx] = f2bf(v - bf2f(h));
    }
    __syncthreads();
    const int b  = bid >> 7;                     // 128 blocks per batch
    const int n0 = (bid & 127) * 16;
    const int nn = tid & 15, d0 = tid >> 4;
#pragma unroll
    for (int d = 0; d < 8; d++){
      int dd = d0 + d*16;
      Xt[(long)b*262144 + (long)dd*2048 + n0 + nn] = f2bf(xs[nn][dd]);
    }
  } else if (bid < 1032){
    const int base = (bid - 1024) * 2048;
#pragma unroll
    for (int k = 0; k < 8; k++){
      int idx = base + k*256 + tid;
      int c = idx >> 7, f = idx & 127;
      w1t[idx] = f2bf(w1[f*128 + c]);            // w1T[c][f] = w1[f][c]
    }
  } else if (bid < 1096){
    float* x0s = (float*)smem;                   // 128
    float* ys  = x0s + 128;                      // 128
    float* red = ys + 128;                       // 256
    const int jj = bid - 1032;
    const int b = jj >> 3, j = jj & 7;
    if (tid < 128) x0s[tid] = x[(long)b*262144 + tid];
    __syncthreads();
    if (tid < 128){
      float a = 0.f;
      for (int f = 0; f < 128; f++) a += x0s[f] * wr[f*128 + tid];
      ys[tid] = a;
    }
    __syncthreads();
    const int m = j*256 + tid;
    const float4* xr = (const float4*)(x + ((long)b*2048 + m)*128);
    const float4* yv = (const float4*)ys;
    float acc = 0.f;
#pragma unroll
    for (int f = 0; f < 32; f++){
      float4 a = xr[f], c = yv[f];
      acc += a.x*c.x + a.y*c.y + a.z*c.z + a.w*c.w;
    }
    S0[b*2048 + m] = acc;
    red[tid] = acc;
    __syncthreads();
    for (int sft = 128; sft > 0; sft >>= 1){
      if (tid < sft) red[tid] = fmaxf(red[tid], red[tid + sft]);
      __syncthreads();
    }
    if (tid == 0) maxpart[jj] = red[0];
  } else {
    // ---- fused ygemm: 128 blocks x 256 thr (4 warps), 128 rows/block ----
    u16* sbh = (u16*)smem;                       // [c][f] bf16 swizzled, 32 KB
    u16* sbl = sbh + 16384;                      // +16384 u16 = +32 KB
    {
      const int c = tid & 127, f0 = (tid >> 7) * 64;
      const int key = (c & 7) << 4;
#pragma unroll
      for (int fi = 0; fi < 64; fi += 2){
        int f = f0 + fi;
        float v0 = wr[f*128 + c], v1 = wr[(f+1)*128 + c];
        u16 h0 = f2bf(v0), h1 = f2bf(v1);
        u32 hw = (u32)h0 | ((u32)h1 << 16);
        u32 lw = (u32)f2bf(v0 - bf2f(h0)) | ((u32)f2bf(v1 - bf2f(h1)) << 16);
        int byte = c*256 + ((((2*f) & ~15) ^ key) + ((2*f) & 15));
        *(u32*)((char*)sbh + byte) = hw;
        *(u32*)((char*)sbl + byte) = lw;
      }
    }
    __syncthreads();
    const int w = tid >> 6, lane = tid & 63, lr = lane & 15, g = lane >> 4;
    const long rowbase = (long)(bid - 1096)*128 + w*32;
    s16x8 ah[2][4], al[2][4];
#pragma unroll
    for (int rh = 0; rh < 2; rh++)
#pragma unroll
      for (int kc = 0; kc < 4; kc++){
        long r = rowbase + rh*16 + lr;
        const float4* px = (const float4*)(x + r*128 + kc*32 + g*8);
        float4 a = px[0], bV = px[1];
        u32 hh0, hh1, hh2, hh3, ll0, ll1, ll2, ll3;
        { u16 p=f2bf(a.x), q=f2bf(a.y); hh0=(u32)p|((u32)q<<16);
          ll0=(u32)f2bf(a.x-bf2f(p))|((u32)f2bf(a.y-bf2f(q))<<16); }
        { u16 p=f2bf(a.z), q=f2bf(a.w); hh1=(u32)p|((u32)q<<16);
          ll1=(u32)f2bf(a.z-bf2f(p))|((u32)f2bf(a.w-bf2f(q))<<16); }
        { u16 p=f2bf(bV.x), q=f2bf(bV.y); hh2=(u32)p|((u32)q<<16);
          ll2=(u32)f2bf(bV.x-bf2f(p))|((u32)f2bf(bV.y-bf2f(q))<<16); }
        { u16 p=f2bf(bV.z), q=f2bf(bV.w); hh3=(u32)p|((u32)q<<16);
          ll3=(u32)f2bf(bV.z-bf2f(p))|((u32)f2bf(bV.w-bf2f(q))<<16); }
        ah[rh][kc] = mk8(hh0,hh1,hh2,hh3);
        al[rh][kc] = mk8(ll0,ll1,ll2,ll3);
      }
    f32x4 acc[2][8];
#pragma unroll
    for (int rh = 0; rh < 2; rh++)
#pragma unroll
      for (int cg = 0; cg < 8; cg++) acc[rh][cg] = f4zero();
    const int swz = (lr & 7) << 4;
#pragma unroll
    for (int cg = 0; cg < 8; cg++){
      const int rowt = (cg*16 + lr) * 256;
#pragma unroll
      for (int kc = 0; kc < 4; kc++){
        int boff = rowt + ((kc*64 + g*16) ^ swz);
        s16x8 bh = *(const s16x8*)((const char*)sbh + boff);
        s16x8 bl = *(const s16x8*)((const char*)sbl + boff);
#pragma unroll
        for (int rh = 0; rh < 2; rh++){
          acc[rh][cg] = MFMA16(ah[rh][kc], bh, acc[rh][cg]);
          acc[rh][cg] = MFMA16(al[rh][kc], bh, acc[rh][cg]);
          acc[rh][cg] = MFMA16(ah[rh][kc], bl, acc[rh][cg]);
        }
      }
    }
#pragma unroll
    for (int rh = 0; rh < 2; rh++)
#pragma unroll
      for (int cg = 0; cg < 8; cg++)
#pragma unroll
        for (int r = 0; r < 4; r++){
          long q = rowbase + rh*16 + 4*g + r;  // C-layout: row=(l>>4)*4+reg
          int  c = cg*16 + lr;                 //           col=l&15
          float v = acc[rh][cg][r] * 1.4426950408889634f;
          u16 h = f2bf(v);
          yh[q*128 + c] = h;
          yl[q*128 + c] = f2bf(v - bf2f(h));
        }
  }
}

// ---------------------------------------------------------------------------
// K3: fused flash, 8-warp (verified round 10/11 structure), with hoisted LDS
//   addressing: one 48KB LDS block, layout (bytes):
//     XH: buf*8192 ; XL: 16384 + buf*8192 ; XT: 32768 + buf*8192
//   Physical layout identical to the verified 3-array version; all per-tile
//   swizzle math collapses to per-lane bases + compile-time ds offsets
//   (uses (ch*16+lr)&7==lr&7 and (dg*16+lr)&3==lr&3).
//   NO launch_bounds min-wave cap (spill rule: rounds 2/4/6).
// ---------------------------------------------------------------------------
__global__ __launch_bounds__(512) void k_flash(
    const u16* __restrict__ xh, const u16* __restrict__ xl, const u16* __restrict__ Xt,
    const u16* __restrict__ yh, const u16* __restrict__ yl,
    u16* __restrict__ Opart, float* __restrict__ mpart, float* __restrict__ lpart,
    int KS, int kslog)
{
  __shared__ __align__(16) char lds[49152];
  const int tid = threadIdx.x, bid = blockIdx.x;
  const int b     = bid & 7;                   // XCD b owns batch b
  const int inner = bid >> 3;
  const int s     = inner & (KS - 1);
  const int qbl   = inner >> kslog;
  const int qb    = b*16 + qbl;
  const int nspan = 2048 >> kslog;
  const int kv0   = s * nspan;
  const int ntiles = nspan >> 5;
  const int w = tid >> 6, lane = tid & 63, lr = lane & 15, g = lane >> 4;
  const long qrow = (long)qb*128 + w*16;       // 16 q-rows per warp

  // ---- hoisted per-lane constants ----
  const int soff = w*1024 + lane*16;
  const int sswo = soff ^ (((soff >> 8) & 7) << 4);        // xh/xl src swz
  const int trow = soff >> 6;
  const int tsrc = trow*4096 + ((soff & 63) ^ ((trow & 3) << 4)); // xt src swz
  const int bS0 = lr*256 + (( 0 + g*16) ^ ((lr & 7) << 4));
  const int bS1 = lr*256 + (( 64 + g*16) ^ ((lr & 7) << 4));
  const int bS2 = lr*256 + ((128 + g*16) ^ ((lr & 7) << 4));
  const int bS3 = lr*256 + ((192 + g*16) ^ ((lr & 7) << 4));
  const int bPV = lr*64 + ((g*16) ^ ((lr & 3) << 4));

  // Y fragments (B-operands), hi/lo — 16 q-cols per warp
  s16x8 byh[4], byl[4];
#pragma unroll
  for (int kc = 0; kc < 4; kc++){
    long r = qrow + lr;
    byh[kc] = *(const s16x8*)(yh + r*128 + kc*32 + g*8);
    byl[kc] = *(const s16x8*)(yl + r*128 + kc*32 + g*8);
  }

  f32x4 o[8];                                  // O^T: [d-tile dg]
#pragma unroll
  for (int dg = 0; dg < 8; dg++) o[dg] = f4zero();
  float mrun = -1e30f, lrun = 0.f;

  const char* gxh  = (const char*)xh + ((long)b*2048 + kv0)*256;
  const char* gxl  = (const char*)xl + ((long)b*2048 + kv0)*256;
  const char* gxtb = (const char*)(Xt + (long)b*262144 + kv0);

  auto stage = [&](int bufi, int t){
    char* dst = lds + bufi*8192 + w*1024;      // wave-uniform dest
    async16(gxh  + (long)t*8192 + sswo, dst);
    async16(gxl  + (long)t*8192 + sswo, dst + 16384);
    async16(gxtb + (long)t*64   + tsrc, dst + 32768);
  };

  stage(0, 0);
  __syncthreads();

  for (int t = 0; t < ntiles; t++){
    const int cur = t & 1;
    if (t + 1 < ntiles) stage(cur ^ 1, t + 1);
    const char* pb = lds + cur*8192;
    const char* a0 = pb + bS0;
    const char* a1 = pb + bS1;
    const char* a2 = pb + bS2;
    const char* a3 = pb + bS3;

    // ---- S^T tile [32kv x 16q], 3-term hi/lo split ----
    f32x4 sacc[2];                             // [kv-half ch]
    sacc[0] = f4zero(); sacc[1] = f4zero();
    __builtin_amdgcn_s_setprio(1);
#pragma unroll
    for (int ch = 0; ch < 2; ch++){
      const int co = ch*4096;                  // fh at co, fl at 16384+co
      s16x8 fh, fl;
      fh = *(const s16x8*)(a0 + co); fl = *(const s16x8*)(a0 + 16384 + co);
      sacc[ch] = MFMA16(fh, byh[0], sacc[ch]);
      sacc[ch] = MFMA16(fl, byh[0], sacc[ch]);
      sacc[ch] = MFMA16(fh, byl[0], sacc[ch]);
      fh = *(const s16x8*)(a1 + co); fl = *(const s16x8*)(a1 + 16384 + co);
      sacc[ch] = MFMA16(fh, byh[1], sacc[ch]);
      sacc[ch] = MFMA16(fl, byh[1], sacc[ch]);
      sacc[ch] = MFMA16(fh, byl[1], sacc[ch]);
      fh = *(const s16x8*)(a2 + co); fl = *(const s16x8*)(a2 + 16384 + co);
      sacc[ch] = MFMA16(fh, byh[2], sacc[ch]);
      sacc[ch] = MFMA16(fl, byh[2], sacc[ch]);
      sacc[ch] = MFMA16(fh, byl[2], sacc[ch]);
      fh = *(const s16x8*)(a3 + co); fl = *(const s16x8*)(a3 + 16384 + co);
      sacc[ch] = MFMA16(fh, byh[3], sacc[ch]);
      sacc[ch] = MFMA16(fl, byh[3], sacc[ch]);
      sacc[ch] = MFMA16(fh, byl[3], sacc[ch]);
    }
    __builtin_amdgcn_s_setprio(0);

    // ---- lane-local online softmax (q = lr lives in this lane) ----
    float cm = fmaxf(fmaxf(fmaxf(sacc[0][0], sacc[0][1]),
                           fmaxf(sacc[0][2], sacc[0][3])),
                     fmaxf(fmaxf(sacc[1][0], sacc[1][1]),
                           fmaxf(sacc[1][2], sacc[1][3])));
    cm = fmaxf(cm, __shfl_xor(cm, 16, 64));
    cm = fmaxf(cm, __shfl_xor(cm, 32, 64));
    if (__any(cm > mrun + 8.f)){               // defer-max (log2 units, P<=256)
      float mn = fmaxf(mrun, cm);
      float sc = exp2f(mrun - mn);
#pragma unroll
      for (int dg = 0; dg < 8; dg++)
#pragma unroll
        for (int r = 0; r < 4; r++) o[dg][r] *= sc;
      lrun *= sc;
      mrun = mn;
    }
    float p[2][4];
#pragma unroll
    for (int ch = 0; ch < 2; ch++)
#pragma unroll
      for (int r = 0; r < 4; r++) p[ch][r] = exp2f(sacc[ch][r] - mrun);
    float ls = ((p[0][0] + p[0][1]) + (p[0][2] + p[0][3]))
             + ((p[1][0] + p[1][1]) + (p[1][2] + p[1][3]));
    ls += __shfl_xor(ls, 16, 64);
    ls += __shfl_xor(ls, 32, 64);
    lrun += ls;
    // lane (g,lr) holds P[q=lr][kv=16ch+4g+r]; B-frag needs kv=8g+j.
    // 4-lane-group permute: sA = 32*(g&1)+lr gives j0..3, sB=sA+16 j4..7, ch=g>>1
    s16x8 bpq;
    {
      u32 pw00 = packtrunc(p[0][0], p[0][1]);
      u32 pw01 = packtrunc(p[0][2], p[0][3]);
      u32 pw10 = packtrunc(p[1][0], p[1][1]);
      u32 pw11 = packtrunc(p[1][2], p[1][3]);
      int sA = ((g & 1) << 5) + lr;
      int sB = sA + 16;
      u32 a0s = (u32)__shfl((int)pw00, sA, 64);
      u32 a1s = (u32)__shfl((int)pw01, sA, 64);
      u32 a2s = (u32)__shfl((int)pw10, sA, 64);
      u32 a3s = (u32)__shfl((int)pw11, sA, 64);
      u32 b0s = (u32)__shfl((int)pw00, sB, 64);
      u32 b1s = (u32)__shfl((int)pw01, sB, 64);
      u32 b2s = (u32)__shfl((int)pw10, sB, 64);
      u32 b3s = (u32)__shfl((int)pw11, sB, 64);
      bool hi = (g >= 2);
      bpq = mk8(hi ? a2s : a0s, hi ? a3s : a1s, hi ? b2s : b0s, hi ? b3s : b1s);
    }

    // ---- O^T += Xt-frag (LDS swz) x P^T (regs) ----
    const char* ap = pb + 32768 + bPV;
    __builtin_amdgcn_s_setprio(1);
#pragma unroll
    for (int half = 0; half < 2; half++){
      s16x8 ax[4];
#pragma unroll
      for (int i = 0; i < 4; i++)
        ax[i] = *(const s16x8*)(ap + (half*4 + i)*1024);
#pragma unroll
      for (int i = 0; i < 4; i++)
        o[half*4 + i] = MFMA16(ax[i], bpq, o[half*4 + i]);
    }
    __builtin_amdgcn_s_setprio(0);
    __syncthreads();   // drains prefetch + guards buffer reuse
  }

  // ---- epilogue: O^T lane holds (d = dg*16+4g+r, q = qrow+lr) ----
  const long pid = bid;
  {
    int lq = w*16 + lr;
#pragma unroll
    for (int dg = 0; dg < 8; dg++){
      u32x2 pw;
      pw[0] = pack2bf(o[dg][0], o[dg][1]);
      pw[1] = pack2bf(o[dg][2], o[dg][3]);
      *(u32x2*)(Opart + pid*16384 + (long)lq*128 + dg*16 + 4*g) = pw;
    }
    if (g == 0){
      mpart[pid*128 + lq] = mrun;
      lpart[pid*128 + lq] = lrun;
    }
  }
}

// ---------------------------------------------------------------------------
// K4 (fused merge + layer1 + a2-partial): 256 blocks x 256 thr, 64 rows each.
//   Phase 1: merge KS partials -> swizzled LDS A1 tile; e-table from S0.
//   Phase 2: x1 = relu(A1 @ w1 + x) IN REGISTERS (never hits HBM except row0).
//   Phase 3: A2p[bid] = sum_q e_q * x1[q,:], Lj[bid] = sum_q e_q.
// ---------------------------------------------------------------------------
__global__ __launch_bounds__(256) void k_mergeL1(
    const u16* __restrict__ Opart, const float* __restrict__ mpart, const float* __restrict__ lpart,
    const u16* __restrict__ w1t, const float* __restrict__ x,
    const float* __restrict__ S0, const float* __restrict__ maxpart,
    float* __restrict__ A2p, float* __restrict__ Lj, float* __restrict__ x1r0,
    int KS)
{
  __shared__ u16 sb[16384];                    // w1^T [c][f] swizzled (32KB)
  __shared__ u16 sa[8192];                     // A1 tile [64][128] swz (16KB)
  __shared__ float eS[64];
  __shared__ float redw[4][128];
  const int tid = threadIdx.x, bid = blockIdx.x;
  const int bb = bid >> 5;                     // batch
#pragma unroll
  for (int k = 0; k < 8; k++){
    int off = (tid + k*256)*16;
    int row = off >> 8;
    *(s16x8*)((char*)sb + (off ^ ((row & 7) << 4))) = *(const s16x8*)((const char*)w1t + off);
  }
  if (tid < 64){
    float M = -1e30f;
#pragma unroll
    for (int jj = 0; jj < 8; jj++) M = fmaxf(M, maxpart[bb*8 + jj]);
    eS[tid] = __expf(S0[bb*2048 + (bid & 31)*64 + tid] - M);
  }
  const long R0 = (long)bid*64;
  // merge phase: 1024 granules (64 rows x 16), 4 per thread
#pragma unroll
  for (int k = 0; k < 4; k++){
    int gidx = tid + k*256;
    int lrow = gidx >> 4, gcol = gidx & 15;
    long R = R0 + lrow;
    int qb = (int)(R >> 7), r = (int)(R & 127);
    int pbase = qb >> 4, qblk = qb & 15;
    float m = -1e30f;
    for (int s = 0; s < KS; s++){
      long pid = (long)((qblk*KS + s)*8 + pbase);
      m = fmaxf(m, mpart[pid*128 + r]);
    }
    float ls = 0.f;
    float a0=0.f,a1=0.f,a2=0.f,a3=0.f,a4=0.f,a5=0.f,a6=0.f,a7=0.f;
    for (int s = 0; s < KS; s++){
      long pid = (long)((qblk*KS + s)*8 + pbase);
      float wgt = exp2f(mpart[pid*128 + r] - m);
      ls += lpart[pid*128 + r] * wgt;
      u32x4 v = *(const u32x4*)(Opart + pid*16384 + (long)r*128 + gcol*8);
      a0 += bf2f((u16)(v[0] & 0xffff)) * wgt;  a1 += bf2f((u16)(v[0] >> 16)) * wgt;
      a2 += bf2f((u16)(v[1] & 0xffff)) * wgt;  a3 += bf2f((u16)(v[1] >> 16)) * wgt;
      a4 += bf2f((u16)(v[2] & 0xffff)) * wgt;  a5 += bf2f((u16)(v[2] >> 16)) * wgt;
      a6 += bf2f((u16)(v[3] & 0xffff)) * wgt;  a7 += bf2f((u16)(v[3] >> 16)) * wgt;
    }
    float inv = 1.f / ls;
    u32x4 pw;
    pw[0] = pack2bf(a0*inv, a1*inv); pw[1] = pack2bf(a2*inv, a3*inv);
    pw[2] = pack2bf(a4*inv, a5*inv); pw[3] = pack2bf(a6*inv, a7*inv);
    int off = lrow*256 + gcol*16;
    *(u32x4*)((char*)sa + (off ^ ((lrow & 7) << 4))) = pw;
  }
  __syncthreads();
  // GEMM phase: 4 warps x 16 rows each
  const int w = tid >> 6, lane = tid & 63, lr = lane & 15, g = lane >> 4;
  const long rowbase = R0 + w*16;
  s16x8 aa[4];
#pragma unroll
  for (int kc = 0; kc < 4; kc++){
    int lrow = w*16 + lr;
    aa[kc] = *(const s16x8*)((const char*)sa +
               (lrow*256 + ((kc*64 + g*16) ^ ((lrow & 7) << 4))));
  }
  f32x4 acc[8];
#pragma unroll
  for (int cg = 0; cg < 8; cg++) acc[cg] = f4zero();
  const int swz = (lr & 7) << 4;
#pragma unroll
  for (int cg = 0; cg < 8; cg++){
    const int rowt = (cg*16 + lr)*256;
#pragma unroll
    for (int kc = 0; kc < 4; kc++){
      s16x8 bV = *(const s16x8*)((const char*)sb + rowt + ((kc*64 + g*16) ^ swz));
      acc[cg] = MFMA16(aa[kc], bV, acc[cg]);
    }
  }
  // x1 values in-register: vv[cg][r] for q = rowbase + 4g + r, c = cg*16+lr
  const float e0 = eS[w*16 + 4*g + 0];
  const float e1 = eS[w*16 + 4*g + 1];
  const float e2 = eS[w*16 + 4*g + 2];
  const float e3 = eS[w*16 + 4*g + 3];
  float sA2[8];
#pragma unroll
  for (int cg = 0; cg < 8; cg++){
    int c = cg*16 + lr;
    f32x4 vv;
#pragma unroll
    for (int r = 0; r < 4; r++){
      long q = rowbase + 4*g + r;
      vv[r] = fmaxf(acc[cg][r] + x[q*128 + c], 0.f);
    }
    if (((bid & 31) == 0) && w == 0 && g == 0)
      x1r0[bb*128 + c] = vv[0];                // batch row 0
    sA2[cg] = e0*vv[0] + e1*vv[1] + e2*vv[2] + e3*vv[3];
  }
#pragma unroll
  for (int cg = 0; cg < 8; cg++){
    sA2[cg] += __shfl_xor(sA2[cg], 16, 64);
    sA2[cg] += __shfl_xor(sA2[cg], 32, 64);
  }
  if (g == 0){
#pragma unroll
    for (int cg = 0; cg < 8; cg++) redw[w][cg*16 + lr] = sA2[cg];
  }
  __syncthreads();
  if (tid < 128)
    A2p[(long)bid*128 + tid] = redw[0][tid] + redw[1][tid] + redw[2][tid] + redw[3][tid];
  if ((tid >> 6) == 2){
    float v = eS[tid & 63];
    v += __shfl_xor(v, 1, 64);  v += __shfl_xor(v, 2, 64);
    v += __shfl_xor(v, 4, 64);  v += __shfl_xor(v, 8, 64);
    v += __shfl_xor(v, 16, 64); v += __shfl_xor(v, 32, 64);
    if ((tid & 63) == 0) Lj[bid] = v;
  }
}

// K5: out = relu((A2/L) @ w2 + x1[:,0,:]) — sums 32 chunks per batch
__global__ __launch_bounds__(256) void k_out(
    const float* __restrict__ A2p, const float* __restrict__ Lj,
    const float* __restrict__ w2, const float* __restrict__ x1r0,
    float* __restrict__ out)
{
  __shared__ float a2s[2][128];
  const int tid = threadIdx.x, bid = blockIdx.x;
  const int b0 = bid*2;
  {
    int which = tid >> 7, f = tid & 127;
    int bb = b0 + which;
    float s = 0.f, L = 0.f;
#pragma unroll
    for (int jj = 0; jj < 32; jj++){
      s += A2p[(long)(bb*32 + jj)*128 + f];
      L += Lj[bb*32 + jj];
    }
    a2s[which][f] = s / L;
  }
  __syncthreads();
  const int which = tid >> 7, d = tid & 127;
  const int b = b0 + which;
  float acc = x1r0[b*128 + d];
  for (int f = 0; f < 128; f++)
    acc += a2s[which][f] * w2[f*128 + d];
  out[b*128 + d] = fmaxf(acc, 0.f);
}

// ---------------------------------------------------------------------------
extern "C" void kernel_launch(void* const* d_in, const int* in_sizes, int n_in,
                              void* d_out, int out_size, void* d_ws, size_t ws_size,
                              hipStream_t stream)
{
  const float* x  = (const float*)d_in[0];
  const float* w1 = (const float*)d_in[1];
  const float* w2 = (const float*)d_in[2];
  const float* wr = (const float*)d_in[3];
  float* out = (float*)d_out;
  char* ws = (char*)d_ws;

  u16*   xh      = (u16*)  (ws + 0);
  u16*   xl      = (u16*)  (ws + 4194304);
  u16*   Xt      = (u16*)  (ws + 8388608);
  u16*   yh      = (u16*)  (ws + 12582912);
  u16*   yl      = (u16*)  (ws + 16777216);
  u16*   w1t     = (u16*)  (ws + 20971520);
  float* S0      = (float*)(ws + 21004288);
  float* maxpart = (float*)(ws + 21069824);
  float* Lj      = (float*)(ws + 21070848);   // 256 floats
  float* A2p     = (float*)(ws + 21071872);   // 256*128*4 = 131072 B
  float* x1r0    = (float*)(ws + 21202944);   // 8*128*4 = 4096 B
  const size_t tail = 21207040;

  int KS = 4, kslog = 2;
  // per-KS bytes: mpart 64K + lpart 64K + Opart bf16 4M
  while (KS > 1 && tail + (size_t)KS*4325376ull > ws_size){ KS >>= 1; kslog--; }
  float* mpart = (float*)(ws + tail);
  float* lpart = (float*)(ws + tail + (size_t)KS*65536);
  u16*   Opart = (u16*)  (ws + tail + (size_t)KS*131072);

  k_prep   <<<1224, 256, 0, stream>>>(x, wr, w1, xh, xl, Xt, w1t, S0, maxpart, yh, yl);
  k_flash  <<<128*KS, 512, 0, stream>>>(xh, xl, Xt, yh, yl, Opart, mpart, lpart, KS, kslog);
  k_mergeL1<<<256, 256, 0, stream>>>(Opart, mpart, lpart, w1t, x, S0, maxpart, A2p, Lj, x1r0, KS);
  k_out    <<<4, 256, 0, stream>>>(A2p, Lj, w2, x1r0, out);
}

// Round 13
// 82.877 us; speedup vs baseline: 4.2024x; 1.0699x over previous
//
#include <hip/hip_runtime.h>
#include <stdint.h>

typedef float  f32x4 __attribute__((ext_vector_type(4)));
typedef short  s16x8 __attribute__((ext_vector_type(8)));
typedef unsigned int u32;
typedef u32    u32x2 __attribute__((ext_vector_type(2)));
typedef u32    u32x4 __attribute__((ext_vector_type(4)));
typedef unsigned short u16;

#define MFMA16(a,b,c) __builtin_amdgcn_mfma_f32_16x16x32_bf16((a),(b),(c),0,0,0)

__device__ __forceinline__ u16 f2bf(float f){
  u32 u = __float_as_uint(f);
  return (u16)((u + 0x7fffu + ((u >> 16) & 1u)) >> 16);   // RNE
}
__device__ __forceinline__ float bf2f(u16 h){ return __uint_as_float(((u32)h) << 16); }
__device__ __forceinline__ u32 pack2bf(float a, float b){ return (u32)f2bf(a) | ((u32)f2bf(b) << 16); }
// truncation pack (round-to-zero): fine for P in [0,1]
__device__ __forceinline__ u32 packtrunc(float a, float b){
  return (__float_as_uint(a) >> 16) | (__float_as_uint(b) & 0xffff0000u);
}
__device__ __forceinline__ f32x4 f4zero(){ f32x4 z; z[0]=0.f; z[1]=0.f; z[2]=0.f; z[3]=0.f; return z; }
// register-only vector build (NO union: unions can defeat SROA -> scratch)
__device__ __forceinline__ s16x8 mk8(u32 a, u32 b, u32 c, u32 d){
  u32x4 w; w[0]=a; w[1]=b; w[2]=c; w[3]=d;
  return __builtin_bit_cast(s16x8, w);
}

// async global->LDS, 16B per lane; LDS dest is wave-uniform base + lane*16
__device__ __forceinline__ void async16(const void* g, void* l){
  __builtin_amdgcn_global_load_lds(
      (const __attribute__((address_space(1))) unsigned int*)g,
      (__attribute__((address_space(3))) unsigned int*)l, 16, 0, 0);
}

// ---------------------------------------------------------------------------
// K1 mega-prep (unchanged, verified). Block ranges:
//   [0,1024): x -> xh/xl + Xt; [1024,1032): w1^T; [1032,1096): S0+maxpart;
//   [1096,1224): ygemm (3-term split from raw fp32, self-contained).
// ---------------------------------------------------------------------------
__global__ __launch_bounds__(256) void k_prep(
    const float* __restrict__ x, const float* __restrict__ wr, const float* __restrict__ w1,
    u16* __restrict__ xh, u16* __restrict__ xl, u16* __restrict__ Xt,
    u16* __restrict__ w1t, float* __restrict__ S0, float* __restrict__ maxpart,
    u16* __restrict__ yh, u16* __restrict__ yl)
{
  __shared__ __align__(16) char smem[65536];
  const int tid = threadIdx.x, bid = blockIdx.x;

  if (bid < 1024){
    float (*xs)[132] = (float(*)[132])smem;
    const long base = (long)bid * 2048;          // 16 rows * 128
#pragma unroll
    for (int k = 0; k < 8; k++){
      int idx = tid + k*256;
      float v = x[base + idx];
      xs[idx>>7][idx&127] = v;
      u16 h = f2bf(v);
      xh[base+idx] = h;
      xl[base+idx] = f2bf(v - bf2f(h));
    }
    __syncthreads();
    const int b  = bid >> 7;                     // 128 blocks per batch
    const int n0 = (bid & 127) * 16;
    const int nn = tid & 15, d0 = tid >> 4;
#pragma unroll
    for (int d = 0; d < 8; d++){
      int dd = d0 + d*16;
      Xt[(long)b*262144 + (long)dd*2048 + n0 + nn] = f2bf(xs[nn][dd]);
    }
  } else if (bid < 1032){
    const int base = (bid - 1024) * 2048;
#pragma unroll
    for (int k = 0; k < 8; k++){
      int idx = base + k*256 + tid;
      int c = idx >> 7, f = idx & 127;
      w1t[idx] = f2bf(w1[f*128 + c]);            // w1T[c][f] = w1[f][c]
    }
  } else if (bid < 1096){
    float* x0s = (float*)smem;                   // 128
    float* ys  = x0s + 128;                      // 128
    float* red = ys + 128;                       // 256
    const int jj = bid - 1032;
    const int b = jj >> 3, j = jj & 7;
    if (tid < 128) x0s[tid] = x[(long)b*262144 + tid];
    __syncthreads();
    if (tid < 128){
      float a = 0.f;
      for (int f = 0; f < 128; f++) a += x0s[f] * wr[f*128 + tid];
      ys[tid] = a;
    }
    __syncthreads();
    const int m = j*256 + tid;
    const float4* xr = (const float4*)(x + ((long)b*2048 + m)*128);
    const float4* yv = (const float4*)ys;
    float acc = 0.f;
#pragma unroll
    for (int f = 0; f < 32; f++){
      float4 a = xr[f], c = yv[f];
      acc += a.x*c.x + a.y*c.y + a.z*c.z + a.w*c.w;
    }
    S0[b*2048 + m] = acc;
    red[tid] = acc;
    __syncthreads();
    for (int sft = 128; sft > 0; sft >>= 1){
      if (tid < sft) red[tid] = fmaxf(red[tid], red[tid + sft]);
      __syncthreads();
    }
    if (tid == 0) maxpart[jj] = red[0];
  } else {
    // ---- fused ygemm: 128 blocks x 256 thr (4 warps), 128 rows/block ----
    u16* sbh = (u16*)smem;                       // [c][f] bf16 swizzled, 32 KB
    u16* sbl = sbh + 16384;                      // +16384 u16 = +32 KB
    {
      const int c = tid & 127, f0 = (tid >> 7) * 64;
      const int key = (c & 7) << 4;
#pragma unroll
      for (int fi = 0; fi < 64; fi += 2){
        int f = f0 + fi;
        float v0 = wr[f*128 + c], v1 = wr[(f+1)*128 + c];
        u16 h0 = f2bf(v0), h1 = f2bf(v1);
        u32 hw = (u32)h0 | ((u32)h1 << 16);
        u32 lw = (u32)f2bf(v0 - bf2f(h0)) | ((u32)f2bf(v1 - bf2f(h1)) << 16);
        int byte = c*256 + ((((2*f) & ~15) ^ key) + ((2*f) & 15));
        *(u32*)((char*)sbh + byte) = hw;
        *(u32*)((char*)sbl + byte) = lw;
      }
    }
    __syncthreads();
    const int w = tid >> 6, lane = tid & 63, lr = lane & 15, g = lane >> 4;
    const long rowbase = (long)(bid - 1096)*128 + w*32;
    s16x8 ah[2][4], al[2][4];
#pragma unroll
    for (int rh = 0; rh < 2; rh++)
#pragma unroll
      for (int kc = 0; kc < 4; kc++){
        long r = rowbase + rh*16 + lr;
        const float4* px = (const float4*)(x + r*128 + kc*32 + g*8);
        float4 a = px[0], bV = px[1];
        u32 hh0, hh1, hh2, hh3, ll0, ll1, ll2, ll3;
        { u16 p=f2bf(a.x), q=f2bf(a.y); hh0=(u32)p|((u32)q<<16);
          ll0=(u32)f2bf(a.x-bf2f(p))|((u32)f2bf(a.y-bf2f(q))<<16); }
        { u16 p=f2bf(a.z), q=f2bf(a.w); hh1=(u32)p|((u32)q<<16);
          ll1=(u32)f2bf(a.z-bf2f(p))|((u32)f2bf(a.w-bf2f(q))<<16); }
        { u16 p=f2bf(bV.x), q=f2bf(bV.y); hh2=(u32)p|((u32)q<<16);
          ll2=(u32)f2bf(bV.x-bf2f(p))|((u32)f2bf(bV.y-bf2f(q))<<16); }
        { u16 p=f2bf(bV.z), q=f2bf(bV.w); hh3=(u32)p|((u32)q<<16);
          ll3=(u32)f2bf(bV.z-bf2f(p))|((u32)f2bf(bV.w-bf2f(q))<<16); }
        ah[rh][kc] = mk8(hh0,hh1,hh2,hh3);
        al[rh][kc] = mk8(ll0,ll1,ll2,ll3);
      }
    f32x4 acc[2][8];
#pragma unroll
    for (int rh = 0; rh < 2; rh++)
#pragma unroll
      for (int cg = 0; cg < 8; cg++) acc[rh][cg] = f4zero();
    const int swz = (lr & 7) << 4;
#pragma unroll
    for (int cg = 0; cg < 8; cg++){
      const int rowt = (cg*16 + lr) * 256;
#pragma unroll
      for (int kc = 0; kc < 4; kc++){
        int boff = rowt + ((kc*64 + g*16) ^ swz);
        s16x8 bh = *(const s16x8*)((const char*)sbh + boff);
        s16x8 bl = *(const s16x8*)((const char*)sbl + boff);
#pragma unroll
        for (int rh = 0; rh < 2; rh++){
          acc[rh][cg] = MFMA16(ah[rh][kc], bh, acc[rh][cg]);
          acc[rh][cg] = MFMA16(al[rh][kc], bh, acc[rh][cg]);
          acc[rh][cg] = MFMA16(ah[rh][kc], bl, acc[rh][cg]);
        }
      }
    }
#pragma unroll
    for (int rh = 0; rh < 2; rh++)
#pragma unroll
      for (int cg = 0; cg < 8; cg++)
#pragma unroll
        for (int r = 0; r < 4; r++){
          long q = rowbase + rh*16 + 4*g + r;  // C-layout: row=(l>>4)*4+reg
          int  c = cg*16 + lr;                 //           col=l&15
          float v = acc[rh][cg][r] * 1.4426950408889634f;
          u16 h = f2bf(v);
          yh[q*128 + c] = h;
          yl[q*128 + c] = f2bf(v - bf2f(h));
        }
  }
}

// ---------------------------------------------------------------------------
// K3: fused flash, 8-warp (round-12 verified body + hoisted addressing).
//   Changes this round: (a) prefetch issued AFTER the S-phase LDS reads
//   (less LDS-pipe contention; still ~60% of tile before barrier);
//   (b) epilogue writes ROW-MAJOR-over-splits partials:
//     Opart[bi][s][d], m/lpart[bi][s] with bi=(qbl*8+b)*128+lq
//   so the merge reads each row's KS splits contiguously.
//   NO launch_bounds min-wave cap (spill rule: rounds 2/4/6).
// ---------------------------------------------------------------------------
__global__ __launch_bounds__(512) void k_flash(
    const u16* __restrict__ xh, const u16* __restrict__ xl, const u16* __restrict__ Xt,
    const u16* __restrict__ yh, const u16* __restrict__ yl,
    u16* __restrict__ Opart, float* __restrict__ mpart, float* __restrict__ lpart,
    int KS, int kslog)
{
  __shared__ __align__(16) char lds[49152];
  const int tid = threadIdx.x, bid = blockIdx.x;
  const int b     = bid & 7;                   // XCD b owns batch b
  const int inner = bid >> 3;
  const int s     = inner & (KS - 1);
  const int qbl   = inner >> kslog;
  const int qb    = b*16 + qbl;
  const int nspan = 2048 >> kslog;
  const int kv0   = s * nspan;
  const int ntiles = nspan >> 5;
  const int w = tid >> 6, lane = tid & 63, lr = lane & 15, g = lane >> 4;
  const long qrow = (long)qb*128 + w*16;       // 16 q-rows per warp

  // ---- hoisted per-lane constants ----
  const int soff = w*1024 + lane*16;
  const int sswo = soff ^ (((soff >> 8) & 7) << 4);        // xh/xl src swz
  const int trow = soff >> 6;
  const int tsrc = trow*4096 + ((soff & 63) ^ ((trow & 3) << 4)); // xt src swz
  const int bS0 = lr*256 + (( 0 + g*16) ^ ((lr & 7) << 4));
  const int bS1 = lr*256 + (( 64 + g*16) ^ ((lr & 7) << 4));
  const int bS2 = lr*256 + ((128 + g*16) ^ ((lr & 7) << 4));
  const int bS3 = lr*256 + ((192 + g*16) ^ ((lr & 7) << 4));
  const int bPV = lr*64 + ((g*16) ^ ((lr & 3) << 4));

  // Y fragments (B-operands), hi/lo — 16 q-cols per warp
  s16x8 byh[4], byl[4];
#pragma unroll
  for (int kc = 0; kc < 4; kc++){
    long r = qrow + lr;
    byh[kc] = *(const s16x8*)(yh + r*128 + kc*32 + g*8);
    byl[kc] = *(const s16x8*)(yl + r*128 + kc*32 + g*8);
  }

  f32x4 o[8];                                  // O^T: [d-tile dg]
#pragma unroll
  for (int dg = 0; dg < 8; dg++) o[dg] = f4zero();
  float mrun = -1e30f, lrun = 0.f;

  const char* gxh  = (const char*)xh + ((long)b*2048 + kv0)*256;
  const char* gxl  = (const char*)xl + ((long)b*2048 + kv0)*256;
  const char* gxtb = (const char*)(Xt + (long)b*262144 + kv0);

  auto stage = [&](int bufi, int t){
    char* dst = lds + bufi*8192 + w*1024;      // wave-uniform dest
    async16(gxh  + (long)t*8192 + sswo, dst);
    async16(gxl  + (long)t*8192 + sswo, dst + 16384);
    async16(gxtb + (long)t*64   + tsrc, dst + 32768);
  };

  stage(0, 0);
  __syncthreads();

  for (int t = 0; t < ntiles; t++){
    const int cur = t & 1;
    const char* pb = lds + cur*8192;
    const char* a0 = pb + bS0;
    const char* a1 = pb + bS1;
    const char* a2 = pb + bS2;
    const char* a3 = pb + bS3;

    // ---- S^T tile [32kv x 16q], 3-term hi/lo split ----
    f32x4 sacc[2];                             // [kv-half ch]
    sacc[0] = f4zero(); sacc[1] = f4zero();
    __builtin_amdgcn_s_setprio(1);
#pragma unroll
    for (int ch = 0; ch < 2; ch++){
      const int co = ch*4096;                  // fh at co, fl at 16384+co
      s16x8 fh, fl;
      fh = *(const s16x8*)(a0 + co); fl = *(const s16x8*)(a0 + 16384 + co);
      sacc[ch] = MFMA16(fh, byh[0], sacc[ch]);
      sacc[ch] = MFMA16(fl, byh[0], sacc[ch]);
      sacc[ch] = MFMA16(fh, byl[0], sacc[ch]);
      fh = *(const s16x8*)(a1 + co); fl = *(const s16x8*)(a1 + 16384 + co);
      sacc[ch] = MFMA16(fh, byh[1], sacc[ch]);
      sacc[ch] = MFMA16(fl, byh[1], sacc[ch]);
      sacc[ch] = MFMA16(fh, byl[1], sacc[ch]);
      fh = *(const s16x8*)(a2 + co); fl = *(const s16x8*)(a2 + 16384 + co);
      sacc[ch] = MFMA16(fh, byh[2], sacc[ch]);
      sacc[ch] = MFMA16(fl, byh[2], sacc[ch]);
      sacc[ch] = MFMA16(fh, byl[2], sacc[ch]);
      fh = *(const s16x8*)(a3 + co); fl = *(const s16x8*)(a3 + 16384 + co);
      sacc[ch] = MFMA16(fh, byh[3], sacc[ch]);
      sacc[ch] = MFMA16(fl, byh[3], sacc[ch]);
      sacc[ch] = MFMA16(fh, byl[3], sacc[ch]);
    }
    __builtin_amdgcn_s_setprio(0);

    // prefetch next tile AFTER the S reads (LDS pipe free during reads)
    if (t + 1 < ntiles) stage(cur ^ 1, t + 1);

    // ---- lane-local online softmax (q = lr lives in this lane) ----
    float cm = fmaxf(fmaxf(fmaxf(sacc[0][0], sacc[0][1]),
                           fmaxf(sacc[0][2], sacc[0][3])),
                     fmaxf(fmaxf(sacc[1][0], sacc[1][1]),
                           fmaxf(sacc[1][2], sacc[1][3])));
    cm = fmaxf(cm, __shfl_xor(cm, 16, 64));
    cm = fmaxf(cm, __shfl_xor(cm, 32, 64));
    if (__any(cm > mrun + 8.f)){               // defer-max (log2 units, P<=256)
      float mn = fmaxf(mrun, cm);
      float sc = exp2f(mrun - mn);
#pragma unroll
      for (int dg = 0; dg < 8; dg++)
#pragma unroll
        for (int r = 0; r < 4; r++) o[dg][r] *= sc;
      lrun *= sc;
      mrun = mn;
    }
    float p[2][4];
#pragma unroll
    for (int ch = 0; ch < 2; ch++)
#pragma unroll
      for (int r = 0; r < 4; r++) p[ch][r] = exp2f(sacc[ch][r] - mrun);
    float ls = ((p[0][0] + p[0][1]) + (p[0][2] + p[0][3]))
             + ((p[1][0] + p[1][1]) + (p[1][2] + p[1][3]));
    ls += __shfl_xor(ls, 16, 64);
    ls += __shfl_xor(ls, 32, 64);
    lrun += ls;
    // lane (g,lr) holds P[q=lr][kv=16ch+4g+r]; B-frag needs kv=8g+j.
    s16x8 bpq;
    {
      u32 pw00 = packtrunc(p[0][0], p[0][1]);
      u32 pw01 = packtrunc(p[0][2], p[0][3]);
      u32 pw10 = packtrunc(p[1][0], p[1][1]);
      u32 pw11 = packtrunc(p[1][2], p[1][3]);
      int sA = ((g & 1) << 5) + lr;
      int sB = sA + 16;
      u32 a0s = (u32)__shfl((int)pw00, sA, 64);
      u32 a1s = (u32)__shfl((int)pw01, sA, 64);
      u32 a2s = (u32)__shfl((int)pw10, sA, 64);
      u32 a3s = (u32)__shfl((int)pw11, sA, 64);
      u32 b0s = (u32)__shfl((int)pw00, sB, 64);
      u32 b1s = (u32)__shfl((int)pw01, sB, 64);
      u32 b2s = (u32)__shfl((int)pw10, sB, 64);
      u32 b3s = (u32)__shfl((int)pw11, sB, 64);
      bool hi = (g >= 2);
      bpq = mk8(hi ? a2s : a0s, hi ? a3s : a1s, hi ? b2s : b0s, hi ? b3s : b1s);
    }

    // ---- O^T += Xt-frag (LDS swz) x P^T (regs) ----
    const char* ap = pb + 32768 + bPV;
    __builtin_amdgcn_s_setprio(1);
#pragma unroll
    for (int half = 0; half < 2; half++){
      s16x8 ax[4];
#pragma unroll
      for (int i = 0; i < 4; i++)
        ax[i] = *(const s16x8*)(ap + (half*4 + i)*1024);
#pragma unroll
      for (int i = 0; i < 4; i++)
        o[half*4 + i] = MFMA16(ax[i], bpq, o[half*4 + i]);
    }
    __builtin_amdgcn_s_setprio(0);
    __syncthreads();   // drains prefetch + guards buffer reuse
  }

  // ---- epilogue: split-major partials for contiguous merge reads ----
  {
    int lq = w*16 + lr;
    long bi = (long)(qbl*8 + b)*128 + lq;
    u16* op = Opart + bi*(long)(128 << kslog) + s*128;
#pragma unroll
    for (int dg = 0; dg < 8; dg++){
      u32x2 pw;
      pw[0] = pack2bf(o[dg][0], o[dg][1]);
      pw[1] = pack2bf(o[dg][2], o[dg][3]);
      *(u32x2*)(op + dg*16 + 4*g) = pw;
    }
    if (g == 0){
      mpart[bi*KS + s] = mrun;
      lpart[bi*KS + s] = lrun;
    }
  }
}

// ---------------------------------------------------------------------------
// K4 (fused merge + layer1 + a2-partial): 512 blocks x 256 thr, 32 rows each.
//   Phase 1: merge KS contiguous split-partials -> swizzled LDS A1 tile.
//   Phase 2: x1 = relu(A1 @ w1 + x) in registers (4 warps = 2 rowhalf x 2 colhalf).
//   Phase 3: A2p[bid] = sum_q e_q * x1[q,:], Lj[bid] = sum_q e_q.
// ---------------------------------------------------------------------------
__global__ __launch_bounds__(256) void k_mergeL1(
    const u16* __restrict__ Opart, const float* __restrict__ mpart, const float* __restrict__ lpart,
    const u16* __restrict__ w1t, const float* __restrict__ x,
    const float* __restrict__ S0, const float* __restrict__ maxpart,
    float* __restrict__ A2p, float* __restrict__ Lj, float* __restrict__ x1r0,
    int KS)
{
  __shared__ u16 sb[16384];                    // w1^T [c][f] swizzled (32KB)
  __shared__ u16 sa[4096];                     // A1 tile [32][128] swz (8KB)
  __shared__ float eS[32];
  __shared__ float redw[4][64];
  const int tid = threadIdx.x, bid = blockIdx.x;
  const int bb   = bid >> 6;                   // batch
  const int qbl  = (bid >> 2) & 15;
  const int rb   = (bid & 3) * 32;             // row offset within q-block
  const long R0  = (long)bid*32;               // global row base
#pragma unroll
  for (int k = 0; k < 8; k++){
    int off = (tid + k*256)*16;
    int row = off >> 8;
    *(s16x8*)((char*)sb + (off ^ ((row & 7) << 4))) = *(const s16x8*)((const char*)w1t + off);
  }
  if (tid < 32){
    float M = -1e30f;
#pragma unroll
    for (int jj = 0; jj < 8; jj++) M = fmaxf(M, maxpart[bb*8 + jj]);
    eS[tid] = __expf(S0[bb*2048 + (bid & 63)*32 + tid] - M);
  }
  // merge phase: 512 granules (32 rows x 16), 2 per thread
#pragma unroll
  for (int k = 0; k < 2; k++){
    int gidx = tid + k*256;
    int lrow = gidx >> 4, gcol = gidx & 15;
    long bi = (long)(qbl*8 + bb)*128 + rb + lrow;
    const float* mp = mpart + bi*KS;
    const float* lp = lpart + bi*KS;
    float m = -1e30f;
    for (int s = 0; s < KS; s++) m = fmaxf(m, mp[s]);
    float ls = 0.f;
    float a0=0.f,a1=0.f,a2=0.f,a3=0.f,a4=0.f,a5=0.f,a6=0.f,a7=0.f;
    const u16* ob = Opart + bi*(long)(KS*128) + gcol*8;
    for (int s = 0; s < KS; s++){
      float wgt = exp2f(mp[s] - m);
      ls += lp[s] * wgt;
      u32x4 v = *(const u32x4*)(ob + s*128);
      a0 += bf2f((u16)(v[0] & 0xffff)) * wgt;  a1 += bf2f((u16)(v[0] >> 16)) * wgt;
      a2 += bf2f((u16)(v[1] & 0xffff)) * wgt;  a3 += bf2f((u16)(v[1] >> 16)) * wgt;
      a4 += bf2f((u16)(v[2] & 0xffff)) * wgt;  a5 += bf2f((u16)(v[2] >> 16)) * wgt;
      a6 += bf2f((u16)(v[3] & 0xffff)) * wgt;  a7 += bf2f((u16)(v[3] >> 16)) * wgt;
    }
    float inv = 1.f / ls;
    u32x4 pw;
    pw[0] = pack2bf(a0*inv, a1*inv); pw[1] = pack2bf(a2*inv, a3*inv);
    pw[2] = pack2bf(a4*inv, a5*inv); pw[3] = pack2bf(a6*inv, a7*inv);
    int off = lrow*256 + gcol*16;
    *(u32x4*)((char*)sa + (off ^ ((lrow & 7) << 4))) = pw;
  }
  __syncthreads();
  // GEMM phase: warp w = rowhalf (w&1) x colhalf (w>>1); 16 rows x 64 cols
  const int w = tid >> 6, lane = tid & 63, lr = lane & 15, g = lane >> 4;
  const int rowhalf = w & 1, colhalf = w >> 1;
  s16x8 aa[4];
#pragma unroll
  for (int kc = 0; kc < 4; kc++){
    int lrow = rowhalf*16 + lr;
    aa[kc] = *(const s16x8*)((const char*)sa +
               (lrow*256 + ((kc*64 + g*16) ^ ((lrow & 7) << 4))));
  }
  f32x4 acc[4];
#pragma unroll
  for (int cg = 0; cg < 4; cg++) acc[cg] = f4zero();
  const int swz = (lr & 7) << 4;
#pragma unroll
  for (int cg = 0; cg < 4; cg++){
    const int c = colhalf*64 + cg*16 + lr;
    const int rowt = c*256;
#pragma unroll
    for (int kc = 0; kc < 4; kc++){
      s16x8 bV = *(const s16x8*)((const char*)sb + rowt + ((kc*64 + g*16) ^ swz));
      acc[cg] = MFMA16(aa[kc], bV, acc[cg]);
    }
  }
  // x1 in-register; e-weighted partial column sums
  const float e0 = eS[rowhalf*16 + 4*g + 0];
  const float e1 = eS[rowhalf*16 + 4*g + 1];
  const float e2 = eS[rowhalf*16 + 4*g + 2];
  const float e3 = eS[rowhalf*16 + 4*g + 3];
  float sA2[4];
#pragma unroll
  for (int cg = 0; cg < 4; cg++){
    int c = colhalf*64 + cg*16 + lr;
    f32x4 vv;
#pragma unroll
    for (int r = 0; r < 4; r++){
      long q = R0 + rowhalf*16 + 4*g + r;
      vv[r] = fmaxf(acc[cg][r] + x[q*128 + c], 0.f);
    }
    if (((bid & 63) == 0) && rowhalf == 0 && g == 0)
      x1r0[bb*128 + c] = vv[0];                // batch row 0
    sA2[cg] = e0*vv[0] + e1*vv[1] + e2*vv[2] + e3*vv[3];
  }
#pragma unroll
  for (int cg = 0; cg < 4; cg++){
    sA2[cg] += __shfl_xor(sA2[cg], 16, 64);
    sA2[cg] += __shfl_xor(sA2[cg], 32, 64);
  }
  if (g == 0){
#pragma unroll
    for (int cg = 0; cg < 4; cg++) redw[w][cg*16 + lr] = sA2[cg];
  }
  __syncthreads();
  if (tid < 128){
    int cl = tid & 63, pair = (tid >> 6) * 2;
    A2p[(long)bid*128 + tid] = redw[pair][cl] + redw[pair + 1][cl];
  }
  if (w == 2){
    float v = (lane < 32) ? eS[lane] : 0.f;
    v += __shfl_xor(v, 1, 64);  v += __shfl_xor(v, 2, 64);
    v += __shfl_xor(v, 4, 64);  v += __shfl_xor(v, 8, 64);
    v += __shfl_xor(v, 16, 64); v += __shfl_xor(v, 32, 64);
    if (lane == 0) Lj[bid] = v;
  }
}

// K5: out = relu((A2/L) @ w2 + x1[:,0,:]) — sums 64 chunks per batch
__global__ __launch_bounds__(256) void k_out(
    const float* __restrict__ A2p, const float* __restrict__ Lj,
    const float* __restrict__ w2, const float* __restrict__ x1r0,
    float* __restrict__ out)
{
  __shared__ float a2s[2][128];
  const int tid = threadIdx.x, bid = blockIdx.x;
  const int b0 = bid*2;
  {
    int which = tid >> 7, f = tid & 127;
    int bb = b0 + which;
    float s = 0.f, L = 0.f;
#pragma unroll
    for (int jj = 0; jj < 64; jj++){
      s += A2p[(long)(bb*64 + jj)*128 + f];
      L += Lj[bb*64 + jj];
    }
    a2s[which][f] = s / L;
  }
  __syncthreads();
  const int which = tid >> 7, d = tid & 127;
  const int b = b0 + which;
  float acc = x1r0[b*128 + d];
  for (int f = 0; f < 128; f++)
    acc += a2s[which][f] * w2[f*128 + d];
  out[b*128 + d] = fmaxf(acc, 0.f);
}

// ---------------------------------------------------------------------------
extern "C" void kernel_launch(void* const* d_in, const int* in_sizes, int n_in,
                              void* d_out, int out_size, void* d_ws, size_t ws_size,
                              hipStream_t stream)
{
  const float* x  = (const float*)d_in[0];
  const float* w1 = (const float*)d_in[1];
  const float* w2 = (const float*)d_in[2];
  const float* wr = (const float*)d_in[3];
  float* out = (float*)d_out;
  char* ws = (char*)d_ws;

  u16*   xh      = (u16*)  (ws + 0);
  u16*   xl      = (u16*)  (ws + 4194304);
  u16*   Xt      = (u16*)  (ws + 8388608);
  u16*   yh      = (u16*)  (ws + 12582912);
  u16*   yl      = (u16*)  (ws + 16777216);
  u16*   w1t     = (u16*)  (ws + 20971520);
  float* S0      = (float*)(ws + 21004288);   // 64 KB
  float* maxpart = (float*)(ws + 21069824);   // 256 B (pad 1 KB)
  float* Lj      = (float*)(ws + 21070848);   // 512 floats = 2 KB
  float* A2p     = (float*)(ws + 21072896);   // 512*128*4 = 256 KB
  float* x1r0    = (float*)(ws + 21335040);   // 4 KB
  const size_t tail = 21339136;

  int KS = 4, kslog = 2;
  // per-KS bytes: mpart 64K + lpart 64K + Opart bf16 4M
  while (KS > 1 && tail + (size_t)KS*4325376ull > ws_size){ KS >>= 1; kslog--; }
  float* mpart = (float*)(ws + tail);
  float* lpart = (float*)(ws + tail + (size_t)KS*65536);
  u16*   Opart = (u16*)  (ws + tail + (size_t)KS*131072);

  k_prep   <<<1224, 256, 0, stream>>>(x, wr, w1, xh, xl, Xt, w1t, S0, maxpart, yh, yl);
  k_flash  <<<128*KS, 512, 0, stream>>>(xh, xl, Xt, yh, yl, Opart, mpart, lpart, KS, kslog);
  k_mergeL1<<<512, 256, 0, stream>>>(Opart, mpart, lpart, w1t, x, S0, maxpart, A2p, Lj, x1r0, KS);
  k_out    <<<4, 256, 0, stream>>>(A2p, Lj, w2, x1r0, out);
}

// Round 14
// 82.378 us; speedup vs baseline: 4.2278x; 1.0060x over previous
//
#include <hip/hip_runtime.h>
#include <stdint.h>

typedef float  f32x4 __attribute__((ext_vector_type(4)));
typedef short  s16x8 __attribute__((ext_vector_type(8)));
typedef unsigned int u32;
typedef u32    u32x2 __attribute__((ext_vector_type(2)));
typedef u32    u32x4 __attribute__((ext_vector_type(4)));
typedef unsigned short u16;

#define MFMA16(a,b,c) __builtin_amdgcn_mfma_f32_16x16x32_bf16((a),(b),(c),0,0,0)

__device__ __forceinline__ u16 f2bf(float f){
  u32 u = __float_as_uint(f);
  return (u16)((u + 0x7fffu + ((u >> 16) & 1u)) >> 16);   // RNE
}
__device__ __forceinline__ float bf2f(u16 h){ return __uint_as_float(((u32)h) << 16); }
__device__ __forceinline__ u32 pack2bf(float a, float b){ return (u32)f2bf(a) | ((u32)f2bf(b) << 16); }
// truncation pack (round-to-zero): fine for P in [0,1]
__device__ __forceinline__ u32 packtrunc(float a, float b){
  return (__float_as_uint(a) >> 16) | (__float_as_uint(b) & 0xffff0000u);
}
__device__ __forceinline__ f32x4 f4zero(){ f32x4 z; z[0]=0.f; z[1]=0.f; z[2]=0.f; z[3]=0.f; return z; }
// register-only vector build (NO union: unions can defeat SROA -> scratch)
__device__ __forceinline__ s16x8 mk8(u32 a, u32 b, u32 c, u32 d){
  u32x4 w; w[0]=a; w[1]=b; w[2]=c; w[3]=d;
  return __builtin_bit_cast(s16x8, w);
}

// async global->LDS, 16B per lane; LDS dest is wave-uniform base + lane*16
__device__ __forceinline__ void async16(const void* g, void* l){
  __builtin_amdgcn_global_load_lds(
      (const __attribute__((address_space(1))) unsigned int*)g,
      (__attribute__((address_space(3))) unsigned int*)l, 16, 0, 0);
}

// ---------------------------------------------------------------------------
// K1 mega-prep. Block ranges (one branch each, no cross-block deps):
//   [0,1024): x -> xh/xl + Xt; [1024,1032): w1^T;
//   [1032,1160): ygemm (3-term split from raw fp32, self-contained).
//   (S0 branch REMOVED: k_flash's q=0 column now produces S0 directly.)
// ---------------------------------------------------------------------------
__global__ __launch_bounds__(256) void k_prep(
    const float* __restrict__ x, const float* __restrict__ wr, const float* __restrict__ w1,
    u16* __restrict__ xh, u16* __restrict__ xl, u16* __restrict__ Xt,
    u16* __restrict__ w1t, u16* __restrict__ yh, u16* __restrict__ yl)
{
  __shared__ __align__(16) char smem[65536];
  const int tid = threadIdx.x, bid = blockIdx.x;

  if (bid < 1024){
    float (*xs)[132] = (float(*)[132])smem;
    const long base = (long)bid * 2048;          // 16 rows * 128
#pragma unroll
    for (int k = 0; k < 8; k++){
      int idx = tid + k*256;
      float v = x[base + idx];
      xs[idx>>7][idx&127] = v;
      u16 h = f2bf(v);
      xh[base+idx] = h;
      xl[base+idx] = f2bf(v - bf2f(h));
    }
    __syncthreads();
    const int b  = bid >> 7;                     // 128 blocks per batch
    const int n0 = (bid & 127) * 16;
    const int nn = tid & 15, d0 = tid >> 4;
#pragma unroll
    for (int d = 0; d < 8; d++){
      int dd = d0 + d*16;
      Xt[(long)b*262144 + (long)dd*2048 + n0 + nn] = f2bf(xs[nn][dd]);
    }
  } else if (bid < 1032){
    const int base = (bid - 1024) * 2048;
#pragma unroll
    for (int k = 0; k < 8; k++){
      int idx = base + k*256 + tid;
      int c = idx >> 7, f = idx & 127;
      w1t[idx] = f2bf(w1[f*128 + c]);            // w1T[c][f] = w1[f][c]
    }
  } else {
    // ---- fused ygemm: 128 blocks x 256 thr (4 warps), 128 rows/block ----
    u16* sbh = (u16*)smem;                       // [c][f] bf16 swizzled, 32 KB
    u16* sbl = sbh + 16384;                      // +16384 u16 = +32 KB
    {
      const int c = tid & 127, f0 = (tid >> 7) * 64;
      const int key = (c & 7) << 4;
#pragma unroll
      for (int fi = 0; fi < 64; fi += 2){
        int f = f0 + fi;
        float v0 = wr[f*128 + c], v1 = wr[(f+1)*128 + c];
        u16 h0 = f2bf(v0), h1 = f2bf(v1);
        u32 hw = (u32)h0 | ((u32)h1 << 16);
        u32 lw = (u32)f2bf(v0 - bf2f(h0)) | ((u32)f2bf(v1 - bf2f(h1)) << 16);
        int byte = c*256 + ((((2*f) & ~15) ^ key) + ((2*f) & 15));
        *(u32*)((char*)sbh + byte) = hw;
        *(u32*)((char*)sbl + byte) = lw;
      }
    }
    __syncthreads();
    const int w = tid >> 6, lane = tid & 63, lr = lane & 15, g = lane >> 4;
    const long rowbase = (long)(bid - 1032)*128 + w*32;
    s16x8 ah[2][4], al[2][4];
#pragma unroll
    for (int rh = 0; rh < 2; rh++)
#pragma unroll
      for (int kc = 0; kc < 4; kc++){
        long r = rowbase + rh*16 + lr;
        const float4* px = (const float4*)(x + r*128 + kc*32 + g*8);
        float4 a = px[0], bV = px[1];
        u32 hh0, hh1, hh2, hh3, ll0, ll1, ll2, ll3;
        { u16 p=f2bf(a.x), q=f2bf(a.y); hh0=(u32)p|((u32)q<<16);
          ll0=(u32)f2bf(a.x-bf2f(p))|((u32)f2bf(a.y-bf2f(q))<<16); }
        { u16 p=f2bf(a.z), q=f2bf(a.w); hh1=(u32)p|((u32)q<<16);
          ll1=(u32)f2bf(a.z-bf2f(p))|((u32)f2bf(a.w-bf2f(q))<<16); }
        { u16 p=f2bf(bV.x), q=f2bf(bV.y); hh2=(u32)p|((u32)q<<16);
          ll2=(u32)f2bf(bV.x-bf2f(p))|((u32)f2bf(bV.y-bf2f(q))<<16); }
        { u16 p=f2bf(bV.z), q=f2bf(bV.w); hh3=(u32)p|((u32)q<<16);
          ll3=(u32)f2bf(bV.z-bf2f(p))|((u32)f2bf(bV.w-bf2f(q))<<16); }
        ah[rh][kc] = mk8(hh0,hh1,hh2,hh3);
        al[rh][kc] = mk8(ll0,ll1,ll2,ll3);
      }
    f32x4 acc[2][8];
#pragma unroll
    for (int rh = 0; rh < 2; rh++)
#pragma unroll
      for (int cg = 0; cg < 8; cg++) acc[rh][cg] = f4zero();
    const int swz = (lr & 7) << 4;
#pragma unroll
    for (int cg = 0; cg < 8; cg++){
      const int rowt = (cg*16 + lr) * 256;
#pragma unroll
      for (int kc = 0; kc < 4; kc++){
        int boff = rowt + ((kc*64 + g*16) ^ swz);
        s16x8 bh = *(const s16x8*)((const char*)sbh + boff);
        s16x8 bl = *(const s16x8*)((const char*)sbl + boff);
#pragma unroll
        for (int rh = 0; rh < 2; rh++){
          acc[rh][cg] = MFMA16(ah[rh][kc], bh, acc[rh][cg]);
          acc[rh][cg] = MFMA16(al[rh][kc], bh, acc[rh][cg]);
          acc[rh][cg] = MFMA16(ah[rh][kc], bl, acc[rh][cg]);
        }
      }
    }
#pragma unroll
    for (int rh = 0; rh < 2; rh++)
#pragma unroll
      for (int cg = 0; cg < 8; cg++)
#pragma unroll
        for (int r = 0; r < 4; r++){
          long q = rowbase + rh*16 + 4*g + r;  // C-layout: row=(l>>4)*4+reg
          int  c = cg*16 + lr;                 //           col=l&15
          float v = acc[rh][cg][r] * 1.4426950408889634f;
          u16 h = f2bf(v);
          yh[q*128 + c] = h;
          yl[q*128 + c] = f2bf(v - bf2f(h));
        }
  }
}

// ---------------------------------------------------------------------------
// K3: fused flash, 8-warp (round-13 verified body + hoisted addressing).
//   New: qbl==0 / w==0 / lr==0 lanes dump the q=0 column of S^T to S0
//   (log2-prescaled) — replaces k_prep's fp32 row-0 logits branch.
//   NO launch_bounds min-wave cap (spill rule: rounds 2/4/6).
// ---------------------------------------------------------------------------
__global__ __launch_bounds__(512) void k_flash(
    const u16* __restrict__ xh, const u16* __restrict__ xl, const u16* __restrict__ Xt,
    const u16* __restrict__ yh, const u16* __restrict__ yl,
    u16* __restrict__ Opart, float* __restrict__ mpart, float* __restrict__ lpart,
    float* __restrict__ S0, int KS, int kslog)
{
  __shared__ __align__(16) char lds[49152];
  const int tid = threadIdx.x, bid = blockIdx.x;
  const int b     = bid & 7;                   // XCD b owns batch b
  const int inner = bid >> 3;
  const int s     = inner & (KS - 1);
  const int qbl   = inner >> kslog;
  const int qb    = b*16 + qbl;
  const int nspan = 2048 >> kslog;
  const int kv0   = s * nspan;
  const int ntiles = nspan >> 5;
  const int w = tid >> 6, lane = tid & 63, lr = lane & 15, g = lane >> 4;
  const long qrow = (long)qb*128 + w*16;       // 16 q-rows per warp

  // ---- hoisted per-lane constants ----
  const int soff = w*1024 + lane*16;
  const int sswo = soff ^ (((soff >> 8) & 7) << 4);        // xh/xl src swz
  const int trow = soff >> 6;
  const int tsrc = trow*4096 + ((soff & 63) ^ ((trow & 3) << 4)); // xt src swz
  const int bS0 = lr*256 + (( 0 + g*16) ^ ((lr & 7) << 4));
  const int bS1 = lr*256 + (( 64 + g*16) ^ ((lr & 7) << 4));
  const int bS2 = lr*256 + ((128 + g*16) ^ ((lr & 7) << 4));
  const int bS3 = lr*256 + ((192 + g*16) ^ ((lr & 7) << 4));
  const int bPV = lr*64 + ((g*16) ^ ((lr & 3) << 4));

  // Y fragments (B-operands), hi/lo — 16 q-cols per warp
  s16x8 byh[4], byl[4];
#pragma unroll
  for (int kc = 0; kc < 4; kc++){
    long r = qrow + lr;
    byh[kc] = *(const s16x8*)(yh + r*128 + kc*32 + g*8);
    byl[kc] = *(const s16x8*)(yl + r*128 + kc*32 + g*8);
  }

  f32x4 o[8];                                  // O^T: [d-tile dg]
#pragma unroll
  for (int dg = 0; dg < 8; dg++) o[dg] = f4zero();
  float mrun = -1e30f, lrun = 0.f;

  const char* gxh  = (const char*)xh + ((long)b*2048 + kv0)*256;
  const char* gxl  = (const char*)xl + ((long)b*2048 + kv0)*256;
  const char* gxtb = (const char*)(Xt + (long)b*262144 + kv0);

  auto stage = [&](int bufi, int t){
    char* dst = lds + bufi*8192 + w*1024;      // wave-uniform dest
    async16(gxh  + (long)t*8192 + sswo, dst);
    async16(gxl  + (long)t*8192 + sswo, dst + 16384);
    async16(gxtb + (long)t*64   + tsrc, dst + 32768);
  };

  stage(0, 0);
  __syncthreads();

  for (int t = 0; t < ntiles; t++){
    const int cur = t & 1;
    const char* pb = lds + cur*8192;
    const char* a0 = pb + bS0;
    const char* a1 = pb + bS1;
    const char* a2 = pb + bS2;
    const char* a3 = pb + bS3;

    // ---- S^T tile [32kv x 16q], 3-term hi/lo split ----
    f32x4 sacc[2];                             // [kv-half ch]
    sacc[0] = f4zero(); sacc[1] = f4zero();
    __builtin_amdgcn_s_setprio(1);
#pragma unroll
    for (int ch = 0; ch < 2; ch++){
      const int co = ch*4096;                  // fh at co, fl at 16384+co
      s16x8 fh, fl;
      fh = *(const s16x8*)(a0 + co); fl = *(const s16x8*)(a0 + 16384 + co);
      sacc[ch] = MFMA16(fh, byh[0], sacc[ch]);
      sacc[ch] = MFMA16(fl, byh[0], sacc[ch]);
      sacc[ch] = MFMA16(fh, byl[0], sacc[ch]);
      fh = *(const s16x8*)(a1 + co); fl = *(const s16x8*)(a1 + 16384 + co);
      sacc[ch] = MFMA16(fh, byh[1], sacc[ch]);
      sacc[ch] = MFMA16(fl, byh[1], sacc[ch]);
      sacc[ch] = MFMA16(fh, byl[1], sacc[ch]);
      fh = *(const s16x8*)(a2 + co); fl = *(const s16x8*)(a2 + 16384 + co);
      sacc[ch] = MFMA16(fh, byh[2], sacc[ch]);
      sacc[ch] = MFMA16(fl, byh[2], sacc[ch]);
      sacc[ch] = MFMA16(fh, byl[2], sacc[ch]);
      fh = *(const s16x8*)(a3 + co); fl = *(const s16x8*)(a3 + 16384 + co);
      sacc[ch] = MFMA16(fh, byh[3], sacc[ch]);
      sacc[ch] = MFMA16(fl, byh[3], sacc[ch]);
      sacc[ch] = MFMA16(fh, byl[3], sacc[ch]);
    }
    __builtin_amdgcn_s_setprio(0);

    // prefetch next tile AFTER the S reads (LDS pipe free during reads)
    if (t + 1 < ntiles) stage(cur ^ 1, t + 1);

    // ---- q=0 column dump -> S0 (only 32 of 512 blocks; warp 0, lr==0) ----
    if (qbl == 0 && w == 0 && lr == 0){
      float* s0p = S0 + b*2048 + kv0 + t*32 + 4*g;
#pragma unroll
      for (int ch = 0; ch < 2; ch++)
#pragma unroll
        for (int r = 0; r < 4; r++)
          s0p[ch*16 + r] = sacc[ch][r];
    }

    // ---- lane-local online softmax (q = lr lives in this lane) ----
    float cm = fmaxf(fmaxf(fmaxf(sacc[0][0], sacc[0][1]),
                           fmaxf(sacc[0][2], sacc[0][3])),
                     fmaxf(fmaxf(sacc[1][0], sacc[1][1]),
                           fmaxf(sacc[1][2], sacc[1][3])));
    cm = fmaxf(cm, __shfl_xor(cm, 16, 64));
    cm = fmaxf(cm, __shfl_xor(cm, 32, 64));
    if (__any(cm > mrun + 8.f)){               // defer-max (log2 units, P<=256)
      float mn = fmaxf(mrun, cm);
      float sc = exp2f(mrun - mn);
#pragma unroll
      for (int dg = 0; dg < 8; dg++)
#pragma unroll
        for (int r = 0; r < 4; r++) o[dg][r] *= sc;
      lrun *= sc;
      mrun = mn;
    }
    float p[2][4];
#pragma unroll
    for (int ch = 0; ch < 2; ch++)
#pragma unroll
      for (int r = 0; r < 4; r++) p[ch][r] = exp2f(sacc[ch][r] - mrun);
    float ls = ((p[0][0] + p[0][1]) + (p[0][2] + p[0][3]))
             + ((p[1][0] + p[1][1]) + (p[1][2] + p[1][3]));
    ls += __shfl_xor(ls, 16, 64);
    ls += __shfl_xor(ls, 32, 64);
    lrun += ls;
    // lane (g,lr) holds P[q=lr][kv=16ch+4g+r]; B-frag needs kv=8g+j.
    s16x8 bpq;
    {
      u32 pw00 = packtrunc(p[0][0], p[0][1]);
      u32 pw01 = packtrunc(p[0][2], p[0][3]);
      u32 pw10 = packtrunc(p[1][0], p[1][1]);
      u32 pw11 = packtrunc(p[1][2], p[1][3]);
      int sA = ((g & 1) << 5) + lr;
      int sB = sA + 16;
      u32 a0s = (u32)__shfl((int)pw00, sA, 64);
      u32 a1s = (u32)__shfl((int)pw01, sA, 64);
      u32 a2s = (u32)__shfl((int)pw10, sA, 64);
      u32 a3s = (u32)__shfl((int)pw11, sA, 64);
      u32 b0s = (u32)__shfl((int)pw00, sB, 64);
      u32 b1s = (u32)__shfl((int)pw01, sB, 64);
      u32 b2s = (u32)__shfl((int)pw10, sB, 64);
      u32 b3s = (u32)__shfl((int)pw11, sB, 64);
      bool hi = (g >= 2);
      bpq = mk8(hi ? a2s : a0s, hi ? a3s : a1s, hi ? b2s : b0s, hi ? b3s : b1s);
    }

    // ---- O^T += Xt-frag (LDS swz) x P^T (regs) ----
    const char* ap = pb + 32768 + bPV;
    __builtin_amdgcn_s_setprio(1);
#pragma unroll
    for (int half = 0; half < 2; half++){
      s16x8 ax[4];
#pragma unroll
      for (int i = 0; i < 4; i++)
        ax[i] = *(const s16x8*)(ap + (half*4 + i)*1024);
#pragma unroll
      for (int i = 0; i < 4; i++)
        o[half*4 + i] = MFMA16(ax[i], bpq, o[half*4 + i]);
    }
    __builtin_amdgcn_s_setprio(0);
    __syncthreads();   // drains prefetch + guards buffer reuse
  }

  // ---- epilogue: split-major partials for contiguous merge reads ----
  {
    int lq = w*16 + lr;
    long bi = (long)(qbl*8 + b)*128 + lq;
    u16* op = Opart + bi*(long)(128 << kslog) + s*128;
#pragma unroll
    for (int dg = 0; dg < 8; dg++){
      u32x2 pw;
      pw[0] = pack2bf(o[dg][0], o[dg][1]);
      pw[1] = pack2bf(o[dg][2], o[dg][3]);
      *(u32x2*)(op + dg*16 + 4*g) = pw;
    }
    if (g == 0){
      mpart[bi*KS + s] = mrun;
      lpart[bi*KS + s] = lrun;
    }
  }
}

// ---------------------------------------------------------------------------
// K4 (fused merge + layer1 + a2-partial): 512 blocks x 256 thr, 32 rows each.
//   Phase 1: merge KS contiguous split-partials -> swizzled LDS A1 tile.
//   Phase 2: x1 = relu(A1 @ w1 + x) in registers (4 warps = 2 rowhalf x 2 colhalf).
//   Phase 3: A2p[bid] = sum_q e_q * x1[q,:], Lj[bid] = sum_q e_q.
//   eS from k_flash's S0 (log2 units) with M0 = row-0 running-max from mpart.
// ---------------------------------------------------------------------------
__global__ __launch_bounds__(256) void k_mergeL1(
    const u16* __restrict__ Opart, const float* __restrict__ mpart, const float* __restrict__ lpart,
    const u16* __restrict__ w1t, const float* __restrict__ x,
    const float* __restrict__ S0,
    float* __restrict__ A2p, float* __restrict__ Lj, float* __restrict__ x1r0,
    int KS)
{
  __shared__ u16 sb[16384];                    // w1^T [c][f] swizzled (32KB)
  __shared__ u16 sa[4096];                     // A1 tile [32][128] swz (8KB)
  __shared__ float eS[32];
  __shared__ float redw[4][64];
  const int tid = threadIdx.x, bid = blockIdx.x;
  const int bb   = bid >> 6;                   // batch
  const int qbl  = (bid >> 2) & 15;
  const int rb   = (bid & 3) * 32;             // row offset within q-block
  const long R0  = (long)bid*32;               // global row base
#pragma unroll
  for (int k = 0; k < 8; k++){
    int off = (tid + k*256)*16;
    int row = off >> 8;
    *(s16x8*)((char*)sb + (off ^ ((row & 7) << 4))) = *(const s16x8*)((const char*)w1t + off);
  }
  if (tid < 32){
    const float* mp0 = mpart + (long)(bb*128)*KS;     // bi for (qbl=0,row 0)
    float M = -1e30f;
    for (int s = 0; s < KS; s++) M = fmaxf(M, mp0[s]);
    eS[tid] = exp2f(S0[bb*2048 + (bid & 63)*32 + tid] - M);
  }
  // merge phase: 512 granules (32 rows x 16), 2 per thread
#pragma unroll
  for (int k = 0; k < 2; k++){
    int gidx = tid + k*256;
    int lrow = gidx >> 4, gcol = gidx & 15;
    long bi = (long)(qbl*8 + bb)*128 + rb + lrow;
    const float* mp = mpart + bi*KS;
    const float* lp = lpart + bi*KS;
    float m = -1e30f;
    for (int s = 0; s < KS; s++) m = fmaxf(m, mp[s]);
    float ls = 0.f;
    float a0=0.f,a1=0.f,a2=0.f,a3=0.f,a4=0.f,a5=0.f,a6=0.f,a7=0.f;
    const u16* ob = Opart + bi*(long)(KS*128) + gcol*8;
    for (int s = 0; s < KS; s++){
      float wgt = exp2f(mp[s] - m);
      ls += lp[s] * wgt;
      u32x4 v = *(const u32x4*)(ob + s*128);
      a0 += bf2f((u16)(v[0] & 0xffff)) * wgt;  a1 += bf2f((u16)(v[0] >> 16)) * wgt;
      a2 += bf2f((u16)(v[1] & 0xffff)) * wgt;  a3 += bf2f((u16)(v[1] >> 16)) * wgt;
      a4 += bf2f((u16)(v[2] & 0xffff)) * wgt;  a5 += bf2f((u16)(v[2] >> 16)) * wgt;
      a6 += bf2f((u16)(v[3] & 0xffff)) * wgt;  a7 += bf2f((u16)(v[3] >> 16)) * wgt;
    }
    float inv = 1.f / ls;
    u32x4 pw;
    pw[0] = pack2bf(a0*inv, a1*inv); pw[1] = pack2bf(a2*inv, a3*inv);
    pw[2] = pack2bf(a4*inv, a5*inv); pw[3] = pack2bf(a6*inv, a7*inv);
    int off = lrow*256 + gcol*16;
    *(u32x4*)((char*)sa + (off ^ ((lrow & 7) << 4))) = pw;
  }
  __syncthreads();
  // GEMM phase: warp w = rowhalf (w&1) x colhalf (w>>1); 16 rows x 64 cols
  const int w = tid >> 6, lane = tid & 63, lr = lane & 15, g = lane >> 4;
  const int rowhalf = w & 1, colhalf = w >> 1;
  s16x8 aa[4];
#pragma unroll
  for (int kc = 0; kc < 4; kc++){
    int lrow = rowhalf*16 + lr;
    aa[kc] = *(const s16x8*)((const char*)sa +
               (lrow*256 + ((kc*64 + g*16) ^ ((lrow & 7) << 4))));
  }
  f32x4 acc[4];
#pragma unroll
  for (int cg = 0; cg < 4; cg++) acc[cg] = f4zero();
  const int swz = (lr & 7) << 4;
#pragma unroll
  for (int cg = 0; cg < 4; cg++){
    const int c = colhalf*64 + cg*16 + lr;
    const int rowt = c*256;
#pragma unroll
    for (int kc = 0; kc < 4; kc++){
      s16x8 bV = *(const s16x8*)((const char*)sb + rowt + ((kc*64 + g*16) ^ swz));
      acc[cg] = MFMA16(aa[kc], bV, acc[cg]);
    }
  }
  // x1 in-register; e-weighted partial column sums
  const float e0 = eS[rowhalf*16 + 4*g + 0];
  const float e1 = eS[rowhalf*16 + 4*g + 1];
  const float e2 = eS[rowhalf*16 + 4*g + 2];
  const float e3 = eS[rowhalf*16 + 4*g + 3];
  float sA2[4];
#pragma unroll
  for (int cg = 0; cg < 4; cg++){
    int c = colhalf*64 + cg*16 + lr;
    f32x4 vv;
#pragma unroll
    for (int r = 0; r < 4; r++){
      long q = R0 + rowhalf*16 + 4*g + r;
      vv[r] = fmaxf(acc[cg][r] + x[q*128 + c], 0.f);
    }
    if (((bid & 63) == 0) && rowhalf == 0 && g == 0)
      x1r0[bb*128 + c] = vv[0];                // batch row 0
    sA2[cg] = e0*vv[0] + e1*vv[1] + e2*vv[2] + e3*vv[3];
  }
#pragma unroll
  for (int cg = 0; cg < 4; cg++){
    sA2[cg] += __shfl_xor(sA2[cg], 16, 64);
    sA2[cg] += __shfl_xor(sA2[cg], 32, 64);
  }
  if (g == 0){
#pragma unroll
    for (int cg = 0; cg < 4; cg++) redw[w][cg*16 + lr] = sA2[cg];
  }
  __syncthreads();
  if (tid < 128){
    int cl = tid & 63, pair = (tid >> 6) * 2;
    A2p[(long)bid*128 + tid] = redw[pair][cl] + redw[pair + 1][cl];
  }
  if (w == 2){
    float v = (lane < 32) ? eS[lane] : 0.f;
    v += __shfl_xor(v, 1, 64);  v += __shfl_xor(v, 2, 64);
    v += __shfl_xor(v, 4, 64);  v += __shfl_xor(v, 8, 64);
    v += __shfl_xor(v, 16, 64); v += __shfl_xor(v, 32, 64);
    if (lane == 0) Lj[bid] = v;
  }
}

// K5: out = relu((A2/L) @ w2 + x1[:,0,:]) — sums 64 chunks per batch
__global__ __launch_bounds__(256) void k_out(
    const float* __restrict__ A2p, const float* __restrict__ Lj,
    const float* __restrict__ w2, const float* __restrict__ x1r0,
    float* __restrict__ out)
{
  __shared__ float a2s[2][128];
  const int tid = threadIdx.x, bid = blockIdx.x;
  const int b0 = bid*2;
  {
    int which = tid >> 7, f = tid & 127;
    int bb = b0 + which;
    float s = 0.f, L = 0.f;
#pragma unroll
    for (int jj = 0; jj < 64; jj++){
      s += A2p[(long)(bb*64 + jj)*128 + f];
      L += Lj[bb*64 + jj];
    }
    a2s[which][f] = s / L;
  }
  __syncthreads();
  const int which = tid >> 7, d = tid & 127;
  const int b = b0 + which;
  float acc = x1r0[b*128 + d];
  for (int f = 0; f < 128; f++)
    acc += a2s[which][f] * w2[f*128 + d];
  out[b*128 + d] = fmaxf(acc, 0.f);
}

// ---------------------------------------------------------------------------
extern "C" void kernel_launch(void* const* d_in, const int* in_sizes, int n_in,
                              void* d_out, int out_size, void* d_ws, size_t ws_size,
                              hipStream_t stream)
{
  const float* x  = (const float*)d_in[0];
  const float* w1 = (const float*)d_in[1];
  const float* w2 = (const float*)d_in[2];
  const float* wr = (const float*)d_in[3];
  float* out = (float*)d_out;
  char* ws = (char*)d_ws;

  u16*   xh      = (u16*)  (ws + 0);
  u16*   xl      = (u16*)  (ws + 4194304);
  u16*   Xt      = (u16*)  (ws + 8388608);
  u16*   yh      = (u16*)  (ws + 12582912);
  u16*   yl      = (u16*)  (ws + 16777216);
  u16*   w1t     = (u16*)  (ws + 20971520);
  float* S0      = (float*)(ws + 21004288);   // 64 KB (written by k_flash)
  float* Lj      = (float*)(ws + 21070848);   // 512 floats = 2 KB
  float* A2p     = (float*)(ws + 21072896);   // 512*128*4 = 256 KB
  float* x1r0    = (float*)(ws + 21335040);   // 4 KB
  const size_t tail = 21339136;

  int KS = 4, kslog = 2;
  // per-KS bytes: mpart 64K + lpart 64K + Opart bf16 4M
  while (KS > 1 && tail + (size_t)KS*4325376ull > ws_size){ KS >>= 1; kslog--; }
  float* mpart = (float*)(ws + tail);
  float* lpart = (float*)(ws + tail + (size_t)KS*65536);
  u16*   Opart = (u16*)  (ws + tail + (size_t)KS*131072);

  k_prep   <<<1160, 256, 0, stream>>>(x, wr, w1, xh, xl, Xt, w1t, yh, yl);
  k_flash  <<<128*KS, 512, 0, stream>>>(xh, xl, Xt, yh, yl, Opart, mpart, lpart, S0, KS, kslog);
  k_mergeL1<<<512, 256, 0, stream>>>(Opart, mpart, lpart, w1t, x, S0, A2p, Lj, x1r0, KS);
  k_out    <<<4, 256, 0, stream>>>(A2p, Lj, w2, x1r0, out);
}

// Round 15
// 76.751 us; speedup vs baseline: 4.5378x; 1.0733x over previous
//
#include <hip/hip_runtime.h>
#include <stdint.h>

typedef float  f32x4 __attribute__((ext_vector_type(4)));
typedef short  s16x8 __attribute__((ext_vector_type(8)));
typedef unsigned int u32;
typedef u32    u32x2 __attribute__((ext_vector_type(2)));
typedef u32    u32x4 __attribute__((ext_vector_type(4)));
typedef unsigned short u16;

#define MFMA16(a,b,c) __builtin_amdgcn_mfma_f32_16x16x32_bf16((a),(b),(c),0,0,0)

__device__ __forceinline__ u16 f2bf(float f){
  u32 u = __float_as_uint(f);
  return (u16)((u + 0x7fffu + ((u >> 16) & 1u)) >> 16);   // RNE
}
__device__ __forceinline__ float bf2f(u16 h){ return __uint_as_float(((u32)h) << 16); }
__device__ __forceinline__ u32 pack2bf(float a, float b){ return (u32)f2bf(a) | ((u32)f2bf(b) << 16); }
// truncation pack (round-to-zero): fine for P in [0,1]
__device__ __forceinline__ u32 packtrunc(float a, float b){
  return (__float_as_uint(a) >> 16) | (__float_as_uint(b) & 0xffff0000u);
}
__device__ __forceinline__ f32x4 f4zero(){ f32x4 z; z[0]=0.f; z[1]=0.f; z[2]=0.f; z[3]=0.f; return z; }
// register-only vector build (NO union: unions can defeat SROA -> scratch)
__device__ __forceinline__ s16x8 mk8(u32 a, u32 b, u32 c, u32 d){
  u32x4 w; w[0]=a; w[1]=b; w[2]=c; w[3]=d;
  return __builtin_bit_cast(s16x8, w);
}

// async global->LDS, 16B per lane; LDS dest is wave-uniform base + lane*16
__device__ __forceinline__ void async16(const void* g, void* l){
  __builtin_amdgcn_global_load_lds(
      (const __attribute__((address_space(1))) unsigned int*)g,
      (__attribute__((address_space(3))) unsigned int*)l, 16, 0, 0);
}

// ---------------------------------------------------------------------------
// K1 mega-prep, fully fused. Block ranges:
//   [0,8):   w1^T bf16
//   [8,264): ygemm (64 rows each) + x-split (xh/xl) + Xt emission.
//     Phase A: wr^T hi/lo -> LDS (64KB). Phase B: y GEMM from raw x (the
//     in-register hi/lo split IS the xh/xl data). Phase C: fragments -> LDS
//     tile (swizzled). Phase D: coalesced xh/xl emit. Phase E: Xt transpose
//     emit from the LDS tile. x is read from HBM exactly ONCE per element.
// ---------------------------------------------------------------------------
__global__ __launch_bounds__(256) void k_prep(
    const float* __restrict__ x, const float* __restrict__ wr, const float* __restrict__ w1,
    u16* __restrict__ xh, u16* __restrict__ xl, u16* __restrict__ Xt,
    u16* __restrict__ w1t, u16* __restrict__ yh, u16* __restrict__ yl)
{
  __shared__ __align__(16) char smem[65536];
  const int tid = threadIdx.x, bid = blockIdx.x;

  if (bid < 8){
    const int base = bid * 2048;
#pragma unroll
    for (int k = 0; k < 8; k++){
      int idx = base + k*256 + tid;
      int c = idx >> 7, f = idx & 127;
      w1t[idx] = f2bf(w1[f*128 + c]);            // w1T[c][f] = w1[f][c]
    }
    return;
  }
  // ---- fused ygemm/x-split: 256 blocks x 256 thr (4 warps), 64 rows ----
  u16* sbh = (u16*)smem;                         // wr^T hi swizzled, 32 KB
  u16* sbl = sbh + 16384;                        // wr^T lo swizzled, 32 KB
  {
    const int c = tid & 127, f0 = (tid >> 7) * 64;
    const int key = (c & 7) << 4;
#pragma unroll
    for (int fi = 0; fi < 64; fi += 2){
      int f = f0 + fi;
      float v0 = wr[f*128 + c], v1 = wr[(f+1)*128 + c];
      u16 h0 = f2bf(v0), h1 = f2bf(v1);
      u32 hw = (u32)h0 | ((u32)h1 << 16);
      u32 lw = (u32)f2bf(v0 - bf2f(h0)) | ((u32)f2bf(v1 - bf2f(h1)) << 16);
      int byte = c*256 + ((((2*f) & ~15) ^ key) + ((2*f) & 15));
      *(u32*)((char*)sbh + byte) = hw;
      *(u32*)((char*)sbl + byte) = lw;
    }
  }
  __syncthreads();
  const int w = tid >> 6, lane = tid & 63, lr = lane & 15, g = lane >> 4;
  const int bidp = bid - 8;
  const long rowbase = (long)bidp * 64;
  s16x8 ah[4], al[4];
#pragma unroll
  for (int kc = 0; kc < 4; kc++){
    long r = rowbase + w*16 + lr;
    const float4* px = (const float4*)(x + r*128 + kc*32 + g*8);
    float4 a = px[0], bV = px[1];
    u32 hh0, hh1, hh2, hh3, ll0, ll1, ll2, ll3;
    { u16 p=f2bf(a.x), q=f2bf(a.y); hh0=(u32)p|((u32)q<<16);
      ll0=(u32)f2bf(a.x-bf2f(p))|((u32)f2bf(a.y-bf2f(q))<<16); }
    { u16 p=f2bf(a.z), q=f2bf(a.w); hh1=(u32)p|((u32)q<<16);
      ll1=(u32)f2bf(a.z-bf2f(p))|((u32)f2bf(a.w-bf2f(q))<<16); }
    { u16 p=f2bf(bV.x), q=f2bf(bV.y); hh2=(u32)p|((u32)q<<16);
      ll2=(u32)f2bf(bV.x-bf2f(p))|((u32)f2bf(bV.y-bf2f(q))<<16); }
    { u16 p=f2bf(bV.z), q=f2bf(bV.w); hh3=(u32)p|((u32)q<<16);
      ll3=(u32)f2bf(bV.z-bf2f(p))|((u32)f2bf(bV.w-bf2f(q))<<16); }
    ah[kc] = mk8(hh0,hh1,hh2,hh3);
    al[kc] = mk8(ll0,ll1,ll2,ll3);
  }
  f32x4 acc[8];
#pragma unroll
  for (int cg = 0; cg < 8; cg++) acc[cg] = f4zero();
  const int swz = (lr & 7) << 4;
#pragma unroll
  for (int cg = 0; cg < 8; cg++){
    const int rowt = (cg*16 + lr) * 256;
#pragma unroll
    for (int kc = 0; kc < 4; kc++){
      int boff = rowt + ((kc*64 + g*16) ^ swz);
      s16x8 bh = *(const s16x8*)((const char*)sbh + boff);
      s16x8 bl = *(const s16x8*)((const char*)sbl + boff);
      acc[cg] = MFMA16(ah[kc], bh, acc[cg]);
      acc[cg] = MFMA16(al[kc], bh, acc[cg]);
      acc[cg] = MFMA16(ah[kc], bl, acc[cg]);
    }
  }
#pragma unroll
  for (int cg = 0; cg < 8; cg++)
#pragma unroll
    for (int r = 0; r < 4; r++){
      long q = rowbase + w*16 + 4*g + r;       // C-layout: row=4g+r, col=lr
      int  c = cg*16 + lr;
      float v = acc[cg][r] * 1.4426950408889634f;
      u16 h = f2bf(v);
      yh[q*128 + c] = h;
      yl[q*128 + c] = f2bf(v - bf2f(h));
    }
  // ---- Phase C: fragments -> LDS x-tile [64][128] (swizzled) ----
  __syncthreads();                               // wr tables fully consumed
#pragma unroll
  for (int kc = 0; kc < 4; kc++){
    int off = (w*16 + lr)*256 + ((kc*64 + g*16) ^ swz);
    *(s16x8*)(smem + off)         = ah[kc];
    *(s16x8*)(smem + 16384 + off) = al[kc];
  }
  __syncthreads();
  // ---- Phase D: coalesced xh/xl emission ----
  {
    char* gbh = (char*)xh + rowbase*256;
    char* gbl = (char*)xl + rowbase*256;
#pragma unroll
    for (int it = 0; it < 4; it++){
      int off = (tid + it*256)*16;
      int row = off >> 8;
      int so = off ^ ((row & 7) << 4);
      *(s16x8*)(gbh + off) = *(const s16x8*)(smem + so);
      *(s16x8*)(gbl + off) = *(const s16x8*)(smem + 16384 + so);
    }
  }
  // ---- Phase E: Xt transpose emission (thread = (d, n-half)) ----
  {
    const int b  = bidp >> 5;
    const int n0 = (bidp & 31) * 64;
    const int d  = tid >> 1, nh = tid & 1;
    u16 tmp[32];
#pragma unroll
    for (int j = 0; j < 32; j++){
      int n = nh*32 + j;
      int byte = n*256 + ((((d >> 3) << 4) ^ ((n & 7) << 4))) + (d & 7)*2;
      tmp[j] = *(const u16*)(smem + byte);
    }
    u16* dst = Xt + (long)b*262144 + (long)d*2048 + n0 + nh*32;
#pragma unroll
    for (int j2 = 0; j2 < 4; j2++){
      s16x8 v = mk8((u32)tmp[j2*8+0] | ((u32)tmp[j2*8+1] << 16),
                    (u32)tmp[j2*8+2] | ((u32)tmp[j2*8+3] << 16),
                    (u32)tmp[j2*8+4] | ((u32)tmp[j2*8+5] << 16),
                    (u32)tmp[j2*8+6] | ((u32)tmp[j2*8+7] << 16));
      *(s16x8*)(dst + j2*8) = v;
    }
  }
}

// ---------------------------------------------------------------------------
// K3: fused flash, 8-warp (round-13/14 verified body + hoisted addressing).
//   qbl==0 / w==0 / lr==0 lanes dump the q=0 column of S^T to S0.
//   NO launch_bounds min-wave cap (spill rule: rounds 2/4/6).
// ---------------------------------------------------------------------------
__global__ __launch_bounds__(512) void k_flash(
    const u16* __restrict__ xh, const u16* __restrict__ xl, const u16* __restrict__ Xt,
    const u16* __restrict__ yh, const u16* __restrict__ yl,
    u16* __restrict__ Opart, float* __restrict__ mpart, float* __restrict__ lpart,
    float* __restrict__ S0, int KS, int kslog)
{
  __shared__ __align__(16) char lds[49152];
  const int tid = threadIdx.x, bid = blockIdx.x;
  const int b     = bid & 7;                   // XCD b owns batch b
  const int inner = bid >> 3;
  const int s     = inner & (KS - 1);
  const int qbl   = inner >> kslog;
  const int qb    = b*16 + qbl;
  const int nspan = 2048 >> kslog;
  const int kv0   = s * nspan;
  const int ntiles = nspan >> 5;
  const int w = tid >> 6, lane = tid & 63, lr = lane & 15, g = lane >> 4;
  const long qrow = (long)qb*128 + w*16;       // 16 q-rows per warp

  // ---- hoisted per-lane constants ----
  const int soff = w*1024 + lane*16;
  const int sswo = soff ^ (((soff >> 8) & 7) << 4);        // xh/xl src swz
  const int trow = soff >> 6;
  const int tsrc = trow*4096 + ((soff & 63) ^ ((trow & 3) << 4)); // xt src swz
  const int bS0 = lr*256 + (( 0 + g*16) ^ ((lr & 7) << 4));
  const int bS1 = lr*256 + (( 64 + g*16) ^ ((lr & 7) << 4));
  const int bS2 = lr*256 + ((128 + g*16) ^ ((lr & 7) << 4));
  const int bS3 = lr*256 + ((192 + g*16) ^ ((lr & 7) << 4));
  const int bPV = lr*64 + ((g*16) ^ ((lr & 3) << 4));

  // Y fragments (B-operands), hi/lo — 16 q-cols per warp
  s16x8 byh[4], byl[4];
#pragma unroll
  for (int kc = 0; kc < 4; kc++){
    long r = qrow + lr;
    byh[kc] = *(const s16x8*)(yh + r*128 + kc*32 + g*8);
    byl[kc] = *(const s16x8*)(yl + r*128 + kc*32 + g*8);
  }

  f32x4 o[8];                                  // O^T: [d-tile dg]
#pragma unroll
  for (int dg = 0; dg < 8; dg++) o[dg] = f4zero();
  float mrun = -1e30f, lrun = 0.f;

  const char* gxh  = (const char*)xh + ((long)b*2048 + kv0)*256;
  const char* gxl  = (const char*)xl + ((long)b*2048 + kv0)*256;
  const char* gxtb = (const char*)(Xt + (long)b*262144 + kv0);

  auto stage = [&](int bufi, int t){
    char* dst = lds + bufi*8192 + w*1024;      // wave-uniform dest
    async16(gxh  + (long)t*8192 + sswo, dst);
    async16(gxl  + (long)t*8192 + sswo, dst + 16384);
    async16(gxtb + (long)t*64   + tsrc, dst + 32768);
  };

  stage(0, 0);
  __syncthreads();

  for (int t = 0; t < ntiles; t++){
    const int cur = t & 1;
    const char* pb = lds + cur*8192;
    const char* a0 = pb + bS0;
    const char* a1 = pb + bS1;
    const char* a2 = pb + bS2;
    const char* a3 = pb + bS3;

    // ---- S^T tile [32kv x 16q], 3-term hi/lo split ----
    f32x4 sacc[2];                             // [kv-half ch]
    sacc[0] = f4zero(); sacc[1] = f4zero();
    __builtin_amdgcn_s_setprio(1);
#pragma unroll
    for (int ch = 0; ch < 2; ch++){
      const int co = ch*4096;                  // fh at co, fl at 16384+co
      s16x8 fh, fl;
      fh = *(const s16x8*)(a0 + co); fl = *(const s16x8*)(a0 + 16384 + co);
      sacc[ch] = MFMA16(fh, byh[0], sacc[ch]);
      sacc[ch] = MFMA16(fl, byh[0], sacc[ch]);
      sacc[ch] = MFMA16(fh, byl[0], sacc[ch]);
      fh = *(const s16x8*)(a1 + co); fl = *(const s16x8*)(a1 + 16384 + co);
      sacc[ch] = MFMA16(fh, byh[1], sacc[ch]);
      sacc[ch] = MFMA16(fl, byh[1], sacc[ch]);
      sacc[ch] = MFMA16(fh, byl[1], sacc[ch]);
      fh = *(const s16x8*)(a2 + co); fl = *(const s16x8*)(a2 + 16384 + co);
      sacc[ch] = MFMA16(fh, byh[2], sacc[ch]);
      sacc[ch] = MFMA16(fl, byh[2], sacc[ch]);
      sacc[ch] = MFMA16(fh, byl[2], sacc[ch]);
      fh = *(const s16x8*)(a3 + co); fl = *(const s16x8*)(a3 + 16384 + co);
      sacc[ch] = MFMA16(fh, byh[3], sacc[ch]);
      sacc[ch] = MFMA16(fl, byh[3], sacc[ch]);
      sacc[ch] = MFMA16(fh, byl[3], sacc[ch]);
    }
    __builtin_amdgcn_s_setprio(0);

    // prefetch next tile AFTER the S reads (LDS pipe free during reads)
    if (t + 1 < ntiles) stage(cur ^ 1, t + 1);

    // ---- q=0 column dump -> S0 (only 32 of 512 blocks; warp 0, lr==0) ----
    if (qbl == 0 && w == 0 && lr == 0){
      float* s0p = S0 + b*2048 + kv0 + t*32 + 4*g;
#pragma unroll
      for (int ch = 0; ch < 2; ch++)
#pragma unroll
        for (int r = 0; r < 4; r++)
          s0p[ch*16 + r] = sacc[ch][r];
    }

    // ---- lane-local online softmax (q = lr lives in this lane) ----
    float cm = fmaxf(fmaxf(fmaxf(sacc[0][0], sacc[0][1]),
                           fmaxf(sacc[0][2], sacc[0][3])),
                     fmaxf(fmaxf(sacc[1][0], sacc[1][1]),
                           fmaxf(sacc[1][2], sacc[1][3])));
    cm = fmaxf(cm, __shfl_xor(cm, 16, 64));
    cm = fmaxf(cm, __shfl_xor(cm, 32, 64));
    if (__any(cm > mrun + 8.f)){               // defer-max (log2 units, P<=256)
      float mn = fmaxf(mrun, cm);
      float sc = exp2f(mrun - mn);
#pragma unroll
      for (int dg = 0; dg < 8; dg++)
#pragma unroll
        for (int r = 0; r < 4; r++) o[dg][r] *= sc;
      lrun *= sc;
      mrun = mn;
    }
    float p[2][4];
#pragma unroll
    for (int ch = 0; ch < 2; ch++)
#pragma unroll
      for (int r = 0; r < 4; r++) p[ch][r] = exp2f(sacc[ch][r] - mrun);
    float ls = ((p[0][0] + p[0][1]) + (p[0][2] + p[0][3]))
             + ((p[1][0] + p[1][1]) + (p[1][2] + p[1][3]));
    ls += __shfl_xor(ls, 16, 64);
    ls += __shfl_xor(ls, 32, 64);
    lrun += ls;
    // lane (g,lr) holds P[q=lr][kv=16ch+4g+r]; B-frag needs kv=8g+j.
    s16x8 bpq;
    {
      u32 pw00 = packtrunc(p[0][0], p[0][1]);
      u32 pw01 = packtrunc(p[0][2], p[0][3]);
      u32 pw10 = packtrunc(p[1][0], p[1][1]);
      u32 pw11 = packtrunc(p[1][2], p[1][3]);
      int sA = ((g & 1) << 5) + lr;
      int sB = sA + 16;
      u32 a0s = (u32)__shfl((int)pw00, sA, 64);
      u32 a1s = (u32)__shfl((int)pw01, sA, 64);
      u32 a2s = (u32)__shfl((int)pw10, sA, 64);
      u32 a3s = (u32)__shfl((int)pw11, sA, 64);
      u32 b0s = (u32)__shfl((int)pw00, sB, 64);
      u32 b1s = (u32)__shfl((int)pw01, sB, 64);
      u32 b2s = (u32)__shfl((int)pw10, sB, 64);
      u32 b3s = (u32)__shfl((int)pw11, sB, 64);
      bool hi = (g >= 2);
      bpq = mk8(hi ? a2s : a0s, hi ? a3s : a1s, hi ? b2s : b0s, hi ? b3s : b1s);
    }

    // ---- O^T += Xt-frag (LDS swz) x P^T (regs) ----
    const char* ap = pb + 32768 + bPV;
    __builtin_amdgcn_s_setprio(1);
#pragma unroll
    for (int half = 0; half < 2; half++){
      s16x8 ax[4];
#pragma unroll
      for (int i = 0; i < 4; i++)
        ax[i] = *(const s16x8*)(ap + (half*4 + i)*1024);
#pragma unroll
      for (int i = 0; i < 4; i++)
        o[half*4 + i] = MFMA16(ax[i], bpq, o[half*4 + i]);
    }
    __builtin_amdgcn_s_setprio(0);
    __syncthreads();   // drains prefetch + guards buffer reuse
  }

  // ---- epilogue: split-major partials for contiguous merge reads ----
  {
    int lq = w*16 + lr;
    long bi = (long)(qbl*8 + b)*128 + lq;
    u16* op = Opart + bi*(long)(128 << kslog) + s*128;
#pragma unroll
    for (int dg = 0; dg < 8; dg++){
      u32x2 pw;
      pw[0] = pack2bf(o[dg][0], o[dg][1]);
      pw[1] = pack2bf(o[dg][2], o[dg][3]);
      *(u32x2*)(op + dg*16 + 4*g) = pw;
    }
    if (g == 0){
      mpart[bi*KS + s] = mrun;
      lpart[bi*KS + s] = lrun;
    }
  }
}

// ---------------------------------------------------------------------------
// K4 (fused merge + layer1 + a2-partial): 512 blocks x 256 thr, 32 rows each.
//   Phase 1: merge KS contiguous split-partials -> swizzled LDS A1 tile.
//   Phase 2: x1 = relu(A1 @ w1 + x) in registers (4 warps = 2 rowhalf x 2 colhalf).
//   Phase 3: A2p[bid] = sum_q e_q * x1[q,:], Lj[bid] = sum_q e_q.
//   eS from k_flash's S0 (log2 units) with M0 = row-0 running-max from mpart.
// ---------------------------------------------------------------------------
__global__ __launch_bounds__(256) void k_mergeL1(
    const u16* __restrict__ Opart, const float* __restrict__ mpart, const float* __restrict__ lpart,
    const u16* __restrict__ w1t, const float* __restrict__ x,
    const float* __restrict__ S0,
    float* __restrict__ A2p, float* __restrict__ Lj, float* __restrict__ x1r0,
    int KS)
{
  __shared__ u16 sb[16384];                    // w1^T [c][f] swizzled (32KB)
  __shared__ u16 sa[4096];                     // A1 tile [32][128] swz (8KB)
  __shared__ float eS[32];
  __shared__ float redw[4][64];
  const int tid = threadIdx.x, bid = blockIdx.x;
  const int bb   = bid >> 6;                   // batch
  const int qbl  = (bid >> 2) & 15;
  const int rb   = (bid & 3) * 32;             // row offset within q-block
  const long R0  = (long)bid*32;               // global row base
#pragma unroll
  for (int k = 0; k < 8; k++){
    int off = (tid + k*256)*16;
    int row = off >> 8;
    *(s16x8*)((char*)sb + (off ^ ((row & 7) << 4))) = *(const s16x8*)((const char*)w1t + off);
  }
  if (tid < 32){
    const float* mp0 = mpart + (long)(bb*128)*KS;     // bi for (qbl=0,row 0)
    float M = -1e30f;
    for (int s = 0; s < KS; s++) M = fmaxf(M, mp0[s]);
    eS[tid] = exp2f(S0[bb*2048 + (bid & 63)*32 + tid] - M);
  }
  // merge phase: 512 granules (32 rows x 16), 2 per thread
#pragma unroll
  for (int k = 0; k < 2; k++){
    int gidx = tid + k*256;
    int lrow = gidx >> 4, gcol = gidx & 15;
    long bi = (long)(qbl*8 + bb)*128 + rb + lrow;
    const float* mp = mpart + bi*KS;
    const float* lp = lpart + bi*KS;
    float m = -1e30f;
    for (int s = 0; s < KS; s++) m = fmaxf(m, mp[s]);
    float ls = 0.f;
    float a0=0.f,a1=0.f,a2=0.f,a3=0.f,a4=0.f,a5=0.f,a6=0.f,a7=0.f;
    const u16* ob = Opart + bi*(long)(KS*128) + gcol*8;
    for (int s = 0; s < KS; s++){
      float wgt = exp2f(mp[s] - m);
      ls += lp[s] * wgt;
      u32x4 v = *(const u32x4*)(ob + s*128);
      a0 += bf2f((u16)(v[0] & 0xffff)) * wgt;  a1 += bf2f((u16)(v[0] >> 16)) * wgt;
      a2 += bf2f((u16)(v[1] & 0xffff)) * wgt;  a3 += bf2f((u16)(v[1] >> 16)) * wgt;
      a4 += bf2f((u16)(v[2] & 0xffff)) * wgt;  a5 += bf2f((u16)(v[2] >> 16)) * wgt;
      a6 += bf2f((u16)(v[3] & 0xffff)) * wgt;  a7 += bf2f((u16)(v[3] >> 16)) * wgt;
    }
    float inv = 1.f / ls;
    u32x4 pw;
    pw[0] = pack2bf(a0*inv, a1*inv); pw[1] = pack2bf(a2*inv, a3*inv);
    pw[2] = pack2bf(a4*inv, a5*inv); pw[3] = pack2bf(a6*inv, a7*inv);
    int off = lrow*256 + gcol*16;
    *(u32x4*)((char*)sa + (off ^ ((lrow & 7) << 4))) = pw;
  }
  __syncthreads();
  // GEMM phase: warp w = rowhalf (w&1) x colhalf (w>>1); 16 rows x 64 cols
  const int w = tid >> 6, lane = tid & 63, lr = lane & 15, g = lane >> 4;
  const int rowhalf = w & 1, colhalf = w >> 1;
  s16x8 aa[4];
#pragma unroll
  for (int kc = 0; kc < 4; kc++){
    int lrow = rowhalf*16 + lr;
    aa[kc] = *(const s16x8*)((const char*)sa +
               (lrow*256 + ((kc*64 + g*16) ^ ((lrow & 7) << 4))));
  }
  f32x4 acc[4];
#pragma unroll
  for (int cg = 0; cg < 4; cg++) acc[cg] = f4zero();
  const int swz = (lr & 7) << 4;
#pragma unroll
  for (int cg = 0; cg < 4; cg++){
    const int c = colhalf*64 + cg*16 + lr;
    const int rowt = c*256;
#pragma unroll
    for (int kc = 0; kc < 4; kc++){
      s16x8 bV = *(const s16x8*)((const char*)sb + rowt + ((kc*64 + g*16) ^ swz));
      acc[cg] = MFMA16(aa[kc], bV, acc[cg]);
    }
  }
  // x1 in-register; e-weighted partial column sums
  const float e0 = eS[rowhalf*16 + 4*g + 0];
  const float e1 = eS[rowhalf*16 + 4*g + 1];
  const float e2 = eS[rowhalf*16 + 4*g + 2];
  const float e3 = eS[rowhalf*16 + 4*g + 3];
  float sA2[4];
#pragma unroll
  for (int cg = 0; cg < 4; cg++){
    int c = colhalf*64 + cg*16 + lr;
    f32x4 vv;
#pragma unroll
    for (int r = 0; r < 4; r++){
      long q = R0 + rowhalf*16 + 4*g + r;
      vv[r] = fmaxf(acc[cg][r] + x[q*128 + c], 0.f);
    }
    if (((bid & 63) == 0) && rowhalf == 0 && g == 0)
      x1r0[bb*128 + c] = vv[0];                // batch row 0
    sA2[cg] = e0*vv[0] + e1*vv[1] + e2*vv[2] + e3*vv[3];
  }
#pragma unroll
  for (int cg = 0; cg < 4; cg++){
    sA2[cg] += __shfl_xor(sA2[cg], 16, 64);
    sA2[cg] += __shfl_xor(sA2[cg], 32, 64);
  }
  if (g == 0){
#pragma unroll
    for (int cg = 0; cg < 4; cg++) redw[w][cg*16 + lr] = sA2[cg];
  }
  __syncthreads();
  if (tid < 128){
    int cl = tid & 63, pair = (tid >> 6) * 2;
    A2p[(long)bid*128 + tid] = redw[pair][cl] + redw[pair + 1][cl];
  }
  if (w == 2){
    float v = (lane < 32) ? eS[lane] : 0.f;
    v += __shfl_xor(v, 1, 64);  v += __shfl_xor(v, 2, 64);
    v += __shfl_xor(v, 4, 64);  v += __shfl_xor(v, 8, 64);
    v += __shfl_xor(v, 16, 64); v += __shfl_xor(v, 32, 64);
    if (lane == 0) Lj[bid] = v;
  }
}

// K5: out = relu((A2/L) @ w2 + x1[:,0,:]) — 8 blocks (1/batch), f split 2-way
__global__ __launch_bounds__(256) void k_out(
    const float* __restrict__ A2p, const float* __restrict__ Lj,
    const float* __restrict__ w2, const float* __restrict__ x1r0,
    float* __restrict__ out)
{
  __shared__ float a2s[128];
  __shared__ float partial[128];
  __shared__ float Lsh;
  const int tid = threadIdx.x, b = blockIdx.x;
  const int f = tid & 127, h = tid >> 7;
  float s = 0.f;
  for (int jj = h*32; jj < h*32 + 32; jj++)
    s += A2p[(long)(b*64 + jj)*128 + f];
  if (h == 1) partial[f] = s;
  if (tid < 64){
    float Lp = Lj[b*64 + tid];
    Lp += __shfl_xor(Lp, 1, 64);  Lp += __shfl_xor(Lp, 2, 64);
    Lp += __shfl_xor(Lp, 4, 64);  Lp += __shfl_xor(Lp, 8, 64);
    Lp += __shfl_xor(Lp, 16, 64); Lp += __shfl_xor(Lp, 32, 64);
    if (tid == 0) Lsh = Lp;
  }
  __syncthreads();
  if (h == 0) a2s[f] = (s + partial[f]) / Lsh;
  __syncthreads();
  const int d = tid & 127, fh = tid >> 7;
  float acc = 0.f;
  for (int f2 = fh*64; f2 < fh*64 + 64; f2++)
    acc += a2s[f2] * w2[f2*128 + d];
  if (fh == 1) partial[d] = acc;
  __syncthreads();
  if (fh == 0)
    out[b*128 + d] = fmaxf(acc + partial[d] + x1r0[b*128 + d], 0.f);
}

// ---------------------------------------------------------------------------
extern "C" void kernel_launch(void* const* d_in, const int* in_sizes, int n_in,
                              void* d_out, int out_size, void* d_ws, size_t ws_size,
                              hipStream_t stream)
{
  const float* x  = (const float*)d_in[0];
  const float* w1 = (const float*)d_in[1];
  const float* w2 = (const float*)d_in[2];
  const float* wr = (const float*)d_in[3];
  float* out = (float*)d_out;
  char* ws = (char*)d_ws;

  u16*   xh      = (u16*)  (ws + 0);
  u16*   xl      = (u16*)  (ws + 4194304);
  u16*   Xt      = (u16*)  (ws + 8388608);
  u16*   yh      = (u16*)  (ws + 12582912);
  u16*   yl      = (u16*)  (ws + 16777216);
  u16*   w1t     = (u16*)  (ws + 20971520);
  float* S0      = (float*)(ws + 21004288);   // 64 KB (written by k_flash)
  float* Lj      = (float*)(ws + 21070848);   // 512 floats = 2 KB
  float* A2p     = (float*)(ws + 21072896);   // 512*128*4 = 256 KB
  float* x1r0    = (float*)(ws + 21335040);   // 4 KB
  const size_t tail = 21339136;

  int KS = 4, kslog = 2;
  // per-KS bytes: mpart 64K + lpart 64K + Opart bf16 4M
  while (KS > 1 && tail + (size_t)KS*4325376ull > ws_size){ KS >>= 1; kslog--; }
  float* mpart = (float*)(ws + tail);
  float* lpart = (float*)(ws + tail + (size_t)KS*65536);
  u16*   Opart = (u16*)  (ws + tail + (size_t)KS*131072);

  k_prep   <<<264, 256, 0, stream>>>(x, wr, w1, xh, xl, Xt, w1t, yh, yl);
  k_flash  <<<128*KS, 512, 0, stream>>>(xh, xl, Xt, yh, yl, Opart, mpart, lpart, S0, KS, kslog);
  k_mergeL1<<<512, 256, 0, stream>>>(Opart, mpart, lpart, w1t, x, S0, A2p, Lj, x1r0, KS);
  k_out    <<<8, 256, 0, stream>>>(A2p, Lj, w2, x1r0, out);
}